// Round 6
// baseline (351.197 us; speedup 1.0000x reference)
//
#include <hip/hip_runtime.h>
#include <hip/hip_bf16.h>

#define TSEQ 2048
#define NHEAD 16
#define DM 1024
#define NBATCH 2
#define MTOK (NBATCH * TSEQ)   // 4096

typedef __attribute__((ext_vector_type(8))) short short8;
typedef __attribute__((ext_vector_type(4))) float floatx4;
typedef __attribute__((address_space(1))) const void gvoid;
typedef __attribute__((address_space(3))) void lvoid;

static __device__ __forceinline__ unsigned short f2bf(float f) {
    unsigned int u = __float_as_uint(f);
    return (unsigned short)((u + 0x7fffu + ((u >> 16) & 1u)) >> 16);
}
static __device__ __forceinline__ float bf2f(unsigned short h) {
    return __uint_as_float(((unsigned int)h) << 16);
}

// ---------------------------------------------------------------------------
// Pack x and the 6 weight matrices to split bf16 rows.
//   x      -> [hi(1024) | lo(1024)]
//   Wproj  -> [hi | lo]            (3-term proj GEMM needs lo)
//   Wq..Wv -> [hi | hi] DUPLICATED (qkv GEMM becomes one plain K=2048 GEMM)
//   Wq,Wk,Wq2,Wk2 rows additionally PER-HEAD INTERLEAVED:
//     d<32 -> (d>>3)*16 + (d&7) ; d>=32 -> ((d-32)>>3)*16 + 8 + (d&7)
//   so each 16-col C-fragment holds RoPE pairs at lanes cc / cc^8
//   (lane-local RoPE via shfl_xor; q and k share the permutation so QK^T
//   is invariant and attention is unchanged; Wv stays plain).
// blocks [0,4096) -> x ; [4096,10240) -> weights (1024 blocks each).
// ---------------------------------------------------------------------------
__global__ __launch_bounds__(256)
void pack_all_kernel(const float* __restrict__ x,
                     const float* __restrict__ w0, const float* __restrict__ w1,
                     const float* __restrict__ w2, const float* __restrict__ w3,
                     const float* __restrict__ w4, const float* __restrict__ w5,
                     unsigned short* __restrict__ dstX, unsigned short* __restrict__ dstW)
{
    const float* src;
    unsigned short* dst;
    int gid;
    bool dup = false, ilv = false;
    if (blockIdx.x < 4096) {
        src = x; dst = dstX;
        gid = blockIdx.x * 256 + threadIdx.x;
    } else {
        int wi = (blockIdx.x - 4096) >> 10;
        const float* srcs[6] = {w0, w1, w2, w3, w4, w5};
        src = srcs[wi];
        dst = dstW + (size_t)wi * 1024 * 2048;
        gid = ((blockIdx.x - 4096) & 1023) * 256 + threadIdx.x;
        dup = (wi != 0);
        ilv = (wi >= 1 && wi <= 4);   // Wq, Wk, Wq2, Wk2
    }
    int e   = gid * 4;
    int row = e >> 10;
    int col = e & 1023;
    float4 f = *(const float4*)(src + (size_t)row * 1024 + col);
    ushort4 hi, lo;
    hi.x = f2bf(f.x); lo.x = f2bf(f.x - bf2f(hi.x));
    hi.y = f2bf(f.y); lo.y = f2bf(f.y - bf2f(hi.y));
    hi.z = f2bf(f.z); lo.z = f2bf(f.z - bf2f(hi.z));
    hi.w = f2bf(f.w); lo.w = f2bf(f.w - bf2f(hi.w));
    int drow = row;
    if (ilv) {
        int hh = row >> 6, d = row & 63;
        int dd = (d < 32) ? ((d >> 3) * 16 + (d & 7))
                          : (((d - 32) >> 3) * 16 + 8 + (d & 7));
        drow = hh * 64 + dd;
    }
    *(ushort4*)(dst + (size_t)drow * 2048 + col)        = hi;
    *(ushort4*)(dst + (size_t)drow * 2048 + 1024 + col) = dup ? hi : lo;
}

// ---------------------------------------------------------------------------
// qkv GEMM (round-1 version, UNCHANGED):
//   C[4096][5120] = Xp[4096][2048] . Bdup[5120][2048]^T   (plain bf16 GEMM)
// Tile 256x320, K-tile 64 (two kh of 32), 512 threads = 8 waves, 2M x 4N.
// ---------------------------------------------------------------------------
#define VMW(N) asm volatile("s_waitcnt vmcnt(" #N ")" ::: "memory")
#define LGKM0  asm volatile("s_waitcnt lgkmcnt(0)" ::: "memory")

__global__ __launch_bounds__(512, 2)
void gemm_qkv(const unsigned short* __restrict__ Ap,
              const unsigned short* __restrict__ Bp,
              unsigned short* __restrict__ Ch, unsigned short* __restrict__ Vt)
{
    __shared__ __align__(16) unsigned short A0s[2][8192];    // [256][32] each
    __shared__ __align__(16) unsigned short A1s[2][8192];
    __shared__ __align__(16) unsigned short B0s[2][10240];   // [320][32] each
    __shared__ __align__(16) unsigned short B1s[2][10240];

    const int t    = threadIdx.x;
    const int lane = t & 63;
    const int w    = t >> 6;
    const int wm   = w >> 2;          // M-half (0..1): 128 rows
    const int wn   = w & 3;           // N-quarter (0..3): 80 cols
    const int s    = lane & 15;
    const int g    = (lane >> 4) & 3;
    const int row0 = blockIdx.x * 256;
    const int col0 = blockIdx.y * 320;

    // read-side swizzled offsets (element units, 32-wide rows)
    const int cofs  = ((g ^ ((lane >> 1) & 3)) << 3);
    const int addrA = (wm * 128 + s) * 32 + cofs;   // + ii*512
    const int addrB = (wn * 80 + s) * 32 + cofs;    // + nf*512

    // stage-side pre-swizzled global source base (logical chunk per thread)
    const int alc = (t & 3) ^ ((t >> 3) & 3);
    const unsigned short* Ag = Ap + (size_t)(row0 + (t >> 2)) * 2048 + alc * 8;
    const unsigned short* Bg = Bp + (size_t)(col0 + (t >> 2)) * 2048 + alc * 8;

#define STAGE_A(dst, kofs) {                                                                              \
    __builtin_amdgcn_global_load_lds((gvoid*)(Ag + (kofs)),              (lvoid*)((dst) + t * 8),        16, 0, 0); \
    __builtin_amdgcn_global_load_lds((gvoid*)(Ag + (kofs) + 128 * 2048), (lvoid*)((dst) + 4096 + t * 8), 16, 0, 0); }

#define STAGE_B(dst, kofs) {                                                                              \
    __builtin_amdgcn_global_load_lds((gvoid*)(Bg + (kofs)),              (lvoid*)((dst) + t * 8),        16, 0, 0); \
    __builtin_amdgcn_global_load_lds((gvoid*)(Bg + (kofs) + 128 * 2048), (lvoid*)((dst) + 4096 + t * 8), 16, 0, 0); \
    if (t < 256)                                                                                          \
    __builtin_amdgcn_global_load_lds((gvoid*)(Bg + (kofs) + 256 * 2048), (lvoid*)((dst) + 8192 + t * 8), 16, 0, 0); }

    floatx4 acc[8][5];
    #pragma unroll
    for (int ii = 0; ii < 8; ++ii)
        #pragma unroll
        for (int nf = 0; nf < 5; ++nf)
            acc[ii][nf] = (floatx4)(0.0f);

    // ---- prologue: tile0 (kh0,kh1) and tile1 (kh0) ----
    STAGE_A(A0s[0], 0);
    STAGE_B(B0s[0], 0);
    STAGE_A(A1s[0], 32);
    STAGE_B(B1s[0], 32);
    STAGE_A(A0s[1], 64);
    STAGE_B(B0s[1], 64);
    VMW(4);                       // tile0 fully landed (newest 4-5 = tile1 kh0)
    __builtin_amdgcn_s_barrier();
    __builtin_amdgcn_sched_barrier(0);

#define MFMA_CLUSTER(IOFS)                                                                      \
    __builtin_amdgcn_s_setprio(1);                                                              \
    _Pragma("unroll")                                                                           \
    for (int ii = 0; ii < 4; ++ii)                                                              \
        _Pragma("unroll")                                                                       \
        for (int nf = 0; nf < 5; ++nf)                                                          \
            acc[(IOFS) + ii][nf] = __builtin_amdgcn_mfma_f32_16x16x32_bf16(af[ii], bf[nf], acc[(IOFS) + ii][nf], 0, 0, 0); \
    __builtin_amdgcn_s_setprio(0);

#define TILE_BODY(TAU, DO12, DO34, W2, W4)                                                      \
{                                                                                               \
    const int cur_ = (TAU) & 1;                                                                 \
    const unsigned short* a0k = A0s[cur_];                                                      \
    const unsigned short* a1k = A1s[cur_];                                                      \
    const unsigned short* b0k = B0s[cur_];                                                      \
    const unsigned short* b1k = B1s[cur_];                                                      \
    short8 af[4], bf[5];                                                                        \
    /* ---- p1: kh0, M-half0 + B-kh0 read ; stage (TAU+1) A-kh1 ---- */                         \
    _Pragma("unroll")                                                                           \
    for (int ii = 0; ii < 4; ++ii) af[ii] = *(const short8*)&a0k[addrA + ii * 512];             \
    _Pragma("unroll")                                                                           \
    for (int nf = 0; nf < 5; ++nf) bf[nf] = *(const short8*)&b0k[addrB + nf * 512];             \
    if (DO12) STAGE_A(A1s[cur_ ^ 1], ((TAU) + 1) * 64 + 32);                                    \
    LGKM0;                                                                                      \
    __builtin_amdgcn_s_barrier();                                                               \
    __builtin_amdgcn_sched_barrier(0);                                                          \
    MFMA_CLUSTER(0)                                                                             \
    /* ---- p2: kh0, M-half1 ; stage (TAU+1) B-kh1 ; vmcnt ---- */                              \
    _Pragma("unroll")                                                                           \
    for (int ii = 0; ii < 4; ++ii) af[ii] = *(const short8*)&a0k[addrA + (ii + 4) * 512];       \
    if (DO12) STAGE_B(B1s[cur_ ^ 1], ((TAU) + 1) * 64 + 32);                                    \
    LGKM0;                                                                                      \
    W2;                                                                                         \
    __builtin_amdgcn_s_barrier();                                                               \
    __builtin_amdgcn_sched_barrier(0);                                                          \
    MFMA_CLUSTER(4)                                                                             \
    /* ---- p3: kh1, M-half0 + B-kh1 read ; stage (TAU+2) A-kh0 ---- */                         \
    _Pragma("unroll")                                                                           \
    for (int ii = 0; ii < 4; ++ii) af[ii] = *(const short8*)&a1k[addrA + ii * 512];             \
    _Pragma("unroll")                                                                           \
    for (int nf = 0; nf < 5; ++nf) bf[nf] = *(const short8*)&b1k[addrB + nf * 512];             \
    if (DO34) STAGE_A(A0s[cur_], ((TAU) + 2) * 64);                                             \
    LGKM0;                                                                                      \
    __builtin_amdgcn_s_barrier();                                                               \
    __builtin_amdgcn_sched_barrier(0);                                                          \
    MFMA_CLUSTER(0)                                                                             \
    /* ---- p4: kh1, M-half1 ; stage (TAU+2) B-kh0 ; vmcnt ---- */                              \
    _Pragma("unroll")                                                                           \
    for (int ii = 0; ii < 4; ++ii) af[ii] = *(const short8*)&a1k[addrA + (ii + 4) * 512];       \
    if (DO34) STAGE_B(B0s[cur_], ((TAU) + 2) * 64);                                             \
    LGKM0;                                                                                      \
    W4;                                                                                         \
    __builtin_amdgcn_s_barrier();                                                               \
    __builtin_amdgcn_sched_barrier(0);                                                          \
    MFMA_CLUSTER(4)                                                                             \
}

    #pragma unroll 2
    for (int tau = 0; tau < 30; ++tau)
        TILE_BODY(tau, 1, 1, VMW(8), VMW(8));
    TILE_BODY(30, 1, 0, VMW(8), VMW(4));
    TILE_BODY(31, 0, 0, VMW(0), ((void)0));

#undef TILE_BODY
#undef MFMA_CLUSTER
#undef STAGE_A
#undef STAGE_B

    // ---- epilogue: lane-local RoPE (+1/64 q-scale); V transposed ----
    const int cr = (lane >> 4) * 4;
    const int cc = lane & 15;
    const int rwbase = row0 + wm * 128;
    const float L2C = -0.41524101186092029f;  // -log2(10000)/32

    #pragma unroll
    for (int nf = 0; nf < 5; ++nf) {
        const int cg = col0 + wn * 80 + nf * 16;  // global col of this frag
        const int p  = cg >> 10;                  // 0=q 1=k 2=q2 3=k2 4=v
        const int h  = (cg >> 6) & 15;
        const int f  = (cg >> 4) & 3;
        if (p < 4) {
            const float sc  = (p == 0 || p == 2) ? 0.015625f : 1.0f;
            const float inv = exp2f((float)(f * 8 + (cc & 7)) * L2C);
            unsigned short* hp = Ch + (size_t)p * 4194304;
            #pragma unroll
            for (int ii = 0; ii < 8; ++ii) {
                int r0  = rwbase + ii * 16 + cr;
                int bhi = ((r0 >> 11) << 4) + h;
                size_t base = ((size_t)bhi * 2048 + (r0 & 2047)) * 64;
                #pragma unroll
                for (int rr = 0; rr < 4; ++rr) {
                    float tt = (float)((r0 + rr) & 2047);
                    float s0, c0;
                    __sincosf(tt * inv, &s0, &c0);
                    float x  = acc[ii][nf][rr];
                    float xp = __shfl_xor(x, 8, 64);
                    float y  = (cc < 8) ? (x * c0 + xp * s0) : (x * c0 - xp * s0);
                    hp[base + (size_t)rr * 64 + (f * 16 + cc)] = f2bf(y * sc);
                }
            }
        } else {
            #pragma unroll
            for (int ii = 0; ii < 8; ++ii) {
                int r0  = rwbase + ii * 16 + cr;
                int bhi = ((r0 >> 11) << 4) + h;
                int d   = f * 16 + cc;
                ushort4 o;
                o.x = f2bf(acc[ii][nf][0]); o.y = f2bf(acc[ii][nf][1]);
                o.z = f2bf(acc[ii][nf][2]); o.w = f2bf(acc[ii][nf][3]);
                *(ushort4*)(Vt + ((size_t)bhi * 64 + d) * 2048 + (r0 & 2047)) = o;
            }
        }
    }
}

// ---------------------------------------------------------------------------
// Output projection: C = (hiA+loA)*hiB^T + hiA*loB^T (3-term), fp32 out.
// 128x128 template (round-5, UNCHANGED): grid (32,8) = 256 blocks = 1/CU,
// 4 waves (wave-tile 64x64), 48 MFMA : 16 ds_reads per K-step, 32 KB LDS.
// ---------------------------------------------------------------------------
__global__ __launch_bounds__(256)
void gemm_proj(const unsigned short* __restrict__ Ap,
               const unsigned short* __restrict__ Bp,
               float* __restrict__ Cf)
{
    __shared__ __align__(16) unsigned short Ah[128 * 32];
    __shared__ __align__(16) unsigned short Al[128 * 32];
    __shared__ __align__(16) unsigned short Bh[128 * 32];
    __shared__ __align__(16) unsigned short Bl[128 * 32];

    const int t    = threadIdx.x;
    const int lane = t & 63;
    const int s    = lane & 15;
    const int row0 = blockIdx.x * 128;
    const int col0 = blockIdx.y * 128;
    const int m0   = ((t >> 6) >> 1) * 64;
    const int n0   = ((t >> 6) & 1) * 64;

    floatx4 acc[4][4];
    #pragma unroll
    for (int i = 0; i < 4; ++i)
        #pragma unroll
        for (int j = 0; j < 4; ++j)
            acc[i][j] = (floatx4)(0.0f);

    const int sr  = t >> 2;
    const int skx = ((t & 3) ^ ((t >> 3) & 3)) * 8;
    char* dA  = (char*)Ah + (size_t)t * 16;
    char* dAl = (char*)Al + (size_t)t * 16;
    char* dB  = (char*)Bh + (size_t)t * 16;
    char* dBl = (char*)Bl + (size_t)t * 16;
    const size_t arow = (size_t)(row0 + sr) * 2048 + skx;
    const size_t brow = (size_t)(col0 + sr) * 2048 + skx;

    #define ISSUE(k0)                                                                         \
    {                                                                                         \
        const unsigned short* ga = Ap + arow + (k0);                                          \
        const unsigned short* gb = Bp + brow + (k0);                                          \
        __builtin_amdgcn_global_load_lds((gvoid*)ga,                 (lvoid*)dA,          16, 0, 0); \
        __builtin_amdgcn_global_load_lds((gvoid*)(ga + 64*2048),     (lvoid*)(dA + 4096), 16, 0, 0); \
        __builtin_amdgcn_global_load_lds((gvoid*)(ga + 1024),        (lvoid*)dAl,         16, 0, 0); \
        __builtin_amdgcn_global_load_lds((gvoid*)(ga + 1024+64*2048),(lvoid*)(dAl + 4096),16, 0, 0); \
        __builtin_amdgcn_global_load_lds((gvoid*)gb,                 (lvoid*)dB,          16, 0, 0); \
        __builtin_amdgcn_global_load_lds((gvoid*)(gb + 64*2048),     (lvoid*)(dB + 4096), 16, 0, 0); \
        __builtin_amdgcn_global_load_lds((gvoid*)(gb + 1024),        (lvoid*)dBl,         16, 0, 0); \
        __builtin_amdgcn_global_load_lds((gvoid*)(gb + 1024+64*2048),(lvoid*)(dBl + 4096),16, 0, 0); \
    }

    const int cofs = (((lane >> 4) ^ ((lane >> 1) & 3)) << 3);

    ISSUE(0);
    for (int ks = 0; ks < 32; ++ks) {
        __syncthreads();
        short8 ahf[4], alf[4], bhf[4], blf[4];
        #pragma unroll
        for (int i = 0; i < 4; ++i) {
            int ra = (m0 + i * 16 + s) * 32 + cofs;
            ahf[i] = *(const short8*)&Ah[ra];
            alf[i] = *(const short8*)&Al[ra];
        }
        #pragma unroll
        for (int j = 0; j < 4; ++j) {
            int rb = (n0 + j * 16 + s) * 32 + cofs;
            bhf[j] = *(const short8*)&Bh[rb];
            blf[j] = *(const short8*)&Bl[rb];
        }
        #pragma unroll
        for (int i = 0; i < 4; ++i)
            #pragma unroll
            for (int j = 0; j < 4; ++j) {
                acc[i][j] = __builtin_amdgcn_mfma_f32_16x16x32_bf16(ahf[i], bhf[j], acc[i][j], 0, 0, 0);
                acc[i][j] = __builtin_amdgcn_mfma_f32_16x16x32_bf16(alf[i], bhf[j], acc[i][j], 0, 0, 0);
                acc[i][j] = __builtin_amdgcn_mfma_f32_16x16x32_bf16(ahf[i], blf[j], acc[i][j], 0, 0, 0);
            }
        __syncthreads();
        if (ks + 1 < 32) ISSUE((ks + 1) * 32);
    }
    #undef ISSUE

    const int cr = (lane >> 4) * 4;
    const int cc = lane & 15;
    #pragma unroll
    for (int i = 0; i < 4; ++i)
        #pragma unroll
        for (int j = 0; j < 4; ++j) {
            int r = row0 + m0 + i * 16 + cr;
            int c = col0 + n0 + j * 16 + cc;
            #pragma unroll
            for (int rr = 0; rr < 4; ++rr)
                Cf[(size_t)(r + rr) * 1024 + c] = acc[i][j][rr];
        }
}

// ---------------------------------------------------------------------------
// MFMA bilinear causal attention — RE-PARTITIONED to 8 waves (512 threads).
// Same algorithm/LDS layout/barrier count as the 4-wave version; k-split goes
// 2-way -> 4-way (32 rows/wave), PV q-ownership 32 -> 16 rows/wave, staging
// halves per thread. 2 blocks/CU x 8 waves = 4 waves/SIMD (was 2) to hide
// the 3-barrier/tile LDS windows under other waves' MFMA.
// __launch_bounds__(512,4) caps VGPR at 128 so both blocks stay resident.
// LDS 80 KB unchanged; psq overlays qs/q2s.
// ---------------------------------------------------------------------------
__global__ __launch_bounds__(512, 4)
void attn_mfma(const unsigned short* __restrict__ qh, const unsigned short* __restrict__ q2h,
               const unsigned short* __restrict__ kh, const unsigned short* __restrict__ k2h,
               const unsigned short* __restrict__ vt, unsigned short* __restrict__ zout)
{
    __shared__ __align__(16) unsigned short smem[40960];   // 80 KB
    unsigned short* qs  = smem;              // [128][64] rot8 (init only)
    unsigned short* q2s = smem + 8192;
    unsigned short* psq = smem;              // [128][128] rot16, overlays qs/q2s
    unsigned short* ks  = smem + 16384;      // [128][64] rot8
    unsigned short* k2s = smem + 24576;
    unsigned short* vts = smem + 32768;      // [64][128] rot16

    const int bh = blockIdx.y;
    const int qt = (bh < 16) ? (15 - blockIdx.x) : blockIdx.x;  // pair heavy+light
    const int t  = threadIdx.x;
    const int lane = t & 63;
    const int w    = t >> 6;          // 0..7
    const int s    = lane & 15;
    const int g    = lane >> 4;
    const int mk   = (w >> 1) * 32;   // 4-way k-split: 32 rows/wave
    const int nq   = (w & 1) * 64;    // 2-way q-split

    // ---- stage q, q2 once, then hoist frags to registers ----
    {
        const unsigned short* qb  = qh  + ((size_t)bh * 2048 + qt * 128) * 64;
        const unsigned short* q2b = q2h + ((size_t)bh * 2048 + qt * 128) * 64;
        const int row = t >> 2;                    // 0..127
        #pragma unroll
        for (int c = 0; c < 2; ++c) {
            int cg  = (t & 3) * 2 + c;             // 0..7
            short8 a  = *(const short8*)(qb  + (size_t)row * 64 + cg * 8);
            short8 a2 = *(const short8*)(q2b + (size_t)row * 64 + cg * 8);
            int cgm = (cg + row) & 7;
            *(short8*)&qs [row * 64 + cgm * 8] = a;
            *(short8*)&q2s[row * 64 + cgm * 8] = a2;
        }
    }
    __syncthreads();
    short8 bq[2][4], bq2[2][4];
    #pragma unroll
    for (int kstep = 0; kstep < 2; ++kstep) {
        const int gl = kstep * 4 + g;
        #pragma unroll
        for (int j = 0; j < 4; ++j) {
            int row = nq + j * 16 + s;
            int a = row * 64 + ((gl + row) & 7) * 8;
            bq[kstep][j]  = *(const short8*)&qs [a];
            bq2[kstep][j] = *(const short8*)&q2s[a];
        }
    }

    floatx4 zac[4];
    #pragma unroll
    for (int j = 0; j < 4; ++j)
        zac[j] = (floatx4)(0.0f);

    for (int tk = 0; tk <= qt; ++tk) {
        // ---- register prefetch (halved per-thread vs 4-wave version) ----
        short8 kf[2], k2f[2], vf[2];
        {
            const unsigned short* kb  = kh  + ((size_t)bh * 2048 + tk * 128) * 64;
            const unsigned short* k2b = k2h + ((size_t)bh * 2048 + tk * 128) * 64;
            const unsigned short* vb  = vt  + (size_t)bh * 131072 + tk * 128;
            const int krow = t >> 2;               // 0..127
            const int vd   = t >> 3;               // 0..63
            #pragma unroll
            for (int c = 0; c < 2; ++c) {
                int cg = (t & 3) * 2 + c;          // 0..7
                kf[c]  = *(const short8*)(kb  + (size_t)krow * 64 + cg * 8);
                k2f[c] = *(const short8*)(k2b + (size_t)krow * 64 + cg * 8);
                int cg16 = (t & 7) * 2 + c;        // 0..15
                vf[c]  = *(const short8*)(vb + (size_t)vd * 2048 + cg16 * 8);
            }
        }
        __syncthreads();   // b0: prev PV done (psq/vts); prev S done (ks/k2s); q-hoist done
        {
            const int krow = t >> 2;
            const int vd   = t >> 3;
            #pragma unroll
            for (int c = 0; c < 2; ++c) {
                int cg  = (t & 3) * 2 + c;
                int cgm = (cg + krow) & 7;
                *(short8*)&ks [krow * 64 + cgm * 8] = kf[c];
                *(short8*)&k2s[krow * 64 + cgm * 8] = k2f[c];
                int cg16  = (t & 7) * 2 + c;
                int cgm16 = (cg16 + vd) & 15;
                *(short8*)&vts[vd * 128 + cgm16 * 8] = vf[c];
            }
        }
        __syncthreads();   // b1: tiles visible

        // ---- S + P, i-outer (2 frags of 16 k-rows per wave) ----
        #pragma unroll
        for (int i = 0; i < 2; ++i) {
            floatx4 a1[4], a2[4];
            #pragma unroll
            for (int j = 0; j < 4; ++j) { a1[j] = (floatx4)(0.0f); a2[j] = (floatx4)(0.0f); }
            #pragma unroll
            for (int kstep = 0; kstep < 2; ++kstep) {
                const int gl = kstep * 4 + g;
                int row = mk + i * 16 + s;
                int a = row * 64 + ((gl + row) & 7) * 8;
                short8 ak  = *(const short8*)&ks [a];
                short8 ak2 = *(const short8*)&k2s[a];
                #pragma unroll
                for (int j = 0; j < 4; ++j) {
                    a1[j] = __builtin_amdgcn_mfma_f32_16x16x32_bf16(ak,  bq[kstep][j],  a1[j], 0, 0, 0);
                    a2[j] = __builtin_amdgcn_mfma_f32_16x16x32_bf16(ak2, bq2[kstep][j], a2[j], 0, 0, 0);
                }
            }
            // P-write for this i: psq region unread by anyone during the loop
            const int kl0   = mk + i * 16 + g * 4;
            const int chunk = kl0 >> 3;
            const int sub   = kl0 & 7;
            if (tk < qt) {
                #pragma unroll
                for (int j = 0; j < 4; ++j) {
                    const int ql = nq + j * 16 + s;
                    ushort4 pw;
                    pw.x = f2bf(a1[j][0] * a2[j][0]);
                    pw.y = f2bf(a1[j][1] * a2[j][1]);
                    pw.z = f2bf(a1[j][2] * a2[j][2]);
                    pw.w = f2bf(a1[j][3] * a2[j][3]);
                    *(ushort4*)&psq[ql * 128 + ((chunk + ql) & 15) * 8 + sub] = pw;
                }
            } else {
                #pragma unroll
                for (int j = 0; j < 4; ++j) {
                    const int ql = nq + j * 16 + s;
                    ushort4 pw;
                    pw.x = (kl0 + 0 <= ql) ? f2bf(a1[j][0] * a2[j][0]) : (unsigned short)0;
                    pw.y = (kl0 + 1 <= ql) ? f2bf(a1[j][1] * a2[j][1]) : (unsigned short)0;
                    pw.z = (kl0 + 2 <= ql) ? f2bf(a1[j][2] * a2[j][2]) : (unsigned short)0;
                    pw.w = (kl0 + 3 <= ql) ? f2bf(a1[j][3] * a2[j][3]) : (unsigned short)0;
                    *(ushort4*)&psq[ql * 128 + ((chunk + ql) & 15) * 8 + sub] = pw;
                }
            }
        }

        __syncthreads();   // b2: psq visible

        // ---- PV: z[q][d] += P[q][k] * vT[d][k] ; wave owns 16 q-rows ----
        const int wm0 = w * 16;
        #pragma unroll
        for (int kstep = 0; kstep < 4; ++kstep) {
            const int cbase = kstep * 4 + g;
            short8 ap, bv[4];
            {
                int q = wm0 + s;
                ap = *(const short8*)&psq[q * 128 + ((cbase + q) & 15) * 8];
            }
            #pragma unroll
            for (int jd = 0; jd < 4; ++jd) {
                int d = jd * 16 + s;
                bv[jd] = *(const short8*)&vts[d * 128 + ((cbase + d) & 15) * 8];
            }
            #pragma unroll
            for (int jd = 0; jd < 4; ++jd)
                zac[jd] = __builtin_amdgcn_mfma_f32_16x16x32_bf16(ap, bv[jd], zac[jd], 0, 0, 0);
        }
    }

    // ---- epilogue: z -> split bf16 [hi | lo] into zout[4096][2048] ----
    const int b = bh >> 4, h = bh & 15;
    const size_t zrow0 = (size_t)(b * TSEQ + qt * 128);
    #pragma unroll
    for (int j = 0; j < 4; ++j)
        #pragma unroll
        for (int r = 0; r < 4; ++r) {
            float zv = zac[j][r];
            unsigned short hi = f2bf(zv);
            unsigned short lo = f2bf(zv - bf2f(hi));
            size_t row = zrow0 + w * 16 + g * 4 + r;
            int col = h * 64 + j * 16 + s;
            zout[row * 2048 + col]        = hi;
            zout[row * 2048 + 1024 + col] = lo;
        }
}

// ---------------------------------------------------------------------------
extern "C" void kernel_launch(void* const* d_in, const int* in_sizes, int n_in,
                              void* d_out, int out_size, void* d_ws, size_t ws_size,
                              hipStream_t stream)
{
    const float* x     = (const float*)d_in[0];
    const float* Wq    = (const float*)d_in[1];
    const float* Wk    = (const float*)d_in[2];
    const float* Wq2   = (const float*)d_in[3];
    const float* Wk2   = (const float*)d_in[4];
    const float* Wv    = (const float*)d_in[5];
    const float* Wproj = (const float*)d_in[6];

    // workspace (bytes):
    //   Xp    bf16 [4096][2048] (x-split, later z-split) @ 0          (16,777,216)
    //   Wp    bf16 [6144][2048]                          @ 16,777,216 (25,165,824)
    //         rows [0,1024)    = Wproj [hi|lo]
    //         rows [1024,6144) = Wq,Wk,Wq2,Wk2 (head-interleaved), Wv [hi|hi]
    //   heads bf16 4x[32][2048][64] (q,k,q2,k2)          @ 41,943,040 (33,554,432)
    //   vt    bf16 [32][64][2048]                        @ 75,497,472 ( 8,388,608)
    unsigned short* Xp    = (unsigned short*)d_ws;
    unsigned short* Wp    = (unsigned short*)((char*)d_ws + 16777216);
    unsigned short* heads = (unsigned short*)((char*)d_ws + 41943040);
    unsigned short* vt    = (unsigned short*)((char*)d_ws + 75497472);

    const size_t HS = (size_t)32 * 2048 * 64;
    unsigned short* qh  = heads;
    unsigned short* kh  = heads + 1 * HS;
    unsigned short* q2h = heads + 2 * HS;
    unsigned short* k2h = heads + 3 * HS;

    pack_all_kernel<<<10240, 256, 0, stream>>>(x, Wproj, Wq, Wk, Wq2, Wk2, Wv, Xp, Wp);
    gemm_qkv<<<dim3(16, 16), 512, 0, stream>>>(Xp, Wp + (size_t)1024 * 2048, heads, vt);
    attn_mfma<<<dim3(16, 32), 512, 0, stream>>>(qh, q2h, kh, k2h, vt, Xp);
    gemm_proj<<<dim3(32, 8), 256, 0, stream>>>(Xp, Wp, (float*)d_out);
}

// Round 7
// 286.520 us; speedup vs baseline: 1.2257x; 1.2257x over previous
//
#include <hip/hip_runtime.h>
#include <hip/hip_bf16.h>

#define TSEQ 2048
#define NHEAD 16
#define DM 1024
#define NBATCH 2
#define MTOK (NBATCH * TSEQ)   // 4096

typedef __attribute__((ext_vector_type(8))) short short8;
typedef __attribute__((ext_vector_type(4))) float floatx4;
typedef __attribute__((address_space(1))) const void gvoid;
typedef __attribute__((address_space(3))) void lvoid;

static __device__ __forceinline__ unsigned short f2bf(float f) {
    unsigned int u = __float_as_uint(f);
    return (unsigned short)((u + 0x7fffu + ((u >> 16) & 1u)) >> 16);
}
static __device__ __forceinline__ float bf2f(unsigned short h) {
    return __uint_as_float(((unsigned int)h) << 16);
}

// ---------------------------------------------------------------------------
// Pack x and the 6 weight matrices to split bf16 rows.
//   x      -> [hi(1024) | lo(1024)]
//   Wproj  -> [hi | lo]            (3-term proj GEMM needs lo)
//   Wq..Wv -> [hi | hi] DUPLICATED (qkv GEMM becomes one plain K=2048 GEMM)
//   Wq,Wk,Wq2,Wk2 rows additionally PER-HEAD INTERLEAVED:
//     d<32 -> (d>>3)*16 + (d&7) ; d>=32 -> ((d-32)>>3)*16 + 8 + (d&7)
//   so each 16-col C-fragment holds RoPE pairs at lanes cc / cc^8
//   (lane-local RoPE via shfl_xor; q and k share the permutation so QK^T
//   is invariant and attention is unchanged; Wv stays plain).
// blocks [0,4096) -> x ; [4096,10240) -> weights (1024 blocks each).
// ---------------------------------------------------------------------------
__global__ __launch_bounds__(256)
void pack_all_kernel(const float* __restrict__ x,
                     const float* __restrict__ w0, const float* __restrict__ w1,
                     const float* __restrict__ w2, const float* __restrict__ w3,
                     const float* __restrict__ w4, const float* __restrict__ w5,
                     unsigned short* __restrict__ dstX, unsigned short* __restrict__ dstW)
{
    const float* src;
    unsigned short* dst;
    int gid;
    bool dup = false, ilv = false;
    if (blockIdx.x < 4096) {
        src = x; dst = dstX;
        gid = blockIdx.x * 256 + threadIdx.x;
    } else {
        int wi = (blockIdx.x - 4096) >> 10;
        const float* srcs[6] = {w0, w1, w2, w3, w4, w5};
        src = srcs[wi];
        dst = dstW + (size_t)wi * 1024 * 2048;
        gid = ((blockIdx.x - 4096) & 1023) * 256 + threadIdx.x;
        dup = (wi != 0);
        ilv = (wi >= 1 && wi <= 4);   // Wq, Wk, Wq2, Wk2
    }
    int e   = gid * 4;
    int row = e >> 10;
    int col = e & 1023;
    float4 f = *(const float4*)(src + (size_t)row * 1024 + col);
    ushort4 hi, lo;
    hi.x = f2bf(f.x); lo.x = f2bf(f.x - bf2f(hi.x));
    hi.y = f2bf(f.y); lo.y = f2bf(f.y - bf2f(hi.y));
    hi.z = f2bf(f.z); lo.z = f2bf(f.z - bf2f(hi.z));
    hi.w = f2bf(f.w); lo.w = f2bf(f.w - bf2f(hi.w));
    int drow = row;
    if (ilv) {
        int hh = row >> 6, d = row & 63;
        int dd = (d < 32) ? ((d >> 3) * 16 + (d & 7))
                          : (((d - 32) >> 3) * 16 + 8 + (d & 7));
        drow = hh * 64 + dd;
    }
    *(ushort4*)(dst + (size_t)drow * 2048 + col)        = hi;
    *(ushort4*)(dst + (size_t)drow * 2048 + 1024 + col) = dup ? hi : lo;
}

// ---------------------------------------------------------------------------
// qkv GEMM (round-1 version, UNCHANGED):
//   C[4096][5120] = Xp[4096][2048] . Bdup[5120][2048]^T   (plain bf16 GEMM)
// Tile 256x320, K-tile 64 (two kh of 32), 512 threads = 8 waves, 2M x 4N.
// ---------------------------------------------------------------------------
#define VMW(N) asm volatile("s_waitcnt vmcnt(" #N ")" ::: "memory")
#define LGKM0  asm volatile("s_waitcnt lgkmcnt(0)" ::: "memory")

__global__ __launch_bounds__(512, 2)
void gemm_qkv(const unsigned short* __restrict__ Ap,
              const unsigned short* __restrict__ Bp,
              unsigned short* __restrict__ Ch, unsigned short* __restrict__ Vt)
{
    __shared__ __align__(16) unsigned short A0s[2][8192];    // [256][32] each
    __shared__ __align__(16) unsigned short A1s[2][8192];
    __shared__ __align__(16) unsigned short B0s[2][10240];   // [320][32] each
    __shared__ __align__(16) unsigned short B1s[2][10240];

    const int t    = threadIdx.x;
    const int lane = t & 63;
    const int w    = t >> 6;
    const int wm   = w >> 2;          // M-half (0..1): 128 rows
    const int wn   = w & 3;           // N-quarter (0..3): 80 cols
    const int s    = lane & 15;
    const int g    = (lane >> 4) & 3;
    const int row0 = blockIdx.x * 256;
    const int col0 = blockIdx.y * 320;

    // read-side swizzled offsets (element units, 32-wide rows)
    const int cofs  = ((g ^ ((lane >> 1) & 3)) << 3);
    const int addrA = (wm * 128 + s) * 32 + cofs;   // + ii*512
    const int addrB = (wn * 80 + s) * 32 + cofs;    // + nf*512

    // stage-side pre-swizzled global source base (logical chunk per thread)
    const int alc = (t & 3) ^ ((t >> 3) & 3);
    const unsigned short* Ag = Ap + (size_t)(row0 + (t >> 2)) * 2048 + alc * 8;
    const unsigned short* Bg = Bp + (size_t)(col0 + (t >> 2)) * 2048 + alc * 8;

#define STAGE_A(dst, kofs) {                                                                              \
    __builtin_amdgcn_global_load_lds((gvoid*)(Ag + (kofs)),              (lvoid*)((dst) + t * 8),        16, 0, 0); \
    __builtin_amdgcn_global_load_lds((gvoid*)(Ag + (kofs) + 128 * 2048), (lvoid*)((dst) + 4096 + t * 8), 16, 0, 0); }

#define STAGE_B(dst, kofs) {                                                                              \
    __builtin_amdgcn_global_load_lds((gvoid*)(Bg + (kofs)),              (lvoid*)((dst) + t * 8),        16, 0, 0); \
    __builtin_amdgcn_global_load_lds((gvoid*)(Bg + (kofs) + 128 * 2048), (lvoid*)((dst) + 4096 + t * 8), 16, 0, 0); \
    if (t < 256)                                                                                          \
    __builtin_amdgcn_global_load_lds((gvoid*)(Bg + (kofs) + 256 * 2048), (lvoid*)((dst) + 8192 + t * 8), 16, 0, 0); }

    floatx4 acc[8][5];
    #pragma unroll
    for (int ii = 0; ii < 8; ++ii)
        #pragma unroll
        for (int nf = 0; nf < 5; ++nf)
            acc[ii][nf] = (floatx4)(0.0f);

    // ---- prologue: tile0 (kh0,kh1) and tile1 (kh0) ----
    STAGE_A(A0s[0], 0);
    STAGE_B(B0s[0], 0);
    STAGE_A(A1s[0], 32);
    STAGE_B(B1s[0], 32);
    STAGE_A(A0s[1], 64);
    STAGE_B(B0s[1], 64);
    VMW(4);                       // tile0 fully landed (newest 4-5 = tile1 kh0)
    __builtin_amdgcn_s_barrier();
    __builtin_amdgcn_sched_barrier(0);

#define MFMA_CLUSTER(IOFS)                                                                      \
    __builtin_amdgcn_s_setprio(1);                                                              \
    _Pragma("unroll")                                                                           \
    for (int ii = 0; ii < 4; ++ii)                                                              \
        _Pragma("unroll")                                                                       \
        for (int nf = 0; nf < 5; ++nf)                                                          \
            acc[(IOFS) + ii][nf] = __builtin_amdgcn_mfma_f32_16x16x32_bf16(af[ii], bf[nf], acc[(IOFS) + ii][nf], 0, 0, 0); \
    __builtin_amdgcn_s_setprio(0);

#define TILE_BODY(TAU, DO12, DO34, W2, W4)                                                      \
{                                                                                               \
    const int cur_ = (TAU) & 1;                                                                 \
    const unsigned short* a0k = A0s[cur_];                                                      \
    const unsigned short* a1k = A1s[cur_];                                                      \
    const unsigned short* b0k = B0s[cur_];                                                      \
    const unsigned short* b1k = B1s[cur_];                                                      \
    short8 af[4], bf[5];                                                                        \
    /* ---- p1: kh0, M-half0 + B-kh0 read ; stage (TAU+1) A-kh1 ---- */                         \
    _Pragma("unroll")                                                                           \
    for (int ii = 0; ii < 4; ++ii) af[ii] = *(const short8*)&a0k[addrA + ii * 512];             \
    _Pragma("unroll")                                                                           \
    for (int nf = 0; nf < 5; ++nf) bf[nf] = *(const short8*)&b0k[addrB + nf * 512];             \
    if (DO12) STAGE_A(A1s[cur_ ^ 1], ((TAU) + 1) * 64 + 32);                                    \
    LGKM0;                                                                                      \
    __builtin_amdgcn_s_barrier();                                                               \
    __builtin_amdgcn_sched_barrier(0);                                                          \
    MFMA_CLUSTER(0)                                                                             \
    /* ---- p2: kh0, M-half1 ; stage (TAU+1) B-kh1 ; vmcnt ---- */                              \
    _Pragma("unroll")                                                                           \
    for (int ii = 0; ii < 4; ++ii) af[ii] = *(const short8*)&a0k[addrA + (ii + 4) * 512];       \
    if (DO12) STAGE_B(B1s[cur_ ^ 1], ((TAU) + 1) * 64 + 32);                                    \
    LGKM0;                                                                                      \
    W2;                                                                                         \
    __builtin_amdgcn_s_barrier();                                                               \
    __builtin_amdgcn_sched_barrier(0);                                                          \
    MFMA_CLUSTER(4)                                                                             \
    /* ---- p3: kh1, M-half0 + B-kh1 read ; stage (TAU+2) A-kh0 ---- */                         \
    _Pragma("unroll")                                                                           \
    for (int ii = 0; ii < 4; ++ii) af[ii] = *(const short8*)&a1k[addrA + ii * 512];             \
    _Pragma("unroll")                                                                           \
    for (int nf = 0; nf < 5; ++nf) bf[nf] = *(const short8*)&b1k[addrB + nf * 512];             \
    if (DO34) STAGE_A(A0s[cur_], ((TAU) + 2) * 64);                                             \
    LGKM0;                                                                                      \
    __builtin_amdgcn_s_barrier();                                                               \
    __builtin_amdgcn_sched_barrier(0);                                                          \
    MFMA_CLUSTER(0)                                                                             \
    /* ---- p4: kh1, M-half1 ; stage (TAU+2) B-kh0 ; vmcnt ---- */                              \
    _Pragma("unroll")                                                                           \
    for (int ii = 0; ii < 4; ++ii) af[ii] = *(const short8*)&a1k[addrA + (ii + 4) * 512];       \
    if (DO34) STAGE_B(B0s[cur_], ((TAU) + 2) * 64);                                             \
    LGKM0;                                                                                      \
    W4;                                                                                         \
    __builtin_amdgcn_s_barrier();                                                               \
    __builtin_amdgcn_sched_barrier(0);                                                          \
    MFMA_CLUSTER(4)                                                                             \
}

    #pragma unroll 2
    for (int tau = 0; tau < 30; ++tau)
        TILE_BODY(tau, 1, 1, VMW(8), VMW(8));
    TILE_BODY(30, 1, 0, VMW(8), VMW(4));
    TILE_BODY(31, 0, 0, VMW(0), ((void)0));

#undef TILE_BODY
#undef MFMA_CLUSTER
#undef STAGE_A
#undef STAGE_B

    // ---- epilogue: lane-local RoPE (+1/64 q-scale); V transposed ----
    const int cr = (lane >> 4) * 4;
    const int cc = lane & 15;
    const int rwbase = row0 + wm * 128;
    const float L2C = -0.41524101186092029f;  // -log2(10000)/32

    #pragma unroll
    for (int nf = 0; nf < 5; ++nf) {
        const int cg = col0 + wn * 80 + nf * 16;  // global col of this frag
        const int p  = cg >> 10;                  // 0=q 1=k 2=q2 3=k2 4=v
        const int h  = (cg >> 6) & 15;
        const int f  = (cg >> 4) & 3;
        if (p < 4) {
            const float sc  = (p == 0 || p == 2) ? 0.015625f : 1.0f;
            const float inv = exp2f((float)(f * 8 + (cc & 7)) * L2C);
            unsigned short* hp = Ch + (size_t)p * 4194304;
            #pragma unroll
            for (int ii = 0; ii < 8; ++ii) {
                int r0  = rwbase + ii * 16 + cr;
                int bhi = ((r0 >> 11) << 4) + h;
                size_t base = ((size_t)bhi * 2048 + (r0 & 2047)) * 64;
                #pragma unroll
                for (int rr = 0; rr < 4; ++rr) {
                    float tt = (float)((r0 + rr) & 2047);
                    float s0, c0;
                    __sincosf(tt * inv, &s0, &c0);
                    float x  = acc[ii][nf][rr];
                    float xp = __shfl_xor(x, 8, 64);
                    float y  = (cc < 8) ? (x * c0 + xp * s0) : (x * c0 - xp * s0);
                    hp[base + (size_t)rr * 64 + (f * 16 + cc)] = f2bf(y * sc);
                }
            }
        } else {
            #pragma unroll
            for (int ii = 0; ii < 8; ++ii) {
                int r0  = rwbase + ii * 16 + cr;
                int bhi = ((r0 >> 11) << 4) + h;
                int d   = f * 16 + cc;
                ushort4 o;
                o.x = f2bf(acc[ii][nf][0]); o.y = f2bf(acc[ii][nf][1]);
                o.z = f2bf(acc[ii][nf][2]); o.w = f2bf(acc[ii][nf][3]);
                *(ushort4*)(Vt + ((size_t)bhi * 64 + d) * 2048 + (r0 & 2047)) = o;
            }
        }
    }
}

// ---------------------------------------------------------------------------
// Output projection: C = (hiA+loA)*hiB^T + hiA*loB^T (3-term), fp32 out.
// 128x128 template (round-5, UNCHANGED): grid (32,8) = 256 blocks = 1/CU,
// 4 waves (wave-tile 64x64), 48 MFMA : 16 ds_reads per K-step, 32 KB LDS.
// ---------------------------------------------------------------------------
__global__ __launch_bounds__(256)
void gemm_proj(const unsigned short* __restrict__ Ap,
               const unsigned short* __restrict__ Bp,
               float* __restrict__ Cf)
{
    __shared__ __align__(16) unsigned short Ah[128 * 32];
    __shared__ __align__(16) unsigned short Al[128 * 32];
    __shared__ __align__(16) unsigned short Bh[128 * 32];
    __shared__ __align__(16) unsigned short Bl[128 * 32];

    const int t    = threadIdx.x;
    const int lane = t & 63;
    const int s    = lane & 15;
    const int row0 = blockIdx.x * 128;
    const int col0 = blockIdx.y * 128;
    const int m0   = ((t >> 6) >> 1) * 64;
    const int n0   = ((t >> 6) & 1) * 64;

    floatx4 acc[4][4];
    #pragma unroll
    for (int i = 0; i < 4; ++i)
        #pragma unroll
        for (int j = 0; j < 4; ++j)
            acc[i][j] = (floatx4)(0.0f);

    const int sr  = t >> 2;
    const int skx = ((t & 3) ^ ((t >> 3) & 3)) * 8;
    char* dA  = (char*)Ah + (size_t)t * 16;
    char* dAl = (char*)Al + (size_t)t * 16;
    char* dB  = (char*)Bh + (size_t)t * 16;
    char* dBl = (char*)Bl + (size_t)t * 16;
    const size_t arow = (size_t)(row0 + sr) * 2048 + skx;
    const size_t brow = (size_t)(col0 + sr) * 2048 + skx;

    #define ISSUE(k0)                                                                         \
    {                                                                                         \
        const unsigned short* ga = Ap + arow + (k0);                                          \
        const unsigned short* gb = Bp + brow + (k0);                                          \
        __builtin_amdgcn_global_load_lds((gvoid*)ga,                 (lvoid*)dA,          16, 0, 0); \
        __builtin_amdgcn_global_load_lds((gvoid*)(ga + 64*2048),     (lvoid*)(dA + 4096), 16, 0, 0); \
        __builtin_amdgcn_global_load_lds((gvoid*)(ga + 1024),        (lvoid*)dAl,         16, 0, 0); \
        __builtin_amdgcn_global_load_lds((gvoid*)(ga + 1024+64*2048),(lvoid*)(dAl + 4096),16, 0, 0); \
        __builtin_amdgcn_global_load_lds((gvoid*)gb,                 (lvoid*)dB,          16, 0, 0); \
        __builtin_amdgcn_global_load_lds((gvoid*)(gb + 64*2048),     (lvoid*)(dB + 4096), 16, 0, 0); \
        __builtin_amdgcn_global_load_lds((gvoid*)(gb + 1024),        (lvoid*)dBl,         16, 0, 0); \
        __builtin_amdgcn_global_load_lds((gvoid*)(gb + 1024+64*2048),(lvoid*)(dBl + 4096),16, 0, 0); \
    }

    const int cofs = (((lane >> 4) ^ ((lane >> 1) & 3)) << 3);

    ISSUE(0);
    for (int ks = 0; ks < 32; ++ks) {
        __syncthreads();
        short8 ahf[4], alf[4], bhf[4], blf[4];
        #pragma unroll
        for (int i = 0; i < 4; ++i) {
            int ra = (m0 + i * 16 + s) * 32 + cofs;
            ahf[i] = *(const short8*)&Ah[ra];
            alf[i] = *(const short8*)&Al[ra];
        }
        #pragma unroll
        for (int j = 0; j < 4; ++j) {
            int rb = (n0 + j * 16 + s) * 32 + cofs;
            bhf[j] = *(const short8*)&Bh[rb];
            blf[j] = *(const short8*)&Bl[rb];
        }
        #pragma unroll
        for (int i = 0; i < 4; ++i)
            #pragma unroll
            for (int j = 0; j < 4; ++j) {
                acc[i][j] = __builtin_amdgcn_mfma_f32_16x16x32_bf16(ahf[i], bhf[j], acc[i][j], 0, 0, 0);
                acc[i][j] = __builtin_amdgcn_mfma_f32_16x16x32_bf16(alf[i], bhf[j], acc[i][j], 0, 0, 0);
                acc[i][j] = __builtin_amdgcn_mfma_f32_16x16x32_bf16(ahf[i], blf[j], acc[i][j], 0, 0, 0);
            }
        __syncthreads();
        if (ks + 1 < 32) ISSUE((ks + 1) * 32);
    }
    #undef ISSUE

    const int cr = (lane >> 4) * 4;
    const int cc = lane & 15;
    #pragma unroll
    for (int i = 0; i < 4; ++i)
        #pragma unroll
        for (int j = 0; j < 4; ++j) {
            int r = row0 + m0 + i * 16 + cr;
            int c = col0 + n0 + j * 16 + cc;
            #pragma unroll
            for (int rr = 0; rr < 4; ++rr)
                Cf[(size_t)(r + rr) * 1024 + c] = acc[i][j][rr];
        }
}

// ---------------------------------------------------------------------------
// MFMA bilinear causal attention — 4-wave version (reverted from 8-wave) with
// XCD-AWARE BLOCK SWIZZLE (T1). Grid is 1-D, 512 blocks = 64/XCD exactly.
// HW assigns XCDs round-robin on linear block id, so:
//   xcd = bid & 7, slot = bid >> 3, bh = xcd*4 + (slot>>4), x = slot & 15
// gives each XCD 4 COMPLETE heads x 16 q-tiles. Its K/K2/V working set is
// 4 x 768 KB = 3 MB < 4 MB L2, so K/V bytes are fetched ~once per XCD
// instead of ~8x (measured 188 MB FETCH on the unswizzled version vs 42 MB
// logical inputs). Heavy/light qt pairing preserved per head.
// LDS 80 KB, 2 blocks/CU; psq overlays qs/q2s; 3 barriers/iter.
// ---------------------------------------------------------------------------
__global__ __launch_bounds__(256, 2)
void attn_mfma(const unsigned short* __restrict__ qh, const unsigned short* __restrict__ q2h,
               const unsigned short* __restrict__ kh, const unsigned short* __restrict__ k2h,
               const unsigned short* __restrict__ vt, unsigned short* __restrict__ zout)
{
    __shared__ __align__(16) unsigned short smem[40960];   // 80 KB
    unsigned short* qs  = smem;              // [128][64] rot8 (init only)
    unsigned short* q2s = smem + 8192;
    unsigned short* psq = smem;              // [128][128] rot16, overlays qs/q2s
    unsigned short* ks  = smem + 16384;      // [128][64] rot8
    unsigned short* k2s = smem + 24576;
    unsigned short* vts = smem + 32768;      // [64][128] rot16

    const int bid  = blockIdx.x;
    const int xcd  = bid & 7;
    const int slot = bid >> 3;
    const int bh   = xcd * 4 + (slot >> 4);
    const int qx   = slot & 15;
    const int qt = (bh < 16) ? (15 - qx) : qx;  // pair heavy+light
    const int t  = threadIdx.x;
    const int lane = t & 63;
    const int w    = t >> 6;
    const int s    = lane & 15;
    const int g    = lane >> 4;
    const int m0   = (w >> 1) * 64;   // k-split
    const int n0   = (w & 1) * 64;    // q-split

    // ---- stage q, q2 once, then hoist frags to registers ----
    {
        const unsigned short* qb  = qh  + ((size_t)bh * 2048 + qt * 128) * 64;
        const unsigned short* q2b = q2h + ((size_t)bh * 2048 + qt * 128) * 64;
        const int row = t >> 1;
        #pragma unroll
        for (int c = 0; c < 4; ++c) {
            int cg  = (t & 1) * 4 + c;
            short8 a  = *(const short8*)(qb  + (size_t)row * 64 + cg * 8);
            short8 a2 = *(const short8*)(q2b + (size_t)row * 64 + cg * 8);
            int cgm = (cg + row) & 7;
            *(short8*)&qs [row * 64 + cgm * 8] = a;
            *(short8*)&q2s[row * 64 + cgm * 8] = a2;
        }
    }
    __syncthreads();
    short8 bq[2][4], bq2[2][4];
    #pragma unroll
    for (int kstep = 0; kstep < 2; ++kstep) {
        const int gl = kstep * 4 + g;
        #pragma unroll
        for (int j = 0; j < 4; ++j) {
            int row = n0 + j * 16 + s;
            int a = row * 64 + ((gl + row) & 7) * 8;
            bq[kstep][j]  = *(const short8*)&qs [a];
            bq2[kstep][j] = *(const short8*)&q2s[a];
        }
    }

    floatx4 zac[2][4];
    #pragma unroll
    for (int i = 0; i < 2; ++i)
        #pragma unroll
        for (int j = 0; j < 4; ++j)
            zac[i][j] = (floatx4)(0.0f);

    for (int tk = 0; tk <= qt; ++tk) {
        // ---- register prefetch ----
        short8 kf[4], k2f[4], vf[4];
        {
            const unsigned short* kb  = kh  + ((size_t)bh * 2048 + tk * 128) * 64;
            const unsigned short* k2b = k2h + ((size_t)bh * 2048 + tk * 128) * 64;
            const unsigned short* vb  = vt  + (size_t)bh * 131072 + tk * 128;
            const int krow = t >> 1;
            const int vd   = t >> 2;
            #pragma unroll
            for (int c = 0; c < 4; ++c) {
                int cg = (t & 1) * 4 + c;
                kf[c]  = *(const short8*)(kb  + (size_t)krow * 64 + cg * 8);
                k2f[c] = *(const short8*)(k2b + (size_t)krow * 64 + cg * 8);
                int cg16 = 4 * (t & 3) + c;
                vf[c]  = *(const short8*)(vb + (size_t)vd * 2048 + cg16 * 8);
            }
        }
        __syncthreads();   // b0: prev PV done (psq/vts); prev S done (ks/k2s); q-hoist done
        {
            const int krow = t >> 1;
            const int vd   = t >> 2;
            #pragma unroll
            for (int c = 0; c < 4; ++c) {
                int cg  = (t & 1) * 4 + c;
                int cgm = (cg + krow) & 7;
                *(short8*)&ks [krow * 64 + cgm * 8] = kf[c];
                *(short8*)&k2s[krow * 64 + cgm * 8] = k2f[c];
                int cg16  = 4 * (t & 3) + c;
                int cgm16 = (cg16 + vd) & 15;
                *(short8*)&vts[vd * 128 + cgm16 * 8] = vf[c];
            }
        }
        __syncthreads();   // b1: tiles visible

        // ---- S + P, i-outer (a1/a2 footprint = one i at a time) ----
        #pragma unroll
        for (int i = 0; i < 4; ++i) {
            floatx4 a1[4], a2[4];
            #pragma unroll
            for (int j = 0; j < 4; ++j) { a1[j] = (floatx4)(0.0f); a2[j] = (floatx4)(0.0f); }
            #pragma unroll
            for (int kstep = 0; kstep < 2; ++kstep) {
                const int gl = kstep * 4 + g;
                int row = m0 + i * 16 + s;
                int a = row * 64 + ((gl + row) & 7) * 8;
                short8 ak  = *(const short8*)&ks [a];
                short8 ak2 = *(const short8*)&k2s[a];
                #pragma unroll
                for (int j = 0; j < 4; ++j) {
                    a1[j] = __builtin_amdgcn_mfma_f32_16x16x32_bf16(ak,  bq[kstep][j],  a1[j], 0, 0, 0);
                    a2[j] = __builtin_amdgcn_mfma_f32_16x16x32_bf16(ak2, bq2[kstep][j], a2[j], 0, 0, 0);
                }
            }
            // P-write for this i: psq region unread by anyone during the loop
            const int kl0   = m0 + i * 16 + g * 4;
            const int chunk = kl0 >> 3;
            const int sub   = kl0 & 7;
            if (tk < qt) {
                #pragma unroll
                for (int j = 0; j < 4; ++j) {
                    const int ql = n0 + j * 16 + s;
                    ushort4 pw;
                    pw.x = f2bf(a1[j][0] * a2[j][0]);
                    pw.y = f2bf(a1[j][1] * a2[j][1]);
                    pw.z = f2bf(a1[j][2] * a2[j][2]);
                    pw.w = f2bf(a1[j][3] * a2[j][3]);
                    *(ushort4*)&psq[ql * 128 + ((chunk + ql) & 15) * 8 + sub] = pw;
                }
            } else {
                #pragma unroll
                for (int j = 0; j < 4; ++j) {
                    const int ql = n0 + j * 16 + s;
                    ushort4 pw;
                    pw.x = (kl0 + 0 <= ql) ? f2bf(a1[j][0] * a2[j][0]) : (unsigned short)0;
                    pw.y = (kl0 + 1 <= ql) ? f2bf(a1[j][1] * a2[j][1]) : (unsigned short)0;
                    pw.z = (kl0 + 2 <= ql) ? f2bf(a1[j][2] * a2[j][2]) : (unsigned short)0;
                    pw.w = (kl0 + 3 <= ql) ? f2bf(a1[j][3] * a2[j][3]) : (unsigned short)0;
                    *(ushort4*)&psq[ql * 128 + ((chunk + ql) & 15) * 8 + sub] = pw;
                }
            }
        }

        __syncthreads();   // b2: psq visible

        // ---- PV: z[q][d] += P[q][k] * vT[d][k] ----
        const int wm0 = w * 32;
        #pragma unroll
        for (int kstep = 0; kstep < 4; ++kstep) {
            const int cbase = kstep * 4 + g;
            short8 ap[2], bv[4];
            #pragma unroll
            for (int i2 = 0; i2 < 2; ++i2) {
                int q = wm0 + i2 * 16 + s;
                ap[i2] = *(const short8*)&psq[q * 128 + ((cbase + q) & 15) * 8];
            }
            #pragma unroll
            for (int jd = 0; jd < 4; ++jd) {
                int d = jd * 16 + s;
                bv[jd] = *(const short8*)&vts[d * 128 + ((cbase + d) & 15) * 8];
            }
            #pragma unroll
            for (int i2 = 0; i2 < 2; ++i2)
                #pragma unroll
                for (int jd = 0; jd < 4; ++jd)
                    zac[i2][jd] = __builtin_amdgcn_mfma_f32_16x16x32_bf16(ap[i2], bv[jd], zac[i2][jd], 0, 0, 0);
        }
    }

    // ---- epilogue: z -> split bf16 [hi | lo] into zout[4096][2048] ----
    const int b = bh >> 4, h = bh & 15;
    const size_t zrow0 = (size_t)(b * TSEQ + qt * 128);
    #pragma unroll
    for (int i2 = 0; i2 < 2; ++i2)
        #pragma unroll
        for (int j = 0; j < 4; ++j)
            #pragma unroll
            for (int r = 0; r < 4; ++r) {
                float zv = zac[i2][j][r];
                unsigned short hi = f2bf(zv);
                unsigned short lo = f2bf(zv - bf2f(hi));
                size_t row = zrow0 + w * 32 + i2 * 16 + g * 4 + r;
                int col = h * 64 + j * 16 + s;
                zout[row * 2048 + col]        = hi;
                zout[row * 2048 + 1024 + col] = lo;
            }
}

// ---------------------------------------------------------------------------
extern "C" void kernel_launch(void* const* d_in, const int* in_sizes, int n_in,
                              void* d_out, int out_size, void* d_ws, size_t ws_size,
                              hipStream_t stream)
{
    const float* x     = (const float*)d_in[0];
    const float* Wq    = (const float*)d_in[1];
    const float* Wk    = (const float*)d_in[2];
    const float* Wq2   = (const float*)d_in[3];
    const float* Wk2   = (const float*)d_in[4];
    const float* Wv    = (const float*)d_in[5];
    const float* Wproj = (const float*)d_in[6];

    // workspace (bytes):
    //   Xp    bf16 [4096][2048] (x-split, later z-split) @ 0          (16,777,216)
    //   Wp    bf16 [6144][2048]                          @ 16,777,216 (25,165,824)
    //         rows [0,1024)    = Wproj [hi|lo]
    //         rows [1024,6144) = Wq,Wk,Wq2,Wk2 (head-interleaved), Wv [hi|hi]
    //   heads bf16 4x[32][2048][64] (q,k,q2,k2)          @ 41,943,040 (33,554,432)
    //   vt    bf16 [32][64][2048]                        @ 75,497,472 ( 8,388,608)
    unsigned short* Xp    = (unsigned short*)d_ws;
    unsigned short* Wp    = (unsigned short*)((char*)d_ws + 16777216);
    unsigned short* heads = (unsigned short*)((char*)d_ws + 41943040);
    unsigned short* vt    = (unsigned short*)((char*)d_ws + 75497472);

    const size_t HS = (size_t)32 * 2048 * 64;
    unsigned short* qh  = heads;
    unsigned short* kh  = heads + 1 * HS;
    unsigned short* q2h = heads + 2 * HS;
    unsigned short* k2h = heads + 3 * HS;

    pack_all_kernel<<<10240, 256, 0, stream>>>(x, Wproj, Wq, Wk, Wq2, Wk2, Wv, Xp, Wp);
    gemm_qkv<<<dim3(16, 16), 512, 0, stream>>>(Xp, Wp + (size_t)1024 * 2048, heads, vt);
    attn_mfma<<<512, 256, 0, stream>>>(qh, q2h, kh, k2h, vt, Xp);
    gemm_proj<<<dim3(32, 8), 256, 0, stream>>>(Xp, Wp, (float*)d_out);
}

// Round 8
// 246.208 us; speedup vs baseline: 1.4264x; 1.1637x over previous
//
#include <hip/hip_runtime.h>
#include <hip/hip_bf16.h>

#define TSEQ 2048
#define NHEAD 16
#define DM 1024
#define NBATCH 2
#define MTOK (NBATCH * TSEQ)   // 4096

typedef __attribute__((ext_vector_type(8))) short short8;
typedef __attribute__((ext_vector_type(4))) float floatx4;
typedef __attribute__((address_space(1))) const void gvoid;
typedef __attribute__((address_space(3))) void lvoid;

static __device__ __forceinline__ unsigned short f2bf(float f) {
    unsigned int u = __float_as_uint(f);
    return (unsigned short)((u + 0x7fffu + ((u >> 16) & 1u)) >> 16);
}
static __device__ __forceinline__ float bf2f(unsigned short h) {
    return __uint_as_float(((unsigned int)h) << 16);
}

// ---------------------------------------------------------------------------
// Pack x and the 6 weight matrices to split bf16 rows.
//   x      -> [hi(1024) | (lo half DEAD — qkv is now 1-term hi-only and attn
//             overwrites Xp before proj reads it; skip the write)]
//   Wproj  -> [hi | lo]            (3-term proj GEMM needs lo)
//   Wq..Wv -> [hi | dead]          (qkv reads only cols 0..1023)
//   Wq,Wk,Wq2,Wk2 rows additionally PER-HEAD INTERLEAVED:
//     d<32 -> (d>>3)*16 + (d&7) ; d>=32 -> ((d-32)>>3)*16 + 8 + (d&7)
//   so each 16-col C-fragment holds RoPE pairs at lanes cc / cc^8.
//   Rationale for 1-term qkv: heads/vt are stored as SINGLE bf16 anyway
//   (2^-9 rel storage rounding); dropping the x-lo GEMM term adds the same
//   ~1.1e-3 relative error — total grows ~sqrt(2), absmax stays << thr.
// blocks [0,4096) -> x ; [4096,10240) -> weights (1024 blocks each).
// ---------------------------------------------------------------------------
__global__ __launch_bounds__(256)
void pack_all_kernel(const float* __restrict__ x,
                     const float* __restrict__ w0, const float* __restrict__ w1,
                     const float* __restrict__ w2, const float* __restrict__ w3,
                     const float* __restrict__ w4, const float* __restrict__ w5,
                     unsigned short* __restrict__ dstX, unsigned short* __restrict__ dstW)
{
    const float* src;
    unsigned short* dst;
    int gid;
    bool wlo = false, ilv = false;
    if (blockIdx.x < 4096) {
        src = x; dst = dstX;
        gid = blockIdx.x * 256 + threadIdx.x;
    } else {
        int wi = (blockIdx.x - 4096) >> 10;
        const float* srcs[6] = {w0, w1, w2, w3, w4, w5};
        src = srcs[wi];
        dst = dstW + (size_t)wi * 1024 * 2048;
        gid = ((blockIdx.x - 4096) & 1023) * 256 + threadIdx.x;
        wlo = (wi == 0);              // only Wproj needs the lo half
        ilv = (wi >= 1 && wi <= 4);   // Wq, Wk, Wq2, Wk2
    }
    int e   = gid * 4;
    int row = e >> 10;
    int col = e & 1023;
    float4 f = *(const float4*)(src + (size_t)row * 1024 + col);
    ushort4 hi, lo;
    hi.x = f2bf(f.x); lo.x = f2bf(f.x - bf2f(hi.x));
    hi.y = f2bf(f.y); lo.y = f2bf(f.y - bf2f(hi.y));
    hi.z = f2bf(f.z); lo.z = f2bf(f.z - bf2f(hi.z));
    hi.w = f2bf(f.w); lo.w = f2bf(f.w - bf2f(hi.w));
    int drow = row;
    if (ilv) {
        int hh = row >> 6, d = row & 63;
        int dd = (d < 32) ? ((d >> 3) * 16 + (d & 7))
                          : (((d - 32) >> 3) * 16 + 8 + (d & 7));
        drow = hh * 64 + dd;
    }
    *(ushort4*)(dst + (size_t)drow * 2048 + col) = hi;
    if (wlo)
        *(ushort4*)(dst + (size_t)drow * 2048 + 1024 + col) = lo;
}

// ---------------------------------------------------------------------------
// qkv GEMM — 1-TERM hi-only, K=1024 (was 2-term K=2048; half the MFMA work):
//   C[4096][5120] = Xhi[4096][1024] . Whi[5120][1024]^T
// Identical structure to the round-1 kernel (tile 256x320, K-tile 64, two kh
// of 32, 8 waves 2M x 4N, counted vmcnt(8), lgkmcnt(0) before each barrier,
// chunk-XOR swizzle) — ONLY the K iteration count changes: 16 tiles not 32.
// Sources read cols 0..1023 = the hi halves of the 2048-wide packed rows.
// Epilogue: lane-local RoPE via shfl_xor(8). Grid 16x16 = 256 blocks = 1/CU.
// ---------------------------------------------------------------------------
#define VMW(N) asm volatile("s_waitcnt vmcnt(" #N ")" ::: "memory")
#define LGKM0  asm volatile("s_waitcnt lgkmcnt(0)" ::: "memory")

__global__ __launch_bounds__(512, 2)
void gemm_qkv(const unsigned short* __restrict__ Ap,
              const unsigned short* __restrict__ Bp,
              unsigned short* __restrict__ Ch, unsigned short* __restrict__ Vt)
{
    __shared__ __align__(16) unsigned short A0s[2][8192];    // [256][32] each
    __shared__ __align__(16) unsigned short A1s[2][8192];
    __shared__ __align__(16) unsigned short B0s[2][10240];   // [320][32] each
    __shared__ __align__(16) unsigned short B1s[2][10240];

    const int t    = threadIdx.x;
    const int lane = t & 63;
    const int w    = t >> 6;
    const int wm   = w >> 2;          // M-half (0..1): 128 rows
    const int wn   = w & 3;           // N-quarter (0..3): 80 cols
    const int s    = lane & 15;
    const int g    = (lane >> 4) & 3;
    const int row0 = blockIdx.x * 256;
    const int col0 = blockIdx.y * 320;

    // read-side swizzled offsets (element units, 32-wide rows)
    const int cofs  = ((g ^ ((lane >> 1) & 3)) << 3);
    const int addrA = (wm * 128 + s) * 32 + cofs;   // + ii*512
    const int addrB = (wn * 80 + s) * 32 + cofs;    // + nf*512

    // stage-side pre-swizzled global source base (logical chunk per thread)
    const int alc = (t & 3) ^ ((t >> 3) & 3);
    const unsigned short* Ag = Ap + (size_t)(row0 + (t >> 2)) * 2048 + alc * 8;
    const unsigned short* Bg = Bp + (size_t)(col0 + (t >> 2)) * 2048 + alc * 8;

#define STAGE_A(dst, kofs) {                                                                              \
    __builtin_amdgcn_global_load_lds((gvoid*)(Ag + (kofs)),              (lvoid*)((dst) + t * 8),        16, 0, 0); \
    __builtin_amdgcn_global_load_lds((gvoid*)(Ag + (kofs) + 128 * 2048), (lvoid*)((dst) + 4096 + t * 8), 16, 0, 0); }

#define STAGE_B(dst, kofs) {                                                                              \
    __builtin_amdgcn_global_load_lds((gvoid*)(Bg + (kofs)),              (lvoid*)((dst) + t * 8),        16, 0, 0); \
    __builtin_amdgcn_global_load_lds((gvoid*)(Bg + (kofs) + 128 * 2048), (lvoid*)((dst) + 4096 + t * 8), 16, 0, 0); \
    if (t < 256)                                                                                          \
    __builtin_amdgcn_global_load_lds((gvoid*)(Bg + (kofs) + 256 * 2048), (lvoid*)((dst) + 8192 + t * 8), 16, 0, 0); }

    floatx4 acc[8][5];
    #pragma unroll
    for (int ii = 0; ii < 8; ++ii)
        #pragma unroll
        for (int nf = 0; nf < 5; ++nf)
            acc[ii][nf] = (floatx4)(0.0f);

    // ---- prologue: tile0 (kh0,kh1) and tile1 (kh0) ----
    STAGE_A(A0s[0], 0);
    STAGE_B(B0s[0], 0);
    STAGE_A(A1s[0], 32);
    STAGE_B(B1s[0], 32);
    STAGE_A(A0s[1], 64);
    STAGE_B(B0s[1], 64);
    VMW(4);                       // tile0 fully landed (newest 4-5 = tile1 kh0)
    __builtin_amdgcn_s_barrier();
    __builtin_amdgcn_sched_barrier(0);

#define MFMA_CLUSTER(IOFS)                                                                      \
    __builtin_amdgcn_s_setprio(1);                                                              \
    _Pragma("unroll")                                                                           \
    for (int ii = 0; ii < 4; ++ii)                                                              \
        _Pragma("unroll")                                                                       \
        for (int nf = 0; nf < 5; ++nf)                                                          \
            acc[(IOFS) + ii][nf] = __builtin_amdgcn_mfma_f32_16x16x32_bf16(af[ii], bf[nf], acc[(IOFS) + ii][nf], 0, 0, 0); \
    __builtin_amdgcn_s_setprio(0);

#define TILE_BODY(TAU, DO12, DO34, W2, W4)                                                      \
{                                                                                               \
    const int cur_ = (TAU) & 1;                                                                 \
    const unsigned short* a0k = A0s[cur_];                                                      \
    const unsigned short* a1k = A1s[cur_];                                                      \
    const unsigned short* b0k = B0s[cur_];                                                      \
    const unsigned short* b1k = B1s[cur_];                                                      \
    short8 af[4], bf[5];                                                                        \
    /* ---- p1: kh0, M-half0 + B-kh0 read ; stage (TAU+1) A-kh1 ---- */                         \
    _Pragma("unroll")                                                                           \
    for (int ii = 0; ii < 4; ++ii) af[ii] = *(const short8*)&a0k[addrA + ii * 512];             \
    _Pragma("unroll")                                                                           \
    for (int nf = 0; nf < 5; ++nf) bf[nf] = *(const short8*)&b0k[addrB + nf * 512];             \
    if (DO12) STAGE_A(A1s[cur_ ^ 1], ((TAU) + 1) * 64 + 32);                                    \
    LGKM0;                                                                                      \
    __builtin_amdgcn_s_barrier();                                                               \
    __builtin_amdgcn_sched_barrier(0);                                                          \
    MFMA_CLUSTER(0)                                                                             \
    /* ---- p2: kh0, M-half1 ; stage (TAU+1) B-kh1 ; vmcnt ---- */                              \
    _Pragma("unroll")                                                                           \
    for (int ii = 0; ii < 4; ++ii) af[ii] = *(const short8*)&a0k[addrA + (ii + 4) * 512];       \
    if (DO12) STAGE_B(B1s[cur_ ^ 1], ((TAU) + 1) * 64 + 32);                                    \
    LGKM0;                                                                                      \
    W2;                                                                                         \
    __builtin_amdgcn_s_barrier();                                                               \
    __builtin_amdgcn_sched_barrier(0);                                                          \
    MFMA_CLUSTER(4)                                                                             \
    /* ---- p3: kh1, M-half0 + B-kh1 read ; stage (TAU+2) A-kh0 ---- */                         \
    _Pragma("unroll")                                                                           \
    for (int ii = 0; ii < 4; ++ii) af[ii] = *(const short8*)&a1k[addrA + ii * 512];             \
    _Pragma("unroll")                                                                           \
    for (int nf = 0; nf < 5; ++nf) bf[nf] = *(const short8*)&b1k[addrB + nf * 512];             \
    if (DO34) STAGE_A(A0s[cur_], ((TAU) + 2) * 64);                                             \
    LGKM0;                                                                                      \
    __builtin_amdgcn_s_barrier();                                                               \
    __builtin_amdgcn_sched_barrier(0);                                                          \
    MFMA_CLUSTER(0)                                                                             \
    /* ---- p4: kh1, M-half1 ; stage (TAU+2) B-kh0 ; vmcnt ---- */                              \
    _Pragma("unroll")                                                                           \
    for (int ii = 0; ii < 4; ++ii) af[ii] = *(const short8*)&a1k[addrA + (ii + 4) * 512];       \
    if (DO34) STAGE_B(B0s[cur_], ((TAU) + 2) * 64);                                             \
    LGKM0;                                                                                      \
    W4;                                                                                         \
    __builtin_amdgcn_s_barrier();                                                               \
    __builtin_amdgcn_sched_barrier(0);                                                          \
    MFMA_CLUSTER(4)                                                                             \
}

    #pragma unroll 2
    for (int tau = 0; tau < 14; ++tau)
        TILE_BODY(tau, 1, 1, VMW(8), VMW(8));
    TILE_BODY(14, 1, 0, VMW(8), VMW(4));
    TILE_BODY(15, 0, 0, VMW(0), ((void)0));

#undef TILE_BODY
#undef MFMA_CLUSTER
#undef STAGE_A
#undef STAGE_B

    // ---- epilogue: lane-local RoPE (+1/64 q-scale); V transposed ----
    const int cr = (lane >> 4) * 4;
    const int cc = lane & 15;
    const int rwbase = row0 + wm * 128;
    const float L2C = -0.41524101186092029f;  // -log2(10000)/32

    #pragma unroll
    for (int nf = 0; nf < 5; ++nf) {
        const int cg = col0 + wn * 80 + nf * 16;  // global col of this frag
        const int p  = cg >> 10;                  // 0=q 1=k 2=q2 3=k2 4=v
        const int h  = (cg >> 6) & 15;
        const int f  = (cg >> 4) & 3;
        if (p < 4) {
            const float sc  = (p == 0 || p == 2) ? 0.015625f : 1.0f;
            const float inv = exp2f((float)(f * 8 + (cc & 7)) * L2C);
            unsigned short* hp = Ch + (size_t)p * 4194304;
            #pragma unroll
            for (int ii = 0; ii < 8; ++ii) {
                int r0  = rwbase + ii * 16 + cr;
                int bhi = ((r0 >> 11) << 4) + h;
                size_t base = ((size_t)bhi * 2048 + (r0 & 2047)) * 64;
                #pragma unroll
                for (int rr = 0; rr < 4; ++rr) {
                    float tt = (float)((r0 + rr) & 2047);
                    float s0, c0;
                    __sincosf(tt * inv, &s0, &c0);
                    float x  = acc[ii][nf][rr];
                    float xp = __shfl_xor(x, 8, 64);
                    float y  = (cc < 8) ? (x * c0 + xp * s0) : (x * c0 - xp * s0);
                    hp[base + (size_t)rr * 64 + (f * 16 + cc)] = f2bf(y * sc);
                }
            }
        } else {
            #pragma unroll
            for (int ii = 0; ii < 8; ++ii) {
                int r0  = rwbase + ii * 16 + cr;
                int bhi = ((r0 >> 11) << 4) + h;
                int d   = f * 16 + cc;
                ushort4 o;
                o.x = f2bf(acc[ii][nf][0]); o.y = f2bf(acc[ii][nf][1]);
                o.z = f2bf(acc[ii][nf][2]); o.w = f2bf(acc[ii][nf][3]);
                *(ushort4*)(Vt + ((size_t)bhi * 64 + d) * 2048 + (r0 & 2047)) = o;
            }
        }
    }
}

// ---------------------------------------------------------------------------
// Output projection: C = (hiA+loA)*hiB^T + hiA*loB^T (3-term), fp32 out.
// 128x128 template (UNCHANGED): grid (32,8) = 256 blocks = 1/CU,
// 4 waves (wave-tile 64x64), 48 MFMA : 16 ds_reads per K-step, 32 KB LDS.
// ---------------------------------------------------------------------------
__global__ __launch_bounds__(256)
void gemm_proj(const unsigned short* __restrict__ Ap,
               const unsigned short* __restrict__ Bp,
               float* __restrict__ Cf)
{
    __shared__ __align__(16) unsigned short Ah[128 * 32];
    __shared__ __align__(16) unsigned short Al[128 * 32];
    __shared__ __align__(16) unsigned short Bh[128 * 32];
    __shared__ __align__(16) unsigned short Bl[128 * 32];

    const int t    = threadIdx.x;
    const int lane = t & 63;
    const int s    = lane & 15;
    const int row0 = blockIdx.x * 128;
    const int col0 = blockIdx.y * 128;
    const int m0   = ((t >> 6) >> 1) * 64;
    const int n0   = ((t >> 6) & 1) * 64;

    floatx4 acc[4][4];
    #pragma unroll
    for (int i = 0; i < 4; ++i)
        #pragma unroll
        for (int j = 0; j < 4; ++j)
            acc[i][j] = (floatx4)(0.0f);

    const int sr  = t >> 2;
    const int skx = ((t & 3) ^ ((t >> 3) & 3)) * 8;
    char* dA  = (char*)Ah + (size_t)t * 16;
    char* dAl = (char*)Al + (size_t)t * 16;
    char* dB  = (char*)Bh + (size_t)t * 16;
    char* dBl = (char*)Bl + (size_t)t * 16;
    const size_t arow = (size_t)(row0 + sr) * 2048 + skx;
    const size_t brow = (size_t)(col0 + sr) * 2048 + skx;

    #define ISSUE(k0)                                                                         \
    {                                                                                         \
        const unsigned short* ga = Ap + arow + (k0);                                          \
        const unsigned short* gb = Bp + brow + (k0);                                          \
        __builtin_amdgcn_global_load_lds((gvoid*)ga,                 (lvoid*)dA,          16, 0, 0); \
        __builtin_amdgcn_global_load_lds((gvoid*)(ga + 64*2048),     (lvoid*)(dA + 4096), 16, 0, 0); \
        __builtin_amdgcn_global_load_lds((gvoid*)(ga + 1024),        (lvoid*)dAl,         16, 0, 0); \
        __builtin_amdgcn_global_load_lds((gvoid*)(ga + 1024+64*2048),(lvoid*)(dAl + 4096),16, 0, 0); \
        __builtin_amdgcn_global_load_lds((gvoid*)gb,                 (lvoid*)dB,          16, 0, 0); \
        __builtin_amdgcn_global_load_lds((gvoid*)(gb + 64*2048),     (lvoid*)(dB + 4096), 16, 0, 0); \
        __builtin_amdgcn_global_load_lds((gvoid*)(gb + 1024),        (lvoid*)dBl,         16, 0, 0); \
        __builtin_amdgcn_global_load_lds((gvoid*)(gb + 1024+64*2048),(lvoid*)(dBl + 4096),16, 0, 0); \
    }

    const int cofs = (((lane >> 4) ^ ((lane >> 1) & 3)) << 3);

    ISSUE(0);
    for (int ks = 0; ks < 32; ++ks) {
        __syncthreads();
        short8 ahf[4], alf[4], bhf[4], blf[4];
        #pragma unroll
        for (int i = 0; i < 4; ++i) {
            int ra = (m0 + i * 16 + s) * 32 + cofs;
            ahf[i] = *(const short8*)&Ah[ra];
            alf[i] = *(const short8*)&Al[ra];
        }
        #pragma unroll
        for (int j = 0; j < 4; ++j) {
            int rb = (n0 + j * 16 + s) * 32 + cofs;
            bhf[j] = *(const short8*)&Bh[rb];
            blf[j] = *(const short8*)&Bl[rb];
        }
        #pragma unroll
        for (int i = 0; i < 4; ++i)
            #pragma unroll
            for (int j = 0; j < 4; ++j) {
                acc[i][j] = __builtin_amdgcn_mfma_f32_16x16x32_bf16(ahf[i], bhf[j], acc[i][j], 0, 0, 0);
                acc[i][j] = __builtin_amdgcn_mfma_f32_16x16x32_bf16(alf[i], bhf[j], acc[i][j], 0, 0, 0);
                acc[i][j] = __builtin_amdgcn_mfma_f32_16x16x32_bf16(ahf[i], blf[j], acc[i][j], 0, 0, 0);
            }
        __syncthreads();
        if (ks + 1 < 32) ISSUE((ks + 1) * 32);
    }
    #undef ISSUE

    const int cr = (lane >> 4) * 4;
    const int cc = lane & 15;
    #pragma unroll
    for (int i = 0; i < 4; ++i)
        #pragma unroll
        for (int j = 0; j < 4; ++j) {
            int r = row0 + m0 + i * 16 + cr;
            int c = col0 + n0 + j * 16 + cc;
            #pragma unroll
            for (int rr = 0; rr < 4; ++rr)
                Cf[(size_t)(r + rr) * 1024 + c] = acc[i][j][rr];
        }
}

// ---------------------------------------------------------------------------
// MFMA bilinear causal attention — 4-wave version with XCD-AWARE SWIZZLE
// (UNCHANGED from round 7). Grid 1-D, 512 blocks = 64/XCD exactly:
//   xcd = bid & 7, slot = bid >> 3, bh = xcd*4 + (slot>>4), x = slot & 15
// Each XCD owns 4 complete heads (K/K2/V working set 3 MB < 4 MB L2).
// LDS 80 KB, 2 blocks/CU; psq overlays qs/q2s; 3 barriers/iter.
// ---------------------------------------------------------------------------
__global__ __launch_bounds__(256, 2)
void attn_mfma(const unsigned short* __restrict__ qh, const unsigned short* __restrict__ q2h,
               const unsigned short* __restrict__ kh, const unsigned short* __restrict__ k2h,
               const unsigned short* __restrict__ vt, unsigned short* __restrict__ zout)
{
    __shared__ __align__(16) unsigned short smem[40960];   // 80 KB
    unsigned short* qs  = smem;              // [128][64] rot8 (init only)
    unsigned short* q2s = smem + 8192;
    unsigned short* psq = smem;              // [128][128] rot16, overlays qs/q2s
    unsigned short* ks  = smem + 16384;      // [128][64] rot8
    unsigned short* k2s = smem + 24576;
    unsigned short* vts = smem + 32768;      // [64][128] rot16

    const int bid  = blockIdx.x;
    const int xcd  = bid & 7;
    const int slot = bid >> 3;
    const int bh   = xcd * 4 + (slot >> 4);
    const int qx   = slot & 15;
    const int qt = (bh < 16) ? (15 - qx) : qx;  // pair heavy+light
    const int t  = threadIdx.x;
    const int lane = t & 63;
    const int w    = t >> 6;
    const int s    = lane & 15;
    const int g    = lane >> 4;
    const int m0   = (w >> 1) * 64;   // k-split
    const int n0   = (w & 1) * 64;    // q-split

    // ---- stage q, q2 once, then hoist frags to registers ----
    {
        const unsigned short* qb  = qh  + ((size_t)bh * 2048 + qt * 128) * 64;
        const unsigned short* q2b = q2h + ((size_t)bh * 2048 + qt * 128) * 64;
        const int row = t >> 1;
        #pragma unroll
        for (int c = 0; c < 4; ++c) {
            int cg  = (t & 1) * 4 + c;
            short8 a  = *(const short8*)(qb  + (size_t)row * 64 + cg * 8);
            short8 a2 = *(const short8*)(q2b + (size_t)row * 64 + cg * 8);
            int cgm = (cg + row) & 7;
            *(short8*)&qs [row * 64 + cgm * 8] = a;
            *(short8*)&q2s[row * 64 + cgm * 8] = a2;
        }
    }
    __syncthreads();
    short8 bq[2][4], bq2[2][4];
    #pragma unroll
    for (int kstep = 0; kstep < 2; ++kstep) {
        const int gl = kstep * 4 + g;
        #pragma unroll
        for (int j = 0; j < 4; ++j) {
            int row = n0 + j * 16 + s;
            int a = row * 64 + ((gl + row) & 7) * 8;
            bq[kstep][j]  = *(const short8*)&qs [a];
            bq2[kstep][j] = *(const short8*)&q2s[a];
        }
    }

    floatx4 zac[2][4];
    #pragma unroll
    for (int i = 0; i < 2; ++i)
        #pragma unroll
        for (int j = 0; j < 4; ++j)
            zac[i][j] = (floatx4)(0.0f);

    for (int tk = 0; tk <= qt; ++tk) {
        // ---- register prefetch ----
        short8 kf[4], k2f[4], vf[4];
        {
            const unsigned short* kb  = kh  + ((size_t)bh * 2048 + tk * 128) * 64;
            const unsigned short* k2b = k2h + ((size_t)bh * 2048 + tk * 128) * 64;
            const unsigned short* vb  = vt  + (size_t)bh * 131072 + tk * 128;
            const int krow = t >> 1;
            const int vd   = t >> 2;
            #pragma unroll
            for (int c = 0; c < 4; ++c) {
                int cg = (t & 1) * 4 + c;
                kf[c]  = *(const short8*)(kb  + (size_t)krow * 64 + cg * 8);
                k2f[c] = *(const short8*)(k2b + (size_t)krow * 64 + cg * 8);
                int cg16 = 4 * (t & 3) + c;
                vf[c]  = *(const short8*)(vb + (size_t)vd * 2048 + cg16 * 8);
            }
        }
        __syncthreads();   // b0: prev PV done (psq/vts); prev S done (ks/k2s); q-hoist done
        {
            const int krow = t >> 1;
            const int vd   = t >> 2;
            #pragma unroll
            for (int c = 0; c < 4; ++c) {
                int cg  = (t & 1) * 4 + c;
                int cgm = (cg + krow) & 7;
                *(short8*)&ks [krow * 64 + cgm * 8] = kf[c];
                *(short8*)&k2s[krow * 64 + cgm * 8] = k2f[c];
                int cg16  = 4 * (t & 3) + c;
                int cgm16 = (cg16 + vd) & 15;
                *(short8*)&vts[vd * 128 + cgm16 * 8] = vf[c];
            }
        }
        __syncthreads();   // b1: tiles visible

        // ---- S + P, i-outer (a1/a2 footprint = one i at a time) ----
        #pragma unroll
        for (int i = 0; i < 4; ++i) {
            floatx4 a1[4], a2[4];
            #pragma unroll
            for (int j = 0; j < 4; ++j) { a1[j] = (floatx4)(0.0f); a2[j] = (floatx4)(0.0f); }
            #pragma unroll
            for (int kstep = 0; kstep < 2; ++kstep) {
                const int gl = kstep * 4 + g;
                int row = m0 + i * 16 + s;
                int a = row * 64 + ((gl + row) & 7) * 8;
                short8 ak  = *(const short8*)&ks [a];
                short8 ak2 = *(const short8*)&k2s[a];
                #pragma unroll
                for (int j = 0; j < 4; ++j) {
                    a1[j] = __builtin_amdgcn_mfma_f32_16x16x32_bf16(ak,  bq[kstep][j],  a1[j], 0, 0, 0);
                    a2[j] = __builtin_amdgcn_mfma_f32_16x16x32_bf16(ak2, bq2[kstep][j], a2[j], 0, 0, 0);
                }
            }
            // P-write for this i: psq region unread by anyone during the loop
            const int kl0   = m0 + i * 16 + g * 4;
            const int chunk = kl0 >> 3;
            const int sub   = kl0 & 7;
            if (tk < qt) {
                #pragma unroll
                for (int j = 0; j < 4; ++j) {
                    const int ql = n0 + j * 16 + s;
                    ushort4 pw;
                    pw.x = f2bf(a1[j][0] * a2[j][0]);
                    pw.y = f2bf(a1[j][1] * a2[j][1]);
                    pw.z = f2bf(a1[j][2] * a2[j][2]);
                    pw.w = f2bf(a1[j][3] * a2[j][3]);
                    *(ushort4*)&psq[ql * 128 + ((chunk + ql) & 15) * 8 + sub] = pw;
                }
            } else {
                #pragma unroll
                for (int j = 0; j < 4; ++j) {
                    const int ql = n0 + j * 16 + s;
                    ushort4 pw;
                    pw.x = (kl0 + 0 <= ql) ? f2bf(a1[j][0] * a2[j][0]) : (unsigned short)0;
                    pw.y = (kl0 + 1 <= ql) ? f2bf(a1[j][1] * a2[j][1]) : (unsigned short)0;
                    pw.z = (kl0 + 2 <= ql) ? f2bf(a1[j][2] * a2[j][2]) : (unsigned short)0;
                    pw.w = (kl0 + 3 <= ql) ? f2bf(a1[j][3] * a2[j][3]) : (unsigned short)0;
                    *(ushort4*)&psq[ql * 128 + ((chunk + ql) & 15) * 8 + sub] = pw;
                }
            }
        }

        __syncthreads();   // b2: psq visible

        // ---- PV: z[q][d] += P[q][k] * vT[d][k] ----
        const int wm0 = w * 32;
        #pragma unroll
        for (int kstep = 0; kstep < 4; ++kstep) {
            const int cbase = kstep * 4 + g;
            short8 ap[2], bv[4];
            #pragma unroll
            for (int i2 = 0; i2 < 2; ++i2) {
                int q = wm0 + i2 * 16 + s;
                ap[i2] = *(const short8*)&psq[q * 128 + ((cbase + q) & 15) * 8];
            }
            #pragma unroll
            for (int jd = 0; jd < 4; ++jd) {
                int d = jd * 16 + s;
                bv[jd] = *(const short8*)&vts[d * 128 + ((cbase + d) & 15) * 8];
            }
            #pragma unroll
            for (int i2 = 0; i2 < 2; ++i2)
                #pragma unroll
                for (int jd = 0; jd < 4; ++jd)
                    zac[i2][jd] = __builtin_amdgcn_mfma_f32_16x16x32_bf16(ap[i2], bv[jd], zac[i2][jd], 0, 0, 0);
        }
    }

    // ---- epilogue: z -> split bf16 [hi | lo] into zout[4096][2048] ----
    const int b = bh >> 4, h = bh & 15;
    const size_t zrow0 = (size_t)(b * TSEQ + qt * 128);
    #pragma unroll
    for (int i2 = 0; i2 < 2; ++i2)
        #pragma unroll
        for (int j = 0; j < 4; ++j)
            #pragma unroll
            for (int r = 0; r < 4; ++r) {
                float zv = zac[i2][j][r];
                unsigned short hi = f2bf(zv);
                unsigned short lo = f2bf(zv - bf2f(hi));
                size_t row = zrow0 + w * 32 + i2 * 16 + g * 4 + r;
                int col = h * 64 + j * 16 + s;
                zout[row * 2048 + col]        = hi;
                zout[row * 2048 + 1024 + col] = lo;
            }
}

// ---------------------------------------------------------------------------
extern "C" void kernel_launch(void* const* d_in, const int* in_sizes, int n_in,
                              void* d_out, int out_size, void* d_ws, size_t ws_size,
                              hipStream_t stream)
{
    const float* x     = (const float*)d_in[0];
    const float* Wq    = (const float*)d_in[1];
    const float* Wk    = (const float*)d_in[2];
    const float* Wq2   = (const float*)d_in[3];
    const float* Wk2   = (const float*)d_in[4];
    const float* Wv    = (const float*)d_in[5];
    const float* Wproj = (const float*)d_in[6];

    // workspace (bytes):
    //   Xp    bf16 [4096][2048] (x-hi packed, later z-split) @ 0      (16,777,216)
    //   Wp    bf16 [6144][2048]                          @ 16,777,216 (25,165,824)
    //         rows [0,1024)    = Wproj [hi|lo]
    //         rows [1024,6144) = Wq,Wk,Wq2,Wk2 (head-interleaved), Wv [hi|dead]
    //   heads bf16 4x[32][2048][64] (q,k,q2,k2)          @ 41,943,040 (33,554,432)
    //   vt    bf16 [32][64][2048]                        @ 75,497,472 ( 8,388,608)
    unsigned short* Xp    = (unsigned short*)d_ws;
    unsigned short* Wp    = (unsigned short*)((char*)d_ws + 16777216);
    unsigned short* heads = (unsigned short*)((char*)d_ws + 41943040);
    unsigned short* vt    = (unsigned short*)((char*)d_ws + 75497472);

    const size_t HS = (size_t)32 * 2048 * 64;
    unsigned short* qh  = heads;
    unsigned short* kh  = heads + 1 * HS;
    unsigned short* q2h = heads + 2 * HS;
    unsigned short* k2h = heads + 3 * HS;

    pack_all_kernel<<<10240, 256, 0, stream>>>(x, Wproj, Wq, Wk, Wq2, Wk2, Wv, Xp, Wp);
    gemm_qkv<<<dim3(16, 16), 512, 0, stream>>>(Xp, Wp + (size_t)1024 * 2048, heads, vt);
    attn_mfma<<<512, 256, 0, stream>>>(qh, q2h, kh, k2h, vt, Xp);
    gemm_proj<<<dim3(32, 8), 256, 0, stream>>>(Xp, Wp, (float*)d_out);
}

// Round 9
// 233.150 us; speedup vs baseline: 1.5063x; 1.0560x over previous
//
#include <hip/hip_runtime.h>
#include <hip/hip_bf16.h>

#define TSEQ 2048
#define NHEAD 16
#define DM 1024
#define NBATCH 2
#define MTOK (NBATCH * TSEQ)   // 4096

typedef __attribute__((ext_vector_type(8))) short short8;
typedef __attribute__((ext_vector_type(4))) float floatx4;
typedef __attribute__((address_space(1))) const void gvoid;
typedef __attribute__((address_space(3))) void lvoid;

static __device__ __forceinline__ unsigned short f2bf(float f) {
    unsigned int u = __float_as_uint(f);
    return (unsigned short)((u + 0x7fffu + ((u >> 16) & 1u)) >> 16);
}
static __device__ __forceinline__ float bf2f(unsigned short h) {
    return __uint_as_float(((unsigned int)h) << 16);
}

// ---------------------------------------------------------------------------
// Pack x and the 6 weight matrices to split bf16 rows.
//   x      -> [hi(1024) | dead]   (1-term qkv; attn overwrites Xp before proj)
//   Wproj  -> [hi | lo]           (3-term proj GEMM needs lo)
//   Wq..Wv -> [hi | dead]         (qkv reads only cols 0..1023)
//   Wq,Wk,Wq2,Wk2 rows additionally PER-HEAD INTERLEAVED:
//     d<32 -> (d>>3)*16 + (d&7) ; d>=32 -> ((d-32)>>3)*16 + 8 + (d&7)
//   so each 16-col C-fragment holds RoPE pairs at lanes cc / cc^8.
// blocks [0,4096) -> x ; [4096,10240) -> weights (1024 blocks each).
// ---------------------------------------------------------------------------
__global__ __launch_bounds__(256)
void pack_all_kernel(const float* __restrict__ x,
                     const float* __restrict__ w0, const float* __restrict__ w1,
                     const float* __restrict__ w2, const float* __restrict__ w3,
                     const float* __restrict__ w4, const float* __restrict__ w5,
                     unsigned short* __restrict__ dstX, unsigned short* __restrict__ dstW)
{
    const float* src;
    unsigned short* dst;
    int gid;
    bool wlo = false, ilv = false;
    if (blockIdx.x < 4096) {
        src = x; dst = dstX;
        gid = blockIdx.x * 256 + threadIdx.x;
    } else {
        int wi = (blockIdx.x - 4096) >> 10;
        const float* srcs[6] = {w0, w1, w2, w3, w4, w5};
        src = srcs[wi];
        dst = dstW + (size_t)wi * 1024 * 2048;
        gid = ((blockIdx.x - 4096) & 1023) * 256 + threadIdx.x;
        wlo = (wi == 0);              // only Wproj needs the lo half
        ilv = (wi >= 1 && wi <= 4);   // Wq, Wk, Wq2, Wk2
    }
    int e   = gid * 4;
    int row = e >> 10;
    int col = e & 1023;
    float4 f = *(const float4*)(src + (size_t)row * 1024 + col);
    ushort4 hi, lo;
    hi.x = f2bf(f.x); lo.x = f2bf(f.x - bf2f(hi.x));
    hi.y = f2bf(f.y); lo.y = f2bf(f.y - bf2f(hi.y));
    hi.z = f2bf(f.z); lo.z = f2bf(f.z - bf2f(hi.z));
    hi.w = f2bf(f.w); lo.w = f2bf(f.w - bf2f(hi.w));
    int drow = row;
    if (ilv) {
        int hh = row >> 6, d = row & 63;
        int dd = (d < 32) ? ((d >> 3) * 16 + (d & 7))
                          : (((d - 32) >> 3) * 16 + 8 + (d & 7));
        drow = hh * 64 + dd;
    }
    *(ushort4*)(dst + (size_t)drow * 2048 + col) = hi;
    if (wlo)
        *(ushort4*)(dst + (size_t)drow * 2048 + 1024 + col) = lo;
}

// ---------------------------------------------------------------------------
// qkv GEMM — 1-TERM hi-only, K=1024 (UNCHANGED from round 8):
//   C[4096][5120] = Xhi[4096][1024] . Whi[5120][1024]^T
// Tile 256x320, K-tile 64, 8 waves 2M x 4N, counted vmcnt(8), 16 K-tiles.
// ---------------------------------------------------------------------------
#define VMW(N) asm volatile("s_waitcnt vmcnt(" #N ")" ::: "memory")
#define LGKM0  asm volatile("s_waitcnt lgkmcnt(0)" ::: "memory")

__global__ __launch_bounds__(512, 2)
void gemm_qkv(const unsigned short* __restrict__ Ap,
              const unsigned short* __restrict__ Bp,
              unsigned short* __restrict__ Ch, unsigned short* __restrict__ Vt)
{
    __shared__ __align__(16) unsigned short A0s[2][8192];    // [256][32] each
    __shared__ __align__(16) unsigned short A1s[2][8192];
    __shared__ __align__(16) unsigned short B0s[2][10240];   // [320][32] each
    __shared__ __align__(16) unsigned short B1s[2][10240];

    const int t    = threadIdx.x;
    const int lane = t & 63;
    const int w    = t >> 6;
    const int wm   = w >> 2;          // M-half (0..1): 128 rows
    const int wn   = w & 3;           // N-quarter (0..3): 80 cols
    const int s    = lane & 15;
    const int g    = (lane >> 4) & 3;
    const int row0 = blockIdx.x * 256;
    const int col0 = blockIdx.y * 320;

    // read-side swizzled offsets (element units, 32-wide rows)
    const int cofs  = ((g ^ ((lane >> 1) & 3)) << 3);
    const int addrA = (wm * 128 + s) * 32 + cofs;   // + ii*512
    const int addrB = (wn * 80 + s) * 32 + cofs;    // + nf*512

    // stage-side pre-swizzled global source base (logical chunk per thread)
    const int alc = (t & 3) ^ ((t >> 3) & 3);
    const unsigned short* Ag = Ap + (size_t)(row0 + (t >> 2)) * 2048 + alc * 8;
    const unsigned short* Bg = Bp + (size_t)(col0 + (t >> 2)) * 2048 + alc * 8;

#define STAGE_A(dst, kofs) {                                                                              \
    __builtin_amdgcn_global_load_lds((gvoid*)(Ag + (kofs)),              (lvoid*)((dst) + t * 8),        16, 0, 0); \
    __builtin_amdgcn_global_load_lds((gvoid*)(Ag + (kofs) + 128 * 2048), (lvoid*)((dst) + 4096 + t * 8), 16, 0, 0); }

#define STAGE_B(dst, kofs) {                                                                              \
    __builtin_amdgcn_global_load_lds((gvoid*)(Bg + (kofs)),              (lvoid*)((dst) + t * 8),        16, 0, 0); \
    __builtin_amdgcn_global_load_lds((gvoid*)(Bg + (kofs) + 128 * 2048), (lvoid*)((dst) + 4096 + t * 8), 16, 0, 0); \
    if (t < 256)                                                                                          \
    __builtin_amdgcn_global_load_lds((gvoid*)(Bg + (kofs) + 256 * 2048), (lvoid*)((dst) + 8192 + t * 8), 16, 0, 0); }

    floatx4 acc[8][5];
    #pragma unroll
    for (int ii = 0; ii < 8; ++ii)
        #pragma unroll
        for (int nf = 0; nf < 5; ++nf)
            acc[ii][nf] = (floatx4)(0.0f);

    // ---- prologue: tile0 (kh0,kh1) and tile1 (kh0) ----
    STAGE_A(A0s[0], 0);
    STAGE_B(B0s[0], 0);
    STAGE_A(A1s[0], 32);
    STAGE_B(B1s[0], 32);
    STAGE_A(A0s[1], 64);
    STAGE_B(B0s[1], 64);
    VMW(4);                       // tile0 fully landed (newest 4-5 = tile1 kh0)
    __builtin_amdgcn_s_barrier();
    __builtin_amdgcn_sched_barrier(0);

#define MFMA_CLUSTER(IOFS)                                                                      \
    __builtin_amdgcn_s_setprio(1);                                                              \
    _Pragma("unroll")                                                                           \
    for (int ii = 0; ii < 4; ++ii)                                                              \
        _Pragma("unroll")                                                                       \
        for (int nf = 0; nf < 5; ++nf)                                                          \
            acc[(IOFS) + ii][nf] = __builtin_amdgcn_mfma_f32_16x16x32_bf16(af[ii], bf[nf], acc[(IOFS) + ii][nf], 0, 0, 0); \
    __builtin_amdgcn_s_setprio(0);

#define TILE_BODY(TAU, DO12, DO34, W2, W4)                                                      \
{                                                                                               \
    const int cur_ = (TAU) & 1;                                                                 \
    const unsigned short* a0k = A0s[cur_];                                                      \
    const unsigned short* a1k = A1s[cur_];                                                      \
    const unsigned short* b0k = B0s[cur_];                                                      \
    const unsigned short* b1k = B1s[cur_];                                                      \
    short8 af[4], bf[5];                                                                        \
    /* ---- p1: kh0, M-half0 + B-kh0 read ; stage (TAU+1) A-kh1 ---- */                         \
    _Pragma("unroll")                                                                           \
    for (int ii = 0; ii < 4; ++ii) af[ii] = *(const short8*)&a0k[addrA + ii * 512];             \
    _Pragma("unroll")                                                                           \
    for (int nf = 0; nf < 5; ++nf) bf[nf] = *(const short8*)&b0k[addrB + nf * 512];             \
    if (DO12) STAGE_A(A1s[cur_ ^ 1], ((TAU) + 1) * 64 + 32);                                    \
    LGKM0;                                                                                      \
    __builtin_amdgcn_s_barrier();                                                               \
    __builtin_amdgcn_sched_barrier(0);                                                          \
    MFMA_CLUSTER(0)                                                                             \
    /* ---- p2: kh0, M-half1 ; stage (TAU+1) B-kh1 ; vmcnt ---- */                              \
    _Pragma("unroll")                                                                           \
    for (int ii = 0; ii < 4; ++ii) af[ii] = *(const short8*)&a0k[addrA + (ii + 4) * 512];       \
    if (DO12) STAGE_B(B1s[cur_ ^ 1], ((TAU) + 1) * 64 + 32);                                    \
    LGKM0;                                                                                      \
    W2;                                                                                         \
    __builtin_amdgcn_s_barrier();                                                               \
    __builtin_amdgcn_sched_barrier(0);                                                          \
    MFMA_CLUSTER(4)                                                                             \
    /* ---- p3: kh1, M-half0 + B-kh1 read ; stage (TAU+2) A-kh0 ---- */                         \
    _Pragma("unroll")                                                                           \
    for (int ii = 0; ii < 4; ++ii) af[ii] = *(const short8*)&a1k[addrA + ii * 512];             \
    _Pragma("unroll")                                                                           \
    for (int nf = 0; nf < 5; ++nf) bf[nf] = *(const short8*)&b1k[addrB + nf * 512];             \
    if (DO34) STAGE_A(A0s[cur_], ((TAU) + 2) * 64);                                             \
    LGKM0;                                                                                      \
    __builtin_amdgcn_s_barrier();                                                               \
    __builtin_amdgcn_sched_barrier(0);                                                          \
    MFMA_CLUSTER(0)                                                                             \
    /* ---- p4: kh1, M-half1 ; stage (TAU+2) B-kh0 ; vmcnt ---- */                              \
    _Pragma("unroll")                                                                           \
    for (int ii = 0; ii < 4; ++ii) af[ii] = *(const short8*)&a1k[addrA + (ii + 4) * 512];       \
    if (DO34) STAGE_B(B0s[cur_], ((TAU) + 2) * 64);                                             \
    LGKM0;                                                                                      \
    W4;                                                                                        \
    __builtin_amdgcn_s_barrier();                                                               \
    __builtin_amdgcn_sched_barrier(0);                                                          \
    MFMA_CLUSTER(4)                                                                             \
}

    #pragma unroll 2
    for (int tau = 0; tau < 14; ++tau)
        TILE_BODY(tau, 1, 1, VMW(8), VMW(8));
    TILE_BODY(14, 1, 0, VMW(8), VMW(4));
    TILE_BODY(15, 0, 0, VMW(0), ((void)0));

#undef TILE_BODY
#undef MFMA_CLUSTER
#undef STAGE_A
#undef STAGE_B

    // ---- epilogue: lane-local RoPE (+1/64 q-scale); V transposed ----
    const int cr = (lane >> 4) * 4;
    const int cc = lane & 15;
    const int rwbase = row0 + wm * 128;
    const float L2C = -0.41524101186092029f;  // -log2(10000)/32

    #pragma unroll
    for (int nf = 0; nf < 5; ++nf) {
        const int cg = col0 + wn * 80 + nf * 16;  // global col of this frag
        const int p  = cg >> 10;                  // 0=q 1=k 2=q2 3=k2 4=v
        const int h  = (cg >> 6) & 15;
        const int f  = (cg >> 4) & 3;
        if (p < 4) {
            const float sc  = (p == 0 || p == 2) ? 0.015625f : 1.0f;
            const float inv = exp2f((float)(f * 8 + (cc & 7)) * L2C);
            unsigned short* hp = Ch + (size_t)p * 4194304;
            #pragma unroll
            for (int ii = 0; ii < 8; ++ii) {
                int r0  = rwbase + ii * 16 + cr;
                int bhi = ((r0 >> 11) << 4) + h;
                size_t base = ((size_t)bhi * 2048 + (r0 & 2047)) * 64;
                #pragma unroll
                for (int rr = 0; rr < 4; ++rr) {
                    float tt = (float)((r0 + rr) & 2047);
                    float s0, c0;
                    __sincosf(tt * inv, &s0, &c0);
                    float x  = acc[ii][nf][rr];
                    float xp = __shfl_xor(x, 8, 64);
                    float y  = (cc < 8) ? (x * c0 + xp * s0) : (x * c0 - xp * s0);
                    hp[base + (size_t)rr * 64 + (f * 16 + cc)] = f2bf(y * sc);
                }
            }
        } else {
            #pragma unroll
            for (int ii = 0; ii < 8; ++ii) {
                int r0  = rwbase + ii * 16 + cr;
                int bhi = ((r0 >> 11) << 4) + h;
                int d   = f * 16 + cc;
                ushort4 o;
                o.x = f2bf(acc[ii][nf][0]); o.y = f2bf(acc[ii][nf][1]);
                o.z = f2bf(acc[ii][nf][2]); o.w = f2bf(acc[ii][nf][3]);
                *(ushort4*)(Vt + ((size_t)bhi * 64 + d) * 2048 + (r0 & 2047)) = o;
            }
        }
    }
}

// ---------------------------------------------------------------------------
// Output projection: C = (hiA+loA)*hiB^T + hiA*loB^T (3-term), fp32 out.
// 128x128 template (UNCHANGED): grid (32,8) = 256 blocks = 1/CU,
// 4 waves (wave-tile 64x64), 48 MFMA : 16 ds_reads per K-step, 32 KB LDS.
// ---------------------------------------------------------------------------
__global__ __launch_bounds__(256)
void gemm_proj(const unsigned short* __restrict__ Ap,
               const unsigned short* __restrict__ Bp,
               float* __restrict__ Cf)
{
    __shared__ __align__(16) unsigned short Ah[128 * 32];
    __shared__ __align__(16) unsigned short Al[128 * 32];
    __shared__ __align__(16) unsigned short Bh[128 * 32];
    __shared__ __align__(16) unsigned short Bl[128 * 32];

    const int t    = threadIdx.x;
    const int lane = t & 63;
    const int s    = lane & 15;
    const int row0 = blockIdx.x * 128;
    const int col0 = blockIdx.y * 128;
    const int m0   = ((t >> 6) >> 1) * 64;
    const int n0   = ((t >> 6) & 1) * 64;

    floatx4 acc[4][4];
    #pragma unroll
    for (int i = 0; i < 4; ++i)
        #pragma unroll
        for (int j = 0; j < 4; ++j)
            acc[i][j] = (floatx4)(0.0f);

    const int sr  = t >> 2;
    const int skx = ((t & 3) ^ ((t >> 3) & 3)) * 8;
    char* dA  = (char*)Ah + (size_t)t * 16;
    char* dAl = (char*)Al + (size_t)t * 16;
    char* dB  = (char*)Bh + (size_t)t * 16;
    char* dBl = (char*)Bl + (size_t)t * 16;
    const size_t arow = (size_t)(row0 + sr) * 2048 + skx;
    const size_t brow = (size_t)(col0 + sr) * 2048 + skx;

    #define ISSUE(k0)                                                                         \
    {                                                                                         \
        const unsigned short* ga = Ap + arow + (k0);                                          \
        const unsigned short* gb = Bp + brow + (k0);                                          \
        __builtin_amdgcn_global_load_lds((gvoid*)ga,                 (lvoid*)dA,          16, 0, 0); \
        __builtin_amdgcn_global_load_lds((gvoid*)(ga + 64*2048),     (lvoid*)(dA + 4096), 16, 0, 0); \
        __builtin_amdgcn_global_load_lds((gvoid*)(ga + 1024),        (lvoid*)dAl,         16, 0, 0); \
        __builtin_amdgcn_global_load_lds((gvoid*)(ga + 1024+64*2048),(lvoid*)(dAl + 4096),16, 0, 0); \
        __builtin_amdgcn_global_load_lds((gvoid*)gb,                 (lvoid*)dB,          16, 0, 0); \
        __builtin_amdgcn_global_load_lds((gvoid*)(gb + 64*2048),     (lvoid*)(dB + 4096), 16, 0, 0); \
        __builtin_amdgcn_global_load_lds((gvoid*)(gb + 1024),        (lvoid*)dBl,         16, 0, 0); \
        __builtin_amdgcn_global_load_lds((gvoid*)(gb + 1024+64*2048),(lvoid*)(dBl + 4096),16, 0, 0); \
    }

    const int cofs = (((lane >> 4) ^ ((lane >> 1) & 3)) << 3);

    ISSUE(0);
    for (int ks = 0; ks < 32; ++ks) {
        __syncthreads();
        short8 ahf[4], alf[4], bhf[4], blf[4];
        #pragma unroll
        for (int i = 0; i < 4; ++i) {
            int ra = (m0 + i * 16 + s) * 32 + cofs;
            ahf[i] = *(const short8*)&Ah[ra];
            alf[i] = *(const short8*)&Al[ra];
        }
        #pragma unroll
        for (int j = 0; j < 4; ++j) {
            int rb = (n0 + j * 16 + s) * 32 + cofs;
            bhf[j] = *(const short8*)&Bh[rb];
            blf[j] = *(const short8*)&Bl[rb];
        }
        #pragma unroll
        for (int i = 0; i < 4; ++i)
            #pragma unroll
            for (int j = 0; j < 4; ++j) {
                acc[i][j] = __builtin_amdgcn_mfma_f32_16x16x32_bf16(ahf[i], bhf[j], acc[i][j], 0, 0, 0);
                acc[i][j] = __builtin_amdgcn_mfma_f32_16x16x32_bf16(alf[i], bhf[j], acc[i][j], 0, 0, 0);
                acc[i][j] = __builtin_amdgcn_mfma_f32_16x16x32_bf16(ahf[i], blf[j], acc[i][j], 0, 0, 0);
            }
        __syncthreads();
        if (ks + 1 < 32) ISSUE((ks + 1) * 32);
    }
    #undef ISSUE

    const int cr = (lane >> 4) * 4;
    const int cc = lane & 15;
    #pragma unroll
    for (int i = 0; i < 4; ++i)
        #pragma unroll
        for (int j = 0; j < 4; ++j) {
            int r = row0 + m0 + i * 16 + cr;
            int c = col0 + n0 + j * 16 + cc;
            #pragma unroll
            for (int rr = 0; rr < 4; ++rr)
                Cf[(size_t)(r + rr) * 1024 + c] = acc[i][j][rr];
        }
}

// ---------------------------------------------------------------------------
// MFMA bilinear causal attention — 8-wave, LOAD-BALANCED 2-pass blocks,
// XCD-aware. Grid 256 = 1 block/CU; every block does EXACTLY 17 tile-iters:
// pass 0 = heavy q-tile (qt = 15-pr, 16-pr iters), pass 1 = light (qt = pr,
// pr+1 iters). Balance holds under ANY block->CU assignment (fixes the
// measured 11% occupancy / 1.9x makespan skew of the per-qt-block version).
// Mapping: xcd = bid&7, hh = (bid>>3)>>3, pr = (bid>>3)&7, bh = xcd*4+hh
// -> each XCD still owns 4 complete heads (K/K2/V 3 MB < 4 MB L2; measured
// FETCH 20.6 MB with this ownership).
// 8 waves (512 thr) = 2 waves/SIMD at 1 block/CU: 4-way k-split (32 rows),
// 2-way q-split for S; PV q-ownership 16 rows/wave (R6 partition, which
// passed correctness). Pass-start __syncthreads protects psq->qs overlay.
// LDS 80 KB; 3 barriers/iter.
// ---------------------------------------------------------------------------
__global__ __launch_bounds__(512, 2)
void attn_mfma(const unsigned short* __restrict__ qh, const unsigned short* __restrict__ q2h,
               const unsigned short* __restrict__ kh, const unsigned short* __restrict__ k2h,
               const unsigned short* __restrict__ vt, unsigned short* __restrict__ zout)
{
    __shared__ __align__(16) unsigned short smem[40960];   // 80 KB
    unsigned short* qs  = smem;              // [128][64] rot8 (init only)
    unsigned short* q2s = smem + 8192;
    unsigned short* psq = smem;              // [128][128] rot16, overlays qs/q2s
    unsigned short* ks  = smem + 16384;      // [128][64] rot8
    unsigned short* k2s = smem + 24576;
    unsigned short* vts = smem + 32768;      // [64][128] rot16

    const int bid  = blockIdx.x;
    const int xcd  = bid & 7;
    const int slot = bid >> 3;          // 0..31
    const int hh   = slot >> 3;         // 0..3
    const int pr   = slot & 7;          // 0..7 (pair index)
    const int bh   = xcd * 4 + hh;
    const int t  = threadIdx.x;
    const int lane = t & 63;
    const int w    = t >> 6;          // 0..7
    const int s    = lane & 15;
    const int g    = lane >> 4;
    const int mk   = (w >> 1) * 32;   // 4-way k-split: 32 rows/wave
    const int nq   = (w & 1) * 64;    // 2-way q-split

    const int b = bh >> 4, h = bh & 15;

    #pragma unroll
    for (int pass = 0; pass < 2; ++pass) {
        const int qt = pass ? pr : (15 - pr);

        __syncthreads();   // prev pass's psq reads done before qs overwrite

        // ---- stage q, q2 for this q-tile, then hoist frags to registers ----
        {
            const unsigned short* qb  = qh  + ((size_t)bh * 2048 + qt * 128) * 64;
            const unsigned short* q2b = q2h + ((size_t)bh * 2048 + qt * 128) * 64;
            const int row = t >> 2;                    // 0..127
            #pragma unroll
            for (int c = 0; c < 2; ++c) {
                int cg  = (t & 3) * 2 + c;             // 0..7
                short8 a  = *(const short8*)(qb  + (size_t)row * 64 + cg * 8);
                short8 a2 = *(const short8*)(q2b + (size_t)row * 64 + cg * 8);
                int cgm = (cg + row) & 7;
                *(short8*)&qs [row * 64 + cgm * 8] = a;
                *(short8*)&q2s[row * 64 + cgm * 8] = a2;
            }
        }
        __syncthreads();
        short8 bq[2][4], bq2[2][4];
        #pragma unroll
        for (int kstep = 0; kstep < 2; ++kstep) {
            const int gl = kstep * 4 + g;
            #pragma unroll
            for (int j = 0; j < 4; ++j) {
                int row = nq + j * 16 + s;
                int a = row * 64 + ((gl + row) & 7) * 8;
                bq[kstep][j]  = *(const short8*)&qs [a];
                bq2[kstep][j] = *(const short8*)&q2s[a];
            }
        }

        floatx4 zac[4];
        #pragma unroll
        for (int j = 0; j < 4; ++j)
            zac[j] = (floatx4)(0.0f);

        for (int tk = 0; tk <= qt; ++tk) {
            // ---- register prefetch ----
            short8 kf[2], k2f[2], vf[2];
            {
                const unsigned short* kb  = kh  + ((size_t)bh * 2048 + tk * 128) * 64;
                const unsigned short* k2b = k2h + ((size_t)bh * 2048 + tk * 128) * 64;
                const unsigned short* vb  = vt  + (size_t)bh * 131072 + tk * 128;
                const int krow = t >> 2;               // 0..127
                const int vd   = t >> 3;               // 0..63
                #pragma unroll
                for (int c = 0; c < 2; ++c) {
                    int cg = (t & 3) * 2 + c;          // 0..7
                    kf[c]  = *(const short8*)(kb  + (size_t)krow * 64 + cg * 8);
                    k2f[c] = *(const short8*)(k2b + (size_t)krow * 64 + cg * 8);
                    int cg16 = (t & 7) * 2 + c;        // 0..15
                    vf[c]  = *(const short8*)(vb + (size_t)vd * 2048 + cg16 * 8);
                }
            }
            __syncthreads();   // b0: prev PV done (psq/vts); prev S done (ks/k2s); q-hoist done
            {
                const int krow = t >> 2;
                const int vd   = t >> 3;
                #pragma unroll
                for (int c = 0; c < 2; ++c) {
                    int cg  = (t & 3) * 2 + c;
                    int cgm = (cg + krow) & 7;
                    *(short8*)&ks [krow * 64 + cgm * 8] = kf[c];
                    *(short8*)&k2s[krow * 64 + cgm * 8] = k2f[c];
                    int cg16  = (t & 7) * 2 + c;
                    int cgm16 = (cg16 + vd) & 15;
                    *(short8*)&vts[vd * 128 + cgm16 * 8] = vf[c];
                }
            }
            __syncthreads();   // b1: tiles visible

            // ---- S + P, i-outer (2 frags of 16 k-rows per wave) ----
            #pragma unroll
            for (int i = 0; i < 2; ++i) {
                floatx4 a1[4], a2[4];
                #pragma unroll
                for (int j = 0; j < 4; ++j) { a1[j] = (floatx4)(0.0f); a2[j] = (floatx4)(0.0f); }
                #pragma unroll
                for (int kstep = 0; kstep < 2; ++kstep) {
                    const int gl = kstep * 4 + g;
                    int row = mk + i * 16 + s;
                    int a = row * 64 + ((gl + row) & 7) * 8;
                    short8 ak  = *(const short8*)&ks [a];
                    short8 ak2 = *(const short8*)&k2s[a];
                    #pragma unroll
                    for (int j = 0; j < 4; ++j) {
                        a1[j] = __builtin_amdgcn_mfma_f32_16x16x32_bf16(ak,  bq[kstep][j],  a1[j], 0, 0, 0);
                        a2[j] = __builtin_amdgcn_mfma_f32_16x16x32_bf16(ak2, bq2[kstep][j], a2[j], 0, 0, 0);
                    }
                }
                // P-write for this i: psq region unread by anyone during the loop
                const int kl0   = mk + i * 16 + g * 4;
                const int chunk = kl0 >> 3;
                const int sub   = kl0 & 7;
                if (tk < qt) {
                    #pragma unroll
                    for (int j = 0; j < 4; ++j) {
                        const int ql = nq + j * 16 + s;
                        ushort4 pw;
                        pw.x = f2bf(a1[j][0] * a2[j][0]);
                        pw.y = f2bf(a1[j][1] * a2[j][1]);
                        pw.z = f2bf(a1[j][2] * a2[j][2]);
                        pw.w = f2bf(a1[j][3] * a2[j][3]);
                        *(ushort4*)&psq[ql * 128 + ((chunk + ql) & 15) * 8 + sub] = pw;
                    }
                } else {
                    #pragma unroll
                    for (int j = 0; j < 4; ++j) {
                        const int ql = nq + j * 16 + s;
                        ushort4 pw;
                        pw.x = (kl0 + 0 <= ql) ? f2bf(a1[j][0] * a2[j][0]) : (unsigned short)0;
                        pw.y = (kl0 + 1 <= ql) ? f2bf(a1[j][1] * a2[j][1]) : (unsigned short)0;
                        pw.z = (kl0 + 2 <= ql) ? f2bf(a1[j][2] * a2[j][2]) : (unsigned short)0;
                        pw.w = (kl0 + 3 <= ql) ? f2bf(a1[j][3] * a2[j][3]) : (unsigned short)0;
                        *(ushort4*)&psq[ql * 128 + ((chunk + ql) & 15) * 8 + sub] = pw;
                    }
                }
            }

            __syncthreads();   // b2: psq visible

            // ---- PV: z[q][d] += P[q][k] * vT[d][k] ; wave owns 16 q-rows ----
            const int wm0 = w * 16;
            #pragma unroll
            for (int kstep = 0; kstep < 4; ++kstep) {
                const int cbase = kstep * 4 + g;
                short8 ap, bv[4];
                {
                    int q = wm0 + s;
                    ap = *(const short8*)&psq[q * 128 + ((cbase + q) & 15) * 8];
                }
                #pragma unroll
                for (int jd = 0; jd < 4; ++jd) {
                    int d = jd * 16 + s;
                    bv[jd] = *(const short8*)&vts[d * 128 + ((cbase + d) & 15) * 8];
                }
                #pragma unroll
                for (int jd = 0; jd < 4; ++jd)
                    zac[jd] = __builtin_amdgcn_mfma_f32_16x16x32_bf16(ap, bv[jd], zac[jd], 0, 0, 0);
            }
        }

        // ---- epilogue: z -> split bf16 [hi | lo] into zout[4096][2048] ----
        const size_t zrow0 = (size_t)(b * TSEQ + qt * 128);
        #pragma unroll
        for (int j = 0; j < 4; ++j)
            #pragma unroll
            for (int r = 0; r < 4; ++r) {
                float zv = zac[j][r];
                unsigned short hi = f2bf(zv);
                unsigned short lo = f2bf(zv - bf2f(hi));
                size_t row = zrow0 + w * 16 + g * 4 + r;
                int col = h * 64 + j * 16 + s;
                zout[row * 2048 + col]        = hi;
                zout[row * 2048 + 1024 + col] = lo;
            }
    }
}

// ---------------------------------------------------------------------------
extern "C" void kernel_launch(void* const* d_in, const int* in_sizes, int n_in,
                              void* d_out, int out_size, void* d_ws, size_t ws_size,
                              hipStream_t stream)
{
    const float* x     = (const float*)d_in[0];
    const float* Wq    = (const float*)d_in[1];
    const float* Wk    = (const float*)d_in[2];
    const float* Wq2   = (const float*)d_in[3];
    const float* Wk2   = (const float*)d_in[4];
    const float* Wv    = (const float*)d_in[5];
    const float* Wproj = (const float*)d_in[6];

    // workspace (bytes):
    //   Xp    bf16 [4096][2048] (x-hi packed, later z-split) @ 0      (16,777,216)
    //   Wp    bf16 [6144][2048]                          @ 16,777,216 (25,165,824)
    //         rows [0,1024)    = Wproj [hi|lo]
    //         rows [1024,6144) = Wq,Wk,Wq2,Wk2 (head-interleaved), Wv [hi|dead]
    //   heads bf16 4x[32][2048][64] (q,k,q2,k2)          @ 41,943,040 (33,554,432)
    //   vt    bf16 [32][64][2048]                        @ 75,497,472 ( 8,388,608)
    unsigned short* Xp    = (unsigned short*)d_ws;
    unsigned short* Wp    = (unsigned short*)((char*)d_ws + 16777216);
    unsigned short* heads = (unsigned short*)((char*)d_ws + 41943040);
    unsigned short* vt    = (unsigned short*)((char*)d_ws + 75497472);

    const size_t HS = (size_t)32 * 2048 * 64;
    unsigned short* qh  = heads;
    unsigned short* kh  = heads + 1 * HS;
    unsigned short* q2h = heads + 2 * HS;
    unsigned short* k2h = heads + 3 * HS;

    pack_all_kernel<<<10240, 256, 0, stream>>>(x, Wproj, Wq, Wk, Wq2, Wk2, Wv, Xp, Wp);
    gemm_qkv<<<dim3(16, 16), 512, 0, stream>>>(Xp, Wp + (size_t)1024 * 2048, heads, vt);
    attn_mfma<<<256, 512, 0, stream>>>(qh, q2h, kh, k2h, vt, Xp);
    gemm_proj<<<dim3(32, 8), 256, 0, stream>>>(Xp, Wp, (float*)d_out);
}

// Round 10
// 228.827 us; speedup vs baseline: 1.5348x; 1.0189x over previous
//
#include <hip/hip_runtime.h>
#include <hip/hip_bf16.h>

#define TSEQ 2048
#define NHEAD 16
#define DM 1024
#define NBATCH 2
#define MTOK (NBATCH * TSEQ)   // 4096

typedef __attribute__((ext_vector_type(8))) short short8;
typedef __attribute__((ext_vector_type(4))) float floatx4;
typedef __attribute__((address_space(1))) const void gvoid;
typedef __attribute__((address_space(3))) void lvoid;

static __device__ __forceinline__ unsigned short f2bf(float f) {
    unsigned int u = __float_as_uint(f);
    return (unsigned short)((u + 0x7fffu + ((u >> 16) & 1u)) >> 16);
}
static __device__ __forceinline__ float bf2f(unsigned short h) {
    return __uint_as_float(((unsigned int)h) << 16);
}

// ---------------------------------------------------------------------------
// Pack x and the 6 weight matrices to split bf16 rows.
//   x      -> [hi(1024) | dead]   (1-term qkv; attn overwrites Xp before proj)
//   Wproj  -> [hi | lo]           (3-term proj GEMM needs lo)
//   Wq..Wv -> [hi | dead]         (qkv reads only cols 0..1023)
//   Wq,Wk,Wq2,Wk2 rows additionally PER-HEAD INTERLEAVED:
//     d<32 -> (d>>3)*16 + (d&7) ; d>=32 -> ((d-32)>>3)*16 + 8 + (d&7)
//   so each 16-col C-fragment holds RoPE pairs at lanes cc / cc^8.
// blocks [0,4096) -> x ; [4096,10240) -> weights (1024 blocks each).
// ---------------------------------------------------------------------------
__global__ __launch_bounds__(256)
void pack_all_kernel(const float* __restrict__ x,
                     const float* __restrict__ w0, const float* __restrict__ w1,
                     const float* __restrict__ w2, const float* __restrict__ w3,
                     const float* __restrict__ w4, const float* __restrict__ w5,
                     unsigned short* __restrict__ dstX, unsigned short* __restrict__ dstW)
{
    const float* src;
    unsigned short* dst;
    int gid;
    bool wlo = false, ilv = false;
    if (blockIdx.x < 4096) {
        src = x; dst = dstX;
        gid = blockIdx.x * 256 + threadIdx.x;
    } else {
        int wi = (blockIdx.x - 4096) >> 10;
        const float* srcs[6] = {w0, w1, w2, w3, w4, w5};
        src = srcs[wi];
        dst = dstW + (size_t)wi * 1024 * 2048;
        gid = ((blockIdx.x - 4096) & 1023) * 256 + threadIdx.x;
        wlo = (wi == 0);              // only Wproj needs the lo half
        ilv = (wi >= 1 && wi <= 4);   // Wq, Wk, Wq2, Wk2
    }
    int e   = gid * 4;
    int row = e >> 10;
    int col = e & 1023;
    float4 f = *(const float4*)(src + (size_t)row * 1024 + col);
    ushort4 hi, lo;
    hi.x = f2bf(f.x); lo.x = f2bf(f.x - bf2f(hi.x));
    hi.y = f2bf(f.y); lo.y = f2bf(f.y - bf2f(hi.y));
    hi.z = f2bf(f.z); lo.z = f2bf(f.z - bf2f(hi.z));
    hi.w = f2bf(f.w); lo.w = f2bf(f.w - bf2f(hi.w));
    int drow = row;
    if (ilv) {
        int hh = row >> 6, d = row & 63;
        int dd = (d < 32) ? ((d >> 3) * 16 + (d & 7))
                          : (((d - 32) >> 3) * 16 + 8 + (d & 7));
        drow = hh * 64 + dd;
    }
    *(ushort4*)(dst + (size_t)drow * 2048 + col) = hi;
    if (wlo)
        *(ushort4*)(dst + (size_t)drow * 2048 + 1024 + col) = lo;
}

// ---------------------------------------------------------------------------
// qkv GEMM — 1-TERM hi-only, K=1024 (UNCHANGED):
//   C[4096][5120] = Xhi[4096][1024] . Whi[5120][1024]^T
// Tile 256x320, K-tile 64, 8 waves 2M x 4N, counted vmcnt(8), 16 K-tiles.
// ---------------------------------------------------------------------------
#define VMW(N) asm volatile("s_waitcnt vmcnt(" #N ")" ::: "memory")
#define LGKM0  asm volatile("s_waitcnt lgkmcnt(0)" ::: "memory")

__global__ __launch_bounds__(512, 2)
void gemm_qkv(const unsigned short* __restrict__ Ap,
              const unsigned short* __restrict__ Bp,
              unsigned short* __restrict__ Ch, unsigned short* __restrict__ Vt)
{
    __shared__ __align__(16) unsigned short A0s[2][8192];    // [256][32] each
    __shared__ __align__(16) unsigned short A1s[2][8192];
    __shared__ __align__(16) unsigned short B0s[2][10240];   // [320][32] each
    __shared__ __align__(16) unsigned short B1s[2][10240];

    const int t    = threadIdx.x;
    const int lane = t & 63;
    const int w    = t >> 6;
    const int wm   = w >> 2;          // M-half (0..1): 128 rows
    const int wn   = w & 3;           // N-quarter (0..3): 80 cols
    const int s    = lane & 15;
    const int g    = (lane >> 4) & 3;
    const int row0 = blockIdx.x * 256;
    const int col0 = blockIdx.y * 320;

    // read-side swizzled offsets (element units, 32-wide rows)
    const int cofs  = ((g ^ ((lane >> 1) & 3)) << 3);
    const int addrA = (wm * 128 + s) * 32 + cofs;   // + ii*512
    const int addrB = (wn * 80 + s) * 32 + cofs;    // + nf*512

    // stage-side pre-swizzled global source base (logical chunk per thread)
    const int alc = (t & 3) ^ ((t >> 3) & 3);
    const unsigned short* Ag = Ap + (size_t)(row0 + (t >> 2)) * 2048 + alc * 8;
    const unsigned short* Bg = Bp + (size_t)(col0 + (t >> 2)) * 2048 + alc * 8;

#define STAGE_A(dst, kofs) {                                                                              \
    __builtin_amdgcn_global_load_lds((gvoid*)(Ag + (kofs)),              (lvoid*)((dst) + t * 8),        16, 0, 0); \
    __builtin_amdgcn_global_load_lds((gvoid*)(Ag + (kofs) + 128 * 2048), (lvoid*)((dst) + 4096 + t * 8), 16, 0, 0); }

#define STAGE_B(dst, kofs) {                                                                              \
    __builtin_amdgcn_global_load_lds((gvoid*)(Bg + (kofs)),              (lvoid*)((dst) + t * 8),        16, 0, 0); \
    __builtin_amdgcn_global_load_lds((gvoid*)(Bg + (kofs) + 128 * 2048), (lvoid*)((dst) + 4096 + t * 8), 16, 0, 0); \
    if (t < 256)                                                                                          \
    __builtin_amdgcn_global_load_lds((gvoid*)(Bg + (kofs) + 256 * 2048), (lvoid*)((dst) + 8192 + t * 8), 16, 0, 0); }

    floatx4 acc[8][5];
    #pragma unroll
    for (int ii = 0; ii < 8; ++ii)
        #pragma unroll
        for (int nf = 0; nf < 5; ++nf)
            acc[ii][nf] = (floatx4)(0.0f);

    // ---- prologue: tile0 (kh0,kh1) and tile1 (kh0) ----
    STAGE_A(A0s[0], 0);
    STAGE_B(B0s[0], 0);
    STAGE_A(A1s[0], 32);
    STAGE_B(B1s[0], 32);
    STAGE_A(A0s[1], 64);
    STAGE_B(B0s[1], 64);
    VMW(4);                       // tile0 fully landed (newest 4-5 = tile1 kh0)
    __builtin_amdgcn_s_barrier();
    __builtin_amdgcn_sched_barrier(0);

#define MFMA_CLUSTER(IOFS)                                                                      \
    __builtin_amdgcn_s_setprio(1);                                                              \
    _Pragma("unroll")                                                                           \
    for (int ii = 0; ii < 4; ++ii)                                                              \
        _Pragma("unroll")                                                                       \
        for (int nf = 0; nf < 5; ++nf)                                                          \
            acc[(IOFS) + ii][nf] = __builtin_amdgcn_mfma_f32_16x16x32_bf16(af[ii], bf[nf], acc[(IOFS) + ii][nf], 0, 0, 0); \
    __builtin_amdgcn_s_setprio(0);

#define TILE_BODY(TAU, DO12, DO34, W2, W4)                                                      \
{                                                                                               \
    const int cur_ = (TAU) & 1;                                                                 \
    const unsigned short* a0k = A0s[cur_];                                                      \
    const unsigned short* a1k = A1s[cur_];                                                      \
    const unsigned short* b0k = B0s[cur_];                                                      \
    const unsigned short* b1k = B1s[cur_];                                                      \
    short8 af[4], bf[5];                                                                        \
    /* ---- p1: kh0, M-half0 + B-kh0 read ; stage (TAU+1) A-kh1 ---- */                         \
    _Pragma("unroll")                                                                           \
    for (int ii = 0; ii < 4; ++ii) af[ii] = *(const short8*)&a0k[addrA + ii * 512];             \
    _Pragma("unroll")                                                                           \
    for (int nf = 0; nf < 5; ++nf) bf[nf] = *(const short8*)&b0k[addrB + nf * 512];             \
    if (DO12) STAGE_A(A1s[cur_ ^ 1], ((TAU) + 1) * 64 + 32);                                    \
    LGKM0;                                                                                      \
    __builtin_amdgcn_s_barrier();                                                               \
    __builtin_amdgcn_sched_barrier(0);                                                          \
    MFMA_CLUSTER(0)                                                                             \
    /* ---- p2: kh0, M-half1 ; stage (TAU+1) B-kh1 ; vmcnt ---- */                              \
    _Pragma("unroll")                                                                           \
    for (int ii = 0; ii < 4; ++ii) af[ii] = *(const short8*)&a0k[addrA + (ii + 4) * 512];       \
    if (DO12) STAGE_B(B1s[cur_ ^ 1], ((TAU) + 1) * 64 + 32);                                    \
    LGKM0;                                                                                      \
    W2;                                                                                         \
    __builtin_amdgcn_s_barrier();                                                               \
    __builtin_amdgcn_sched_barrier(0);                                                          \
    MFMA_CLUSTER(4)                                                                             \
    /* ---- p3: kh1, M-half0 + B-kh1 read ; stage (TAU+2) A-kh0 ---- */                         \
    _Pragma("unroll")                                                                           \
    for (int ii = 0; ii < 4; ++ii) af[ii] = *(const short8*)&a1k[addrA + ii * 512];             \
    _Pragma("unroll")                                                                           \
    for (int nf = 0; nf < 5; ++nf) bf[nf] = *(const short8*)&b1k[addrB + nf * 512];             \
    if (DO34) STAGE_A(A0s[cur_], ((TAU) + 2) * 64);                                             \
    LGKM0;                                                                                      \
    __builtin_amdgcn_s_barrier();                                                               \
    __builtin_amdgcn_sched_barrier(0);                                                          \
    MFMA_CLUSTER(0)                                                                             \
    /* ---- p4: kh1, M-half1 ; stage (TAU+2) B-kh0 ; vmcnt ---- */                              \
    _Pragma("unroll")                                                                           \
    for (int ii = 0; ii < 4; ++ii) af[ii] = *(const short8*)&a1k[addrA + (ii + 4) * 512];       \
    if (DO34) STAGE_B(B0s[cur_], ((TAU) + 2) * 64);                                             \
    LGKM0;                                                                                      \
    W4;                                                                                        \
    __builtin_amdgcn_s_barrier();                                                               \
    __builtin_amdgcn_sched_barrier(0);                                                          \
    MFMA_CLUSTER(4)                                                                             \
}

    #pragma unroll 2
    for (int tau = 0; tau < 14; ++tau)
        TILE_BODY(tau, 1, 1, VMW(8), VMW(8));
    TILE_BODY(14, 1, 0, VMW(8), VMW(4));
    TILE_BODY(15, 0, 0, VMW(0), ((void)0));

#undef TILE_BODY
#undef MFMA_CLUSTER
#undef STAGE_A
#undef STAGE_B

    // ---- epilogue: lane-local RoPE (+1/64 q-scale); V transposed ----
    const int cr = (lane >> 4) * 4;
    const int cc = lane & 15;
    const int rwbase = row0 + wm * 128;
    const float L2C = -0.41524101186092029f;  // -log2(10000)/32

    #pragma unroll
    for (int nf = 0; nf < 5; ++nf) {
        const int cg = col0 + wn * 80 + nf * 16;  // global col of this frag
        const int p  = cg >> 10;                  // 0=q 1=k 2=q2 3=k2 4=v
        const int h  = (cg >> 6) & 15;
        const int f  = (cg >> 4) & 3;
        if (p < 4) {
            const float sc  = (p == 0 || p == 2) ? 0.015625f : 1.0f;
            const float inv = exp2f((float)(f * 8 + (cc & 7)) * L2C);
            unsigned short* hp = Ch + (size_t)p * 4194304;
            #pragma unroll
            for (int ii = 0; ii < 8; ++ii) {
                int r0  = rwbase + ii * 16 + cr;
                int bhi = ((r0 >> 11) << 4) + h;
                size_t base = ((size_t)bhi * 2048 + (r0 & 2047)) * 64;
                #pragma unroll
                for (int rr = 0; rr < 4; ++rr) {
                    float tt = (float)((r0 + rr) & 2047);
                    float s0, c0;
                    __sincosf(tt * inv, &s0, &c0);
                    float x  = acc[ii][nf][rr];
                    float xp = __shfl_xor(x, 8, 64);
                    float y  = (cc < 8) ? (x * c0 + xp * s0) : (x * c0 - xp * s0);
                    hp[base + (size_t)rr * 64 + (f * 16 + cc)] = f2bf(y * sc);
                }
            }
        } else {
            #pragma unroll
            for (int ii = 0; ii < 8; ++ii) {
                int r0  = rwbase + ii * 16 + cr;
                int bhi = ((r0 >> 11) << 4) + h;
                int d   = f * 16 + cc;
                ushort4 o;
                o.x = f2bf(acc[ii][nf][0]); o.y = f2bf(acc[ii][nf][1]);
                o.z = f2bf(acc[ii][nf][2]); o.w = f2bf(acc[ii][nf][3]);
                *(ushort4*)(Vt + ((size_t)bhi * 64 + d) * 2048 + (r0 & 2047)) = o;
            }
        }
    }
}

// ---------------------------------------------------------------------------
// Output projection: C = (hiA+loA)*hiB^T + hiA*loB^T (3-term), fp32 out.
// 128x128 template (UNCHANGED): grid (32,8) = 256 blocks = 1/CU,
// 4 waves (wave-tile 64x64), 48 MFMA : 16 ds_reads per K-step, 32 KB LDS.
// ---------------------------------------------------------------------------
__global__ __launch_bounds__(256)
void gemm_proj(const unsigned short* __restrict__ Ap,
               const unsigned short* __restrict__ Bp,
               float* __restrict__ Cf)
{
    __shared__ __align__(16) unsigned short Ah[128 * 32];
    __shared__ __align__(16) unsigned short Al[128 * 32];
    __shared__ __align__(16) unsigned short Bh[128 * 32];
    __shared__ __align__(16) unsigned short Bl[128 * 32];

    const int t    = threadIdx.x;
    const int lane = t & 63;
    const int s    = lane & 15;
    const int row0 = blockIdx.x * 128;
    const int col0 = blockIdx.y * 128;
    const int m0   = ((t >> 6) >> 1) * 64;
    const int n0   = ((t >> 6) & 1) * 64;

    floatx4 acc[4][4];
    #pragma unroll
    for (int i = 0; i < 4; ++i)
        #pragma unroll
        for (int j = 0; j < 4; ++j)
            acc[i][j] = (floatx4)(0.0f);

    const int sr  = t >> 2;
    const int skx = ((t & 3) ^ ((t >> 3) & 3)) * 8;
    char* dA  = (char*)Ah + (size_t)t * 16;
    char* dAl = (char*)Al + (size_t)t * 16;
    char* dB  = (char*)Bh + (size_t)t * 16;
    char* dBl = (char*)Bl + (size_t)t * 16;
    const size_t arow = (size_t)(row0 + sr) * 2048 + skx;
    const size_t brow = (size_t)(col0 + sr) * 2048 + skx;

    #define ISSUE(k0)                                                                         \
    {                                                                                         \
        const unsigned short* ga = Ap + arow + (k0);                                          \
        const unsigned short* gb = Bp + brow + (k0);                                          \
        __builtin_amdgcn_global_load_lds((gvoid*)ga,                 (lvoid*)dA,          16, 0, 0); \
        __builtin_amdgcn_global_load_lds((gvoid*)(ga + 64*2048),     (lvoid*)(dA + 4096), 16, 0, 0); \
        __builtin_amdgcn_global_load_lds((gvoid*)(ga + 1024),        (lvoid*)dAl,         16, 0, 0); \
        __builtin_amdgcn_global_load_lds((gvoid*)(ga + 1024+64*2048),(lvoid*)(dAl + 4096),16, 0, 0); \
        __builtin_amdgcn_global_load_lds((gvoid*)gb,                 (lvoid*)dB,          16, 0, 0); \
        __builtin_amdgcn_global_load_lds((gvoid*)(gb + 64*2048),     (lvoid*)(dB + 4096), 16, 0, 0); \
        __builtin_amdgcn_global_load_lds((gvoid*)(gb + 1024),        (lvoid*)dBl,         16, 0, 0); \
        __builtin_amdgcn_global_load_lds((gvoid*)(gb + 1024+64*2048),(lvoid*)(dBl + 4096),16, 0, 0); \
    }

    const int cofs = (((lane >> 4) ^ ((lane >> 1) & 3)) << 3);

    ISSUE(0);
    for (int ks = 0; ks < 32; ++ks) {
        __syncthreads();
        short8 ahf[4], alf[4], bhf[4], blf[4];
        #pragma unroll
        for (int i = 0; i < 4; ++i) {
            int ra = (m0 + i * 16 + s) * 32 + cofs;
            ahf[i] = *(const short8*)&Ah[ra];
            alf[i] = *(const short8*)&Al[ra];
        }
        #pragma unroll
        for (int j = 0; j < 4; ++j) {
            int rb = (n0 + j * 16 + s) * 32 + cofs;
            bhf[j] = *(const short8*)&Bh[rb];
            blf[j] = *(const short8*)&Bl[rb];
        }
        #pragma unroll
        for (int i = 0; i < 4; ++i)
            #pragma unroll
            for (int j = 0; j < 4; ++j) {
                acc[i][j] = __builtin_amdgcn_mfma_f32_16x16x32_bf16(ahf[i], bhf[j], acc[i][j], 0, 0, 0);
                acc[i][j] = __builtin_amdgcn_mfma_f32_16x16x32_bf16(alf[i], bhf[j], acc[i][j], 0, 0, 0);
                acc[i][j] = __builtin_amdgcn_mfma_f32_16x16x32_bf16(ahf[i], blf[j], acc[i][j], 0, 0, 0);
            }
        __syncthreads();
        if (ks + 1 < 32) ISSUE((ks + 1) * 32);
    }
    #undef ISSUE

    const int cr = (lane >> 4) * 4;
    const int cc = lane & 15;
    #pragma unroll
    for (int i = 0; i < 4; ++i)
        #pragma unroll
        for (int j = 0; j < 4; ++j) {
            int r = row0 + m0 + i * 16 + cr;
            int c = col0 + n0 + j * 16 + cc;
            #pragma unroll
            for (int rr = 0; rr < 4; ++rr)
                Cf[(size_t)(r + rr) * 1024 + c] = acc[i][j][rr];
        }
}

// ---------------------------------------------------------------------------
// MFMA bilinear causal attention — 8-wave, balanced 2-pass, XCD-aware
// (round-9 structure) + T14 ASYNC-STAGE SPLIT: K/V global loads for tile
// tk+1 are issued AFTER b1, so their L2/HBM latency hides under the whole
// S+P+PV compute phase instead of draining right after b0 (the compiler's
// vmcnt(0) before ds_writes now finds data already landed — the loads were
// issued one full iteration earlier). sched_barrier(0) pins the loads
// before S+P so the compiler can't sink them. WAR on kf/k2f/vf is safe:
// ds_writes(tk) read the regs at issue, before LOADKV(tk+1) issues.
// Grid 256 = 1 block/CU, every block exactly 17 tile-iters. LDS 80 KB.
// ---------------------------------------------------------------------------
__global__ __launch_bounds__(512, 2)
void attn_mfma(const unsigned short* __restrict__ qh, const unsigned short* __restrict__ q2h,
               const unsigned short* __restrict__ kh, const unsigned short* __restrict__ k2h,
               const unsigned short* __restrict__ vt, unsigned short* __restrict__ zout)
{
    __shared__ __align__(16) unsigned short smem[40960];   // 80 KB
    unsigned short* qs  = smem;              // [128][64] rot8 (init only)
    unsigned short* q2s = smem + 8192;
    unsigned short* psq = smem;              // [128][128] rot16, overlays qs/q2s
    unsigned short* ks  = smem + 16384;      // [128][64] rot8
    unsigned short* k2s = smem + 24576;
    unsigned short* vts = smem + 32768;      // [64][128] rot16

    const int bid  = blockIdx.x;
    const int xcd  = bid & 7;
    const int slot = bid >> 3;          // 0..31
    const int hh   = slot >> 3;         // 0..3
    const int pr   = slot & 7;          // 0..7 (pair index)
    const int bh   = xcd * 4 + hh;
    const int t  = threadIdx.x;
    const int lane = t & 63;
    const int w    = t >> 6;          // 0..7
    const int s    = lane & 15;
    const int g    = lane >> 4;
    const int mk   = (w >> 1) * 32;   // 4-way k-split: 32 rows/wave
    const int nq   = (w & 1) * 64;    // 2-way q-split

    const int b = bh >> 4, h = bh & 15;

    short8 kf[2], k2f[2], vf[2];

#define LOADKV(TK) {                                                                \
    const unsigned short* kb  = kh  + ((size_t)bh * 2048 + (TK) * 128) * 64;        \
    const unsigned short* k2b = k2h + ((size_t)bh * 2048 + (TK) * 128) * 64;        \
    const unsigned short* vb  = vt  + (size_t)bh * 131072 + (TK) * 128;             \
    const int krow_ = t >> 2;                                                       \
    const int vd_   = t >> 3;                                                       \
    _Pragma("unroll")                                                               \
    for (int c = 0; c < 2; ++c) {                                                   \
        int cg_ = (t & 3) * 2 + c;                                                  \
        kf[c]  = *(const short8*)(kb  + (size_t)krow_ * 64 + cg_ * 8);              \
        k2f[c] = *(const short8*)(k2b + (size_t)krow_ * 64 + cg_ * 8);              \
        int cg16_ = (t & 7) * 2 + c;                                                \
        vf[c]  = *(const short8*)(vb + (size_t)vd_ * 2048 + cg16_ * 8);             \
    } }

    #pragma unroll
    for (int pass = 0; pass < 2; ++pass) {
        const int qt = pass ? pr : (15 - pr);

        __syncthreads();   // prev pass's psq reads done before qs overwrite

        // issue first K/V tile loads early: latency overlaps q staging + hoist
        LOADKV(0);

        // ---- stage q, q2 for this q-tile, then hoist frags to registers ----
        {
            const unsigned short* qb  = qh  + ((size_t)bh * 2048 + qt * 128) * 64;
            const unsigned short* q2b = q2h + ((size_t)bh * 2048 + qt * 128) * 64;
            const int row = t >> 2;                    // 0..127
            #pragma unroll
            for (int c = 0; c < 2; ++c) {
                int cg  = (t & 3) * 2 + c;             // 0..7
                short8 a  = *(const short8*)(qb  + (size_t)row * 64 + cg * 8);
                short8 a2 = *(const short8*)(q2b + (size_t)row * 64 + cg * 8);
                int cgm = (cg + row) & 7;
                *(short8*)&qs [row * 64 + cgm * 8] = a;
                *(short8*)&q2s[row * 64 + cgm * 8] = a2;
            }
        }
        __syncthreads();
        short8 bq[2][4], bq2[2][4];
        #pragma unroll
        for (int kstep = 0; kstep < 2; ++kstep) {
            const int gl = kstep * 4 + g;
            #pragma unroll
            for (int j = 0; j < 4; ++j) {
                int row = nq + j * 16 + s;
                int a = row * 64 + ((gl + row) & 7) * 8;
                bq[kstep][j]  = *(const short8*)&qs [a];
                bq2[kstep][j] = *(const short8*)&q2s[a];
            }
        }

        floatx4 zac[4];
        #pragma unroll
        for (int j = 0; j < 4; ++j)
            zac[j] = (floatx4)(0.0f);

        for (int tk = 0; tk <= qt; ++tk) {
            __syncthreads();   // b0: prev PV done (psq/vts); prev S done (ks/k2s); q-hoist done
            {
                // ds_writes(tk): consumes kf/k2f/vf loaded one iteration ago
                // (compiler's vmcnt drain here finds data already landed)
                const int krow = t >> 2;
                const int vd   = t >> 3;
                #pragma unroll
                for (int c = 0; c < 2; ++c) {
                    int cg  = (t & 3) * 2 + c;
                    int cgm = (cg + krow) & 7;
                    *(short8*)&ks [krow * 64 + cgm * 8] = kf[c];
                    *(short8*)&k2s[krow * 64 + cgm * 8] = k2f[c];
                    int cg16  = (t & 7) * 2 + c;
                    int cgm16 = (cg16 + vd) & 15;
                    *(short8*)&vts[vd * 128 + cgm16 * 8] = vf[c];
                }
            }
            __syncthreads();   // b1: tiles visible

            // ---- T14: issue next tile's K/V loads; latency hides under S+P+PV
            if (tk < qt) LOADKV(tk + 1);
            __builtin_amdgcn_sched_barrier(0);

            // ---- S + P, i-outer (2 frags of 16 k-rows per wave) ----
            #pragma unroll
            for (int i = 0; i < 2; ++i) {
                floatx4 a1[4], a2[4];
                #pragma unroll
                for (int j = 0; j < 4; ++j) { a1[j] = (floatx4)(0.0f); a2[j] = (floatx4)(0.0f); }
                #pragma unroll
                for (int kstep = 0; kstep < 2; ++kstep) {
                    const int gl = kstep * 4 + g;
                    int row = mk + i * 16 + s;
                    int a = row * 64 + ((gl + row) & 7) * 8;
                    short8 ak  = *(const short8*)&ks [a];
                    short8 ak2 = *(const short8*)&k2s[a];
                    #pragma unroll
                    for (int j = 0; j < 4; ++j) {
                        a1[j] = __builtin_amdgcn_mfma_f32_16x16x32_bf16(ak,  bq[kstep][j],  a1[j], 0, 0, 0);
                        a2[j] = __builtin_amdgcn_mfma_f32_16x16x32_bf16(ak2, bq2[kstep][j], a2[j], 0, 0, 0);
                    }
                }
                // P-write for this i: psq region unread by anyone during the loop
                const int kl0   = mk + i * 16 + g * 4;
                const int chunk = kl0 >> 3;
                const int sub   = kl0 & 7;
                if (tk < qt) {
                    #pragma unroll
                    for (int j = 0; j < 4; ++j) {
                        const int ql = nq + j * 16 + s;
                        ushort4 pw;
                        pw.x = f2bf(a1[j][0] * a2[j][0]);
                        pw.y = f2bf(a1[j][1] * a2[j][1]);
                        pw.z = f2bf(a1[j][2] * a2[j][2]);
                        pw.w = f2bf(a1[j][3] * a2[j][3]);
                        *(ushort4*)&psq[ql * 128 + ((chunk + ql) & 15) * 8 + sub] = pw;
                    }
                } else {
                    #pragma unroll
                    for (int j = 0; j < 4; ++j) {
                        const int ql = nq + j * 16 + s;
                        ushort4 pw;
                        pw.x = (kl0 + 0 <= ql) ? f2bf(a1[j][0] * a2[j][0]) : (unsigned short)0;
                        pw.y = (kl0 + 1 <= ql) ? f2bf(a1[j][1] * a2[j][1]) : (unsigned short)0;
                        pw.z = (kl0 + 2 <= ql) ? f2bf(a1[j][2] * a2[j][2]) : (unsigned short)0;
                        pw.w = (kl0 + 3 <= ql) ? f2bf(a1[j][3] * a2[j][3]) : (unsigned short)0;
                        *(ushort4*)&psq[ql * 128 + ((chunk + ql) & 15) * 8 + sub] = pw;
                    }
                }
            }

            __syncthreads();   // b2: psq visible

            // ---- PV: z[q][d] += P[q][k] * vT[d][k] ; wave owns 16 q-rows ----
            const int wm0 = w * 16;
            #pragma unroll
            for (int kstep = 0; kstep < 4; ++kstep) {
                const int cbase = kstep * 4 + g;
                short8 ap, bv[4];
                {
                    int q = wm0 + s;
                    ap = *(const short8*)&psq[q * 128 + ((cbase + q) & 15) * 8];
                }
                #pragma unroll
                for (int jd = 0; jd < 4; ++jd) {
                    int d = jd * 16 + s;
                    bv[jd] = *(const short8*)&vts[d * 128 + ((cbase + d) & 15) * 8];
                }
                #pragma unroll
                for (int jd = 0; jd < 4; ++jd)
                    zac[jd] = __builtin_amdgcn_mfma_f32_16x16x32_bf16(ap, bv[jd], zac[jd], 0, 0, 0);
            }
        }

        // ---- epilogue: z -> split bf16 [hi | lo] into zout[4096][2048] ----
        const size_t zrow0 = (size_t)(b * TSEQ + qt * 128);
        #pragma unroll
        for (int j = 0; j < 4; ++j)
            #pragma unroll
            for (int r = 0; r < 4; ++r) {
                float zv = zac[j][r];
                unsigned short hi = f2bf(zv);
                unsigned short lo = f2bf(zv - bf2f(hi));
                size_t row = zrow0 + w * 16 + g * 4 + r;
                int col = h * 64 + j * 16 + s;
                zout[row * 2048 + col]        = hi;
                zout[row * 2048 + 1024 + col] = lo;
            }
    }
#undef LOADKV
}

// ---------------------------------------------------------------------------
extern "C" void kernel_launch(void* const* d_in, const int* in_sizes, int n_in,
                              void* d_out, int out_size, void* d_ws, size_t ws_size,
                              hipStream_t stream)
{
    const float* x     = (const float*)d_in[0];
    const float* Wq    = (const float*)d_in[1];
    const float* Wk    = (const float*)d_in[2];
    const float* Wq2   = (const float*)d_in[3];
    const float* Wk2   = (const float*)d_in[4];
    const float* Wv    = (const float*)d_in[5];
    const float* Wproj = (const float*)d_in[6];

    // workspace (bytes):
    //   Xp    bf16 [4096][2048] (x-hi packed, later z-split) @ 0      (16,777,216)
    //   Wp    bf16 [6144][2048]                          @ 16,777,216 (25,165,824)
    //         rows [0,1024)    = Wproj [hi|lo]
    //         rows [1024,6144) = Wq,Wk,Wq2,Wk2 (head-interleaved), Wv [hi|dead]
    //   heads bf16 4x[32][2048][64] (q,k,q2,k2)          @ 41,943,040 (33,554,432)
    //   vt    bf16 [32][64][2048]                        @ 75,497,472 ( 8,388,608)
    unsigned short* Xp    = (unsigned short*)d_ws;
    unsigned short* Wp    = (unsigned short*)((char*)d_ws + 16777216);
    unsigned short* heads = (unsigned short*)((char*)d_ws + 41943040);
    unsigned short* vt    = (unsigned short*)((char*)d_ws + 75497472);

    const size_t HS = (size_t)32 * 2048 * 64;
    unsigned short* qh  = heads;
    unsigned short* kh  = heads + 1 * HS;
    unsigned short* q2h = heads + 2 * HS;
    unsigned short* k2h = heads + 3 * HS;

    pack_all_kernel<<<10240, 256, 0, stream>>>(x, Wproj, Wq, Wk, Wq2, Wk2, Wv, Xp, Wp);
    gemm_qkv<<<dim3(16, 16), 512, 0, stream>>>(Xp, Wp + (size_t)1024 * 2048, heads, vt);
    attn_mfma<<<256, 512, 0, stream>>>(qh, q2h, kh, k2h, vt, Xp);
    gemm_proj<<<dim3(32, 8), 256, 0, stream>>>(Xp, Wp, (float*)d_out);
}

// Round 11
// 227.937 us; speedup vs baseline: 1.5408x; 1.0039x over previous
//
#include <hip/hip_runtime.h>
#include <hip/hip_bf16.h>

#define TSEQ 2048
#define NHEAD 16
#define DM 1024
#define NBATCH 2
#define MTOK (NBATCH * TSEQ)   // 4096

typedef __attribute__((ext_vector_type(8))) short short8;
typedef __attribute__((ext_vector_type(4))) float floatx4;
typedef __attribute__((address_space(1))) const void gvoid;
typedef __attribute__((address_space(3))) void lvoid;

static __device__ __forceinline__ unsigned short f2bf(float f) {
    unsigned int u = __float_as_uint(f);
    return (unsigned short)((u + 0x7fffu + ((u >> 16) & 1u)) >> 16);
}
static __device__ __forceinline__ float bf2f(unsigned short h) {
    return __uint_as_float(((unsigned int)h) << 16);
}

// ---------------------------------------------------------------------------
// Pack x and the 6 weight matrices to split bf16 rows.
//   x      -> [hi(1024) | dead]   (1-term qkv; attn overwrites Xp before proj)
//   Wproj  -> [hi | lo]           (3-term proj GEMM needs lo)
//   Wq..Wv -> [hi | dead]         (qkv reads only cols 0..1023)
//   Wq,Wk,Wq2,Wk2 rows additionally PER-HEAD INTERLEAVED:
//     d<32 -> (d>>3)*16 + (d&7) ; d>=32 -> ((d-32)>>3)*16 + 8 + (d&7)
//   so each 16-col C-fragment holds RoPE pairs at lanes cc / cc^8.
// blocks [0,4096) -> x ; [4096,10240) -> weights (1024 blocks each).
// ---------------------------------------------------------------------------
__global__ __launch_bounds__(256)
void pack_all_kernel(const float* __restrict__ x,
                     const float* __restrict__ w0, const float* __restrict__ w1,
                     const float* __restrict__ w2, const float* __restrict__ w3,
                     const float* __restrict__ w4, const float* __restrict__ w5,
                     unsigned short* __restrict__ dstX, unsigned short* __restrict__ dstW)
{
    const float* src;
    unsigned short* dst;
    int gid;
    bool wlo = false, ilv = false;
    if (blockIdx.x < 4096) {
        src = x; dst = dstX;
        gid = blockIdx.x * 256 + threadIdx.x;
    } else {
        int wi = (blockIdx.x - 4096) >> 10;
        const float* srcs[6] = {w0, w1, w2, w3, w4, w5};
        src = srcs[wi];
        dst = dstW + (size_t)wi * 1024 * 2048;
        gid = ((blockIdx.x - 4096) & 1023) * 256 + threadIdx.x;
        wlo = (wi == 0);              // only Wproj needs the lo half
        ilv = (wi >= 1 && wi <= 4);   // Wq, Wk, Wq2, Wk2
    }
    int e   = gid * 4;
    int row = e >> 10;
    int col = e & 1023;
    float4 f = *(const float4*)(src + (size_t)row * 1024 + col);
    ushort4 hi, lo;
    hi.x = f2bf(f.x); lo.x = f2bf(f.x - bf2f(hi.x));
    hi.y = f2bf(f.y); lo.y = f2bf(f.y - bf2f(hi.y));
    hi.z = f2bf(f.z); lo.z = f2bf(f.z - bf2f(hi.z));
    hi.w = f2bf(f.w); lo.w = f2bf(f.w - bf2f(hi.w));
    int drow = row;
    if (ilv) {
        int hh = row >> 6, d = row & 63;
        int dd = (d < 32) ? ((d >> 3) * 16 + (d & 7))
                          : (((d - 32) >> 3) * 16 + 8 + (d & 7));
        drow = hh * 64 + dd;
    }
    *(ushort4*)(dst + (size_t)drow * 2048 + col) = hi;
    if (wlo)
        *(ushort4*)(dst + (size_t)drow * 2048 + 1024 + col) = lo;
}

// ---------------------------------------------------------------------------
// qkv GEMM — 1-TERM hi-only, K=1024 (UNCHANGED):
//   C[4096][5120] = Xhi[4096][1024] . Whi[5120][1024]^T
// Tile 256x320, K-tile 64, 8 waves 2M x 4N, counted vmcnt(8), 16 K-tiles.
// ---------------------------------------------------------------------------
#define VMW(N) asm volatile("s_waitcnt vmcnt(" #N ")" ::: "memory")
#define LGKM0  asm volatile("s_waitcnt lgkmcnt(0)" ::: "memory")

__global__ __launch_bounds__(512, 2)
void gemm_qkv(const unsigned short* __restrict__ Ap,
              const unsigned short* __restrict__ Bp,
              unsigned short* __restrict__ Ch, unsigned short* __restrict__ Vt)
{
    __shared__ __align__(16) unsigned short A0s[2][8192];    // [256][32] each
    __shared__ __align__(16) unsigned short A1s[2][8192];
    __shared__ __align__(16) unsigned short B0s[2][10240];   // [320][32] each
    __shared__ __align__(16) unsigned short B1s[2][10240];

    const int t    = threadIdx.x;
    const int lane = t & 63;
    const int w    = t >> 6;
    const int wm   = w >> 2;          // M-half (0..1): 128 rows
    const int wn   = w & 3;           // N-quarter (0..3): 80 cols
    const int s    = lane & 15;
    const int g    = (lane >> 4) & 3;
    const int row0 = blockIdx.x * 256;
    const int col0 = blockIdx.y * 320;

    // read-side swizzled offsets (element units, 32-wide rows)
    const int cofs  = ((g ^ ((lane >> 1) & 3)) << 3);
    const int addrA = (wm * 128 + s) * 32 + cofs;   // + ii*512
    const int addrB = (wn * 80 + s) * 32 + cofs;    // + nf*512

    // stage-side pre-swizzled global source base (logical chunk per thread)
    const int alc = (t & 3) ^ ((t >> 3) & 3);
    const unsigned short* Ag = Ap + (size_t)(row0 + (t >> 2)) * 2048 + alc * 8;
    const unsigned short* Bg = Bp + (size_t)(col0 + (t >> 2)) * 2048 + alc * 8;

#define STAGE_A(dst, kofs) {                                                                              \
    __builtin_amdgcn_global_load_lds((gvoid*)(Ag + (kofs)),              (lvoid*)((dst) + t * 8),        16, 0, 0); \
    __builtin_amdgcn_global_load_lds((gvoid*)(Ag + (kofs) + 128 * 2048), (lvoid*)((dst) + 4096 + t * 8), 16, 0, 0); }

#define STAGE_B(dst, kofs) {                                                                              \
    __builtin_amdgcn_global_load_lds((gvoid*)(Bg + (kofs)),              (lvoid*)((dst) + t * 8),        16, 0, 0); \
    __builtin_amdgcn_global_load_lds((gvoid*)(Bg + (kofs) + 128 * 2048), (lvoid*)((dst) + 4096 + t * 8), 16, 0, 0); \
    if (t < 256)                                                                                          \
    __builtin_amdgcn_global_load_lds((gvoid*)(Bg + (kofs) + 256 * 2048), (lvoid*)((dst) + 8192 + t * 8), 16, 0, 0); }

    floatx4 acc[8][5];
    #pragma unroll
    for (int ii = 0; ii < 8; ++ii)
        #pragma unroll
        for (int nf = 0; nf < 5; ++nf)
            acc[ii][nf] = (floatx4)(0.0f);

    // ---- prologue: tile0 (kh0,kh1) and tile1 (kh0) ----
    STAGE_A(A0s[0], 0);
    STAGE_B(B0s[0], 0);
    STAGE_A(A1s[0], 32);
    STAGE_B(B1s[0], 32);
    STAGE_A(A0s[1], 64);
    STAGE_B(B0s[1], 64);
    VMW(4);                       // tile0 fully landed (newest 4-5 = tile1 kh0)
    __builtin_amdgcn_s_barrier();
    __builtin_amdgcn_sched_barrier(0);

#define MFMA_CLUSTER(IOFS)                                                                      \
    __builtin_amdgcn_s_setprio(1);                                                              \
    _Pragma("unroll")                                                                           \
    for (int ii = 0; ii < 4; ++ii)                                                              \
        _Pragma("unroll")                                                                       \
        for (int nf = 0; nf < 5; ++nf)                                                          \
            acc[(IOFS) + ii][nf] = __builtin_amdgcn_mfma_f32_16x16x32_bf16(af[ii], bf[nf], acc[(IOFS) + ii][nf], 0, 0, 0); \
    __builtin_amdgcn_s_setprio(0);

#define TILE_BODY(TAU, DO12, DO34, W2, W4)                                                      \
{                                                                                               \
    const int cur_ = (TAU) & 1;                                                                 \
    const unsigned short* a0k = A0s[cur_];                                                      \
    const unsigned short* a1k = A1s[cur_];                                                      \
    const unsigned short* b0k = B0s[cur_];                                                      \
    const unsigned short* b1k = B1s[cur_];                                                      \
    short8 af[4], bf[5];                                                                        \
    /* ---- p1: kh0, M-half0 + B-kh0 read ; stage (TAU+1) A-kh1 ---- */                         \
    _Pragma("unroll")                                                                           \
    for (int ii = 0; ii < 4; ++ii) af[ii] = *(const short8*)&a0k[addrA + ii * 512];             \
    _Pragma("unroll")                                                                           \
    for (int nf = 0; nf < 5; ++nf) bf[nf] = *(const short8*)&b0k[addrB + nf * 512];             \
    if (DO12) STAGE_A(A1s[cur_ ^ 1], ((TAU) + 1) * 64 + 32);                                    \
    LGKM0;                                                                                      \
    __builtin_amdgcn_s_barrier();                                                               \
    __builtin_amdgcn_sched_barrier(0);                                                          \
    MFMA_CLUSTER(0)                                                                             \
    /* ---- p2: kh0, M-half1 ; stage (TAU+1) B-kh1 ; vmcnt ---- */                              \
    _Pragma("unroll")                                                                           \
    for (int ii = 0; ii < 4; ++ii) af[ii] = *(const short8*)&a0k[addrA + (ii + 4) * 512];       \
    if (DO12) STAGE_B(B1s[cur_ ^ 1], ((TAU) + 1) * 64 + 32);                                    \
    LGKM0;                                                                                      \
    W2;                                                                                         \
    __builtin_amdgcn_s_barrier();                                                               \
    __builtin_amdgcn_sched_barrier(0);                                                          \
    MFMA_CLUSTER(4)                                                                             \
    /* ---- p3: kh1, M-half0 + B-kh1 read ; stage (TAU+2) A-kh0 ---- */                         \
    _Pragma("unroll")                                                                           \
    for (int ii = 0; ii < 4; ++ii) af[ii] = *(const short8*)&a1k[addrA + ii * 512];             \
    _Pragma("unroll")                                                                           \
    for (int nf = 0; nf < 5; ++nf) bf[nf] = *(const short8*)&b1k[addrB + nf * 512];             \
    if (DO34) STAGE_A(A0s[cur_], ((TAU) + 2) * 64);                                             \
    LGKM0;                                                                                      \
    __builtin_amdgcn_s_barrier();                                                               \
    __builtin_amdgcn_sched_barrier(0);                                                          \
    MFMA_CLUSTER(0)                                                                             \
    /* ---- p4: kh1, M-half1 ; stage (TAU+2) B-kh0 ; vmcnt ---- */                              \
    _Pragma("unroll")                                                                           \
    for (int ii = 0; ii < 4; ++ii) af[ii] = *(const short8*)&a1k[addrA + (ii + 4) * 512];       \
    if (DO34) STAGE_B(B0s[cur_], ((TAU) + 2) * 64);                                             \
    LGKM0;                                                                                      \
    W4;                                                                                        \
    __builtin_amdgcn_s_barrier();                                                               \
    __builtin_amdgcn_sched_barrier(0);                                                          \
    MFMA_CLUSTER(4)                                                                             \
}

    #pragma unroll 2
    for (int tau = 0; tau < 14; ++tau)
        TILE_BODY(tau, 1, 1, VMW(8), VMW(8));
    TILE_BODY(14, 1, 0, VMW(8), VMW(4));
    TILE_BODY(15, 0, 0, VMW(0), ((void)0));

#undef TILE_BODY
#undef MFMA_CLUSTER
#undef STAGE_A
#undef STAGE_B

    // ---- epilogue: lane-local RoPE (+1/64 q-scale); V transposed ----
    const int cr = (lane >> 4) * 4;
    const int cc = lane & 15;
    const int rwbase = row0 + wm * 128;
    const float L2C = -0.41524101186092029f;  // -log2(10000)/32

    #pragma unroll
    for (int nf = 0; nf < 5; ++nf) {
        const int cg = col0 + wn * 80 + nf * 16;  // global col of this frag
        const int p  = cg >> 10;                  // 0=q 1=k 2=q2 3=k2 4=v
        const int h  = (cg >> 6) & 15;
        const int f  = (cg >> 4) & 3;
        if (p < 4) {
            const float sc  = (p == 0 || p == 2) ? 0.015625f : 1.0f;
            const float inv = exp2f((float)(f * 8 + (cc & 7)) * L2C);
            unsigned short* hp = Ch + (size_t)p * 4194304;
            #pragma unroll
            for (int ii = 0; ii < 8; ++ii) {
                int r0  = rwbase + ii * 16 + cr;
                int bhi = ((r0 >> 11) << 4) + h;
                size_t base = ((size_t)bhi * 2048 + (r0 & 2047)) * 64;
                #pragma unroll
                for (int rr = 0; rr < 4; ++rr) {
                    float tt = (float)((r0 + rr) & 2047);
                    float s0, c0;
                    __sincosf(tt * inv, &s0, &c0);
                    float x  = acc[ii][nf][rr];
                    float xp = __shfl_xor(x, 8, 64);
                    float y  = (cc < 8) ? (x * c0 + xp * s0) : (x * c0 - xp * s0);
                    hp[base + (size_t)rr * 64 + (f * 16 + cc)] = f2bf(y * sc);
                }
            }
        } else {
            #pragma unroll
            for (int ii = 0; ii < 8; ++ii) {
                int r0  = rwbase + ii * 16 + cr;
                int bhi = ((r0 >> 11) << 4) + h;
                int d   = f * 16 + cc;
                ushort4 o;
                o.x = f2bf(acc[ii][nf][0]); o.y = f2bf(acc[ii][nf][1]);
                o.z = f2bf(acc[ii][nf][2]); o.w = f2bf(acc[ii][nf][3]);
                *(ushort4*)(Vt + ((size_t)bhi * 64 + d) * 2048 + (r0 & 2047)) = o;
            }
        }
    }
}

// ---------------------------------------------------------------------------
// Output projection: C = (hiA+loA)*hiB^T + hiA*loB^T (3-term), fp32 out.
// 128x128 template (UNCHANGED): grid (32,8) = 256 blocks = 1/CU,
// 4 waves (wave-tile 64x64), 48 MFMA : 16 ds_reads per K-step, 32 KB LDS.
// ---------------------------------------------------------------------------
__global__ __launch_bounds__(256)
void gemm_proj(const unsigned short* __restrict__ Ap,
               const unsigned short* __restrict__ Bp,
               float* __restrict__ Cf)
{
    __shared__ __align__(16) unsigned short Ah[128 * 32];
    __shared__ __align__(16) unsigned short Al[128 * 32];
    __shared__ __align__(16) unsigned short Bh[128 * 32];
    __shared__ __align__(16) unsigned short Bl[128 * 32];

    const int t    = threadIdx.x;
    const int lane = t & 63;
    const int s    = lane & 15;
    const int row0 = blockIdx.x * 128;
    const int col0 = blockIdx.y * 128;
    const int m0   = ((t >> 6) >> 1) * 64;
    const int n0   = ((t >> 6) & 1) * 64;

    floatx4 acc[4][4];
    #pragma unroll
    for (int i = 0; i < 4; ++i)
        #pragma unroll
        for (int j = 0; j < 4; ++j)
            acc[i][j] = (floatx4)(0.0f);

    const int sr  = t >> 2;
    const int skx = ((t & 3) ^ ((t >> 3) & 3)) * 8;
    char* dA  = (char*)Ah + (size_t)t * 16;
    char* dAl = (char*)Al + (size_t)t * 16;
    char* dB  = (char*)Bh + (size_t)t * 16;
    char* dBl = (char*)Bl + (size_t)t * 16;
    const size_t arow = (size_t)(row0 + sr) * 2048 + skx;
    const size_t brow = (size_t)(col0 + sr) * 2048 + skx;

    #define ISSUE(k0)                                                                         \
    {                                                                                         \
        const unsigned short* ga = Ap + arow + (k0);                                          \
        const unsigned short* gb = Bp + brow + (k0);                                          \
        __builtin_amdgcn_global_load_lds((gvoid*)ga,                 (lvoid*)dA,          16, 0, 0); \
        __builtin_amdgcn_global_load_lds((gvoid*)(ga + 64*2048),     (lvoid*)(dA + 4096), 16, 0, 0); \
        __builtin_amdgcn_global_load_lds((gvoid*)(ga + 1024),        (lvoid*)dAl,         16, 0, 0); \
        __builtin_amdgcn_global_load_lds((gvoid*)(ga + 1024+64*2048),(lvoid*)(dAl + 4096),16, 0, 0); \
        __builtin_amdgcn_global_load_lds((gvoid*)gb,                 (lvoid*)dB,          16, 0, 0); \
        __builtin_amdgcn_global_load_lds((gvoid*)(gb + 64*2048),     (lvoid*)(dB + 4096), 16, 0, 0); \
        __builtin_amdgcn_global_load_lds((gvoid*)(gb + 1024),        (lvoid*)dBl,         16, 0, 0); \
        __builtin_amdgcn_global_load_lds((gvoid*)(gb + 1024+64*2048),(lvoid*)(dBl + 4096),16, 0, 0); \
    }

    const int cofs = (((lane >> 4) ^ ((lane >> 1) & 3)) << 3);

    ISSUE(0);
    for (int ks = 0; ks < 32; ++ks) {
        __syncthreads();
        short8 ahf[4], alf[4], bhf[4], blf[4];
        #pragma unroll
        for (int i = 0; i < 4; ++i) {
            int ra = (m0 + i * 16 + s) * 32 + cofs;
            ahf[i] = *(const short8*)&Ah[ra];
            alf[i] = *(const short8*)&Al[ra];
        }
        #pragma unroll
        for (int j = 0; j < 4; ++j) {
            int rb = (n0 + j * 16 + s) * 32 + cofs;
            bhf[j] = *(const short8*)&Bh[rb];
            blf[j] = *(const short8*)&Bl[rb];
        }
        #pragma unroll
        for (int i = 0; i < 4; ++i)
            #pragma unroll
            for (int j = 0; j < 4; ++j) {
                acc[i][j] = __builtin_amdgcn_mfma_f32_16x16x32_bf16(ahf[i], bhf[j], acc[i][j], 0, 0, 0);
                acc[i][j] = __builtin_amdgcn_mfma_f32_16x16x32_bf16(alf[i], bhf[j], acc[i][j], 0, 0, 0);
                acc[i][j] = __builtin_amdgcn_mfma_f32_16x16x32_bf16(ahf[i], blf[j], acc[i][j], 0, 0, 0);
            }
        __syncthreads();
        if (ks + 1 < 32) ISSUE((ks + 1) * 32);
    }
    #undef ISSUE

    const int cr = (lane >> 4) * 4;
    const int cc = lane & 15;
    #pragma unroll
    for (int i = 0; i < 4; ++i)
        #pragma unroll
        for (int j = 0; j < 4; ++j) {
            int r = row0 + m0 + i * 16 + cr;
            int c = col0 + n0 + j * 16 + cc;
            #pragma unroll
            for (int rr = 0; rr < 4; ++rr)
                Cf[(size_t)(r + rr) * 1024 + c] = acc[i][j][rr];
        }
}

// ---------------------------------------------------------------------------
// MFMA bilinear causal attention — 8-wave, balanced 2-pass, XCD-aware,
// T14 prefetch + DOUBLE-BUFFERED K/V (128 KB LDS, 1 block/CU):
// per iter only 2 barriers (was 3), and the K/V ds_writes run CONCURRENTLY
// with S+P's MFMA instead of in a serial window between two barriers:
//   bA(end prev iter) -> { ds_write KV[cur^1](tk+1 data) || S+P reads
//   KV[cur] -> psq } -> b2 -> { LOADKV(tk+2) || PV reads psq+vts[cur] } -> bA
// Hazards: writes to KV[cur^1] guarded by prev iter's end barrier (its
// S+P/PV reads of [cur^1] complete pre-barrier); S+P(tk) reads KV[cur]
// written during iter tk-1, visible via 2 intervening barriers; psq/qs
// overlay guarded by b_init after q-hoist; WRITEKV's regs drained by
// compiler vmcnt (loads issued one full iteration earlier).
// Grid 256 = 1 block/CU, every block exactly 17 tile-iters.
// ---------------------------------------------------------------------------
__global__ __launch_bounds__(512, 2)
void attn_mfma(const unsigned short* __restrict__ qh, const unsigned short* __restrict__ q2h,
               const unsigned short* __restrict__ kh, const unsigned short* __restrict__ k2h,
               const unsigned short* __restrict__ vt, unsigned short* __restrict__ zout)
{
    __shared__ __align__(16) unsigned short smem[65536];   // 128 KB
    unsigned short* qs  = smem;              // [128][64] rot8 (init only)
    unsigned short* q2s = smem + 8192;
    unsigned short* psq = smem;              // [128][128] rot16, overlays qs/q2s
    unsigned short* kvb = smem + 16384;      // 2 x {ks 8192, k2s 8192, vts 8192}

    const int bid  = blockIdx.x;
    const int xcd  = bid & 7;
    const int slot = bid >> 3;          // 0..31
    const int hh   = slot >> 3;         // 0..3
    const int pr   = slot & 7;          // 0..7 (pair index)
    const int bh   = xcd * 4 + hh;
    const int t  = threadIdx.x;
    const int lane = t & 63;
    const int w    = t >> 6;          // 0..7
    const int s    = lane & 15;
    const int g    = lane >> 4;
    const int mk   = (w >> 1) * 32;   // 4-way k-split: 32 rows/wave
    const int nq   = (w & 1) * 64;    // 2-way q-split

    const int b = bh >> 4, h = bh & 15;

    short8 kf[2], k2f[2], vf[2];

#define LOADKV(TK) {                                                                \
    const unsigned short* kb  = kh  + ((size_t)bh * 2048 + (TK) * 128) * 64;        \
    const unsigned short* k2b = k2h + ((size_t)bh * 2048 + (TK) * 128) * 64;        \
    const unsigned short* vb  = vt  + (size_t)bh * 131072 + (TK) * 128;             \
    const int krow_ = t >> 2;                                                       \
    const int vd_   = t >> 3;                                                       \
    _Pragma("unroll")                                                               \
    for (int c = 0; c < 2; ++c) {                                                   \
        int cg_ = (t & 3) * 2 + c;                                                  \
        kf[c]  = *(const short8*)(kb  + (size_t)krow_ * 64 + cg_ * 8);              \
        k2f[c] = *(const short8*)(k2b + (size_t)krow_ * 64 + cg_ * 8);              \
        int cg16_ = (t & 7) * 2 + c;                                                \
        vf[c]  = *(const short8*)(vb + (size_t)vd_ * 2048 + cg16_ * 8);             \
    } }

#define WRITEKV(DST) {                                                              \
    unsigned short* ksd_  = (DST);                                                  \
    unsigned short* k2sd_ = (DST) + 8192;                                           \
    unsigned short* vtsd_ = (DST) + 16384;                                          \
    const int krow_ = t >> 2;                                                       \
    const int vd_   = t >> 3;                                                       \
    _Pragma("unroll")                                                               \
    for (int c = 0; c < 2; ++c) {                                                   \
        int cg_  = (t & 3) * 2 + c;                                                 \
        int cgm_ = (cg_ + krow_) & 7;                                               \
        *(short8*)&ksd_ [krow_ * 64 + cgm_ * 8] = kf[c];                            \
        *(short8*)&k2sd_[krow_ * 64 + cgm_ * 8] = k2f[c];                           \
        int cg16_  = (t & 7) * 2 + c;                                               \
        int cgm16_ = (cg16_ + vd_) & 15;                                            \
        *(short8*)&vtsd_[vd_ * 128 + cgm16_ * 8] = vf[c];                           \
    } }

    #pragma unroll
    for (int pass = 0; pass < 2; ++pass) {
        const int qt = pass ? pr : (15 - pr);

        __syncthreads();   // pass boundary: prev pass's psq/KV reads all done

        // issue K/V tile-0 loads early: latency overlaps q staging + hoist
        LOADKV(0);

        // ---- stage q, q2 for this q-tile ----
        {
            const unsigned short* qb  = qh  + ((size_t)bh * 2048 + qt * 128) * 64;
            const unsigned short* q2b = q2h + ((size_t)bh * 2048 + qt * 128) * 64;
            const int row = t >> 2;                    // 0..127
            #pragma unroll
            for (int c = 0; c < 2; ++c) {
                int cg  = (t & 3) * 2 + c;             // 0..7
                short8 a  = *(const short8*)(qb  + (size_t)row * 64 + cg * 8);
                short8 a2 = *(const short8*)(q2b + (size_t)row * 64 + cg * 8);
                int cgm = (cg + row) & 7;
                *(short8*)&qs [row * 64 + cgm * 8] = a;
                *(short8*)&q2s[row * 64 + cgm * 8] = a2;
            }
        }
        __syncthreads();   // qs visible
        short8 bq[2][4], bq2[2][4];
        #pragma unroll
        for (int kstep = 0; kstep < 2; ++kstep) {
            const int gl = kstep * 4 + g;
            #pragma unroll
            for (int j = 0; j < 4; ++j) {
                int row = nq + j * 16 + s;
                int a = row * 64 + ((gl + row) & 7) * 8;
                bq[kstep][j]  = *(const short8*)&qs [a];
                bq2[kstep][j] = *(const short8*)&q2s[a];
            }
        }

        // write KV[0] (compiler drains vmcnt for kf here), prefetch tile 1
        WRITEKV(kvb);
        if (qt > 0) LOADKV(1);
        __syncthreads();   // b_init: KV[0] visible; all waves' q-hoist done
                           // (guards psq overlay of qs)

        floatx4 zac[4];
        #pragma unroll
        for (int j = 0; j < 4; ++j)
            zac[j] = (floatx4)(0.0f);

        for (int tk = 0; tk <= qt; ++tk) {
            const int cur = tk & 1;
            unsigned short* kvc = kvb + cur * 24576;        // read buffer
            unsigned short* kvn = kvb + (cur ^ 1) * 24576;  // write buffer

            // ---- phase A: ds_write next K/V (overlaps S+P MFMA) ----
            if (tk < qt) WRITEKV(kvn);

            // ---- S + P, i-outer (2 frags of 16 k-rows per wave) ----
            #pragma unroll
            for (int i = 0; i < 2; ++i) {
                floatx4 a1[4], a2[4];
                #pragma unroll
                for (int j = 0; j < 4; ++j) { a1[j] = (floatx4)(0.0f); a2[j] = (floatx4)(0.0f); }
                #pragma unroll
                for (int kstep = 0; kstep < 2; ++kstep) {
                    const int gl = kstep * 4 + g;
                    int row = mk + i * 16 + s;
                    int a = row * 64 + ((gl + row) & 7) * 8;
                    short8 ak  = *(const short8*)&kvc[a];
                    short8 ak2 = *(const short8*)&kvc[8192 + a];
                    #pragma unroll
                    for (int j = 0; j < 4; ++j) {
                        a1[j] = __builtin_amdgcn_mfma_f32_16x16x32_bf16(ak,  bq[kstep][j],  a1[j], 0, 0, 0);
                        a2[j] = __builtin_amdgcn_mfma_f32_16x16x32_bf16(ak2, bq2[kstep][j], a2[j], 0, 0, 0);
                    }
                }
                // P-write for this i: psq region unread by anyone during the loop
                const int kl0   = mk + i * 16 + g * 4;
                const int chunk = kl0 >> 3;
                const int sub   = kl0 & 7;
                if (tk < qt) {
                    #pragma unroll
                    for (int j = 0; j < 4; ++j) {
                        const int ql = nq + j * 16 + s;
                        ushort4 pw;
                        pw.x = f2bf(a1[j][0] * a2[j][0]);
                        pw.y = f2bf(a1[j][1] * a2[j][1]);
                        pw.z = f2bf(a1[j][2] * a2[j][2]);
                        pw.w = f2bf(a1[j][3] * a2[j][3]);
                        *(ushort4*)&psq[ql * 128 + ((chunk + ql) & 15) * 8 + sub] = pw;
                    }
                } else {
                    #pragma unroll
                    for (int j = 0; j < 4; ++j) {
                        const int ql = nq + j * 16 + s;
                        ushort4 pw;
                        pw.x = (kl0 + 0 <= ql) ? f2bf(a1[j][0] * a2[j][0]) : (unsigned short)0;
                        pw.y = (kl0 + 1 <= ql) ? f2bf(a1[j][1] * a2[j][1]) : (unsigned short)0;
                        pw.z = (kl0 + 2 <= ql) ? f2bf(a1[j][2] * a2[j][2]) : (unsigned short)0;
                        pw.w = (kl0 + 3 <= ql) ? f2bf(a1[j][3] * a2[j][3]) : (unsigned short)0;
                        *(ushort4*)&psq[ql * 128 + ((chunk + ql) & 15) * 8 + sub] = pw;
                    }
                }
            }

            __syncthreads();   // b2: psq (and KV writes) visible

            // ---- phase B: prefetch K/V(tk+2) regs; latency hides under PV ----
            if (tk + 2 <= qt) LOADKV(tk + 2);
            __builtin_amdgcn_sched_barrier(0);

            // ---- PV: z[q][d] += P[q][k] * vT[d][k] ; wave owns 16 q-rows ----
            const int wm0 = w * 16;
            #pragma unroll
            for (int kstep = 0; kstep < 4; ++kstep) {
                const int cbase = kstep * 4 + g;
                short8 ap, bv[4];
                {
                    int q = wm0 + s;
                    ap = *(const short8*)&psq[q * 128 + ((cbase + q) & 15) * 8];
                }
                #pragma unroll
                for (int jd = 0; jd < 4; ++jd) {
                    int d = jd * 16 + s;
                    bv[jd] = *(const short8*)&kvc[16384 + d * 128 + ((cbase + d) & 15) * 8];
                }
                #pragma unroll
                for (int jd = 0; jd < 4; ++jd)
                    zac[jd] = __builtin_amdgcn_mfma_f32_16x16x32_bf16(ap, bv[jd], zac[jd], 0, 0, 0);
            }

            __syncthreads();   // bA: PV reads done; next iter may overwrite
                               // KV[cur] and psq
        }

        // ---- epilogue: z -> split bf16 [hi | lo] into zout[4096][2048] ----
        const size_t zrow0 = (size_t)(b * TSEQ + qt * 128);
        #pragma unroll
        for (int j = 0; j < 4; ++j)
            #pragma unroll
            for (int r = 0; r < 4; ++r) {
                float zv = zac[j][r];
                unsigned short hi = f2bf(zv);
                unsigned short lo = f2bf(zv - bf2f(hi));
                size_t row = zrow0 + w * 16 + g * 4 + r;
                int col = h * 64 + j * 16 + s;
                zout[row * 2048 + col]        = hi;
                zout[row * 2048 + 1024 + col] = lo;
            }
    }
#undef LOADKV
#undef WRITEKV
}

// ---------------------------------------------------------------------------
extern "C" void kernel_launch(void* const* d_in, const int* in_sizes, int n_in,
                              void* d_out, int out_size, void* d_ws, size_t ws_size,
                              hipStream_t stream)
{
    const float* x     = (const float*)d_in[0];
    const float* Wq    = (const float*)d_in[1];
    const float* Wk    = (const float*)d_in[2];
    const float* Wq2   = (const float*)d_in[3];
    const float* Wk2   = (const float*)d_in[4];
    const float* Wv    = (const float*)d_in[5];
    const float* Wproj = (const float*)d_in[6];

    // workspace (bytes):
    //   Xp    bf16 [4096][2048] (x-hi packed, later z-split) @ 0      (16,777,216)
    //   Wp    bf16 [6144][2048]                          @ 16,777,216 (25,165,824)
    //         rows [0,1024)    = Wproj [hi|lo]
    //         rows [1024,6144) = Wq,Wk,Wq2,Wk2 (head-interleaved), Wv [hi|dead]
    //   heads bf16 4x[32][2048][64] (q,k,q2,k2)          @ 41,943,040 (33,554,432)
    //   vt    bf16 [32][64][2048]                        @ 75,497,472 ( 8,388,608)
    unsigned short* Xp    = (unsigned short*)d_ws;
    unsigned short* Wp    = (unsigned short*)((char*)d_ws + 16777216);
    unsigned short* heads = (unsigned short*)((char*)d_ws + 41943040);
    unsigned short* vt    = (unsigned short*)((char*)d_ws + 75497472);

    const size_t HS = (size_t)32 * 2048 * 64;
    unsigned short* qh  = heads;
    unsigned short* kh  = heads + 1 * HS;
    unsigned short* q2h = heads + 2 * HS;
    unsigned short* k2h = heads + 3 * HS;

    pack_all_kernel<<<10240, 256, 0, stream>>>(x, Wproj, Wq, Wk, Wq2, Wk2, Wv, Xp, Wp);
    gemm_qkv<<<dim3(16, 16), 512, 0, stream>>>(Xp, Wp + (size_t)1024 * 2048, heads, vt);
    attn_mfma<<<256, 512, 0, stream>>>(qh, q2h, kh, k2h, vt, Xp);
    gemm_proj<<<dim3(32, 8), 256, 0, stream>>>(Xp, Wp, (float*)d_out);
}

// Round 12
// 202.214 us; speedup vs baseline: 1.7368x; 1.1272x over previous
//
#include <hip/hip_runtime.h>
#include <hip/hip_bf16.h>

#define TSEQ 2048
#define NHEAD 16
#define DM 1024
#define NBATCH 2
#define MTOK (NBATCH * TSEQ)   // 4096

typedef __attribute__((ext_vector_type(8))) short short8;
typedef __attribute__((ext_vector_type(4))) float floatx4;
typedef __attribute__((address_space(1))) const void gvoid;
typedef __attribute__((address_space(3))) void lvoid;

static __device__ __forceinline__ unsigned short f2bf(float f) {
    unsigned int u = __float_as_uint(f);
    return (unsigned short)((u + 0x7fffu + ((u >> 16) & 1u)) >> 16);
}
static __device__ __forceinline__ float bf2f(unsigned short h) {
    return __uint_as_float(((unsigned int)h) << 16);
}

// ---------------------------------------------------------------------------
// Pack x and the 6 weight matrices to bf16 rows (SINGLE precision level —
// round 8 measured that split-bf16 terms past a bf16-stored tensor don't
// move absmax; z/y now follow the same rule, so NO lo halves anywhere).
//   x, Wproj, Wq..Wv -> [hi(1024) | dead]
//   Wq,Wk,Wq2,Wk2 rows additionally PER-HEAD INTERLEAVED:
//     d<32 -> (d>>3)*16 + (d&7) ; d>=32 -> ((d-32)>>3)*16 + 8 + (d&7)
//   so each 16-col C-fragment holds RoPE pairs at lanes cc / cc^8.
// blocks [0,4096) -> x ; [4096,10240) -> weights (1024 blocks each).
// ---------------------------------------------------------------------------
__global__ __launch_bounds__(256)
void pack_all_kernel(const float* __restrict__ x,
                     const float* __restrict__ w0, const float* __restrict__ w1,
                     const float* __restrict__ w2, const float* __restrict__ w3,
                     const float* __restrict__ w4, const float* __restrict__ w5,
                     unsigned short* __restrict__ dstX, unsigned short* __restrict__ dstW)
{
    const float* src;
    unsigned short* dst;
    int gid;
    bool ilv = false;
    if (blockIdx.x < 4096) {
        src = x; dst = dstX;
        gid = blockIdx.x * 256 + threadIdx.x;
    } else {
        int wi = (blockIdx.x - 4096) >> 10;
        const float* srcs[6] = {w0, w1, w2, w3, w4, w5};
        src = srcs[wi];
        dst = dstW + (size_t)wi * 1024 * 2048;
        gid = ((blockIdx.x - 4096) & 1023) * 256 + threadIdx.x;
        ilv = (wi >= 1 && wi <= 4);   // Wq, Wk, Wq2, Wk2
    }
    int e   = gid * 4;
    int row = e >> 10;
    int col = e & 1023;
    float4 f = *(const float4*)(src + (size_t)row * 1024 + col);
    ushort4 hi;
    hi.x = f2bf(f.x);
    hi.y = f2bf(f.y);
    hi.z = f2bf(f.z);
    hi.w = f2bf(f.w);
    int drow = row;
    if (ilv) {
        int hh = row >> 6, d = row & 63;
        int dd = (d < 32) ? ((d >> 3) * 16 + (d & 7))
                          : (((d - 32) >> 3) * 16 + 8 + (d & 7));
        drow = hh * 64 + dd;
    }
    *(ushort4*)(dst + (size_t)drow * 2048 + col) = hi;
}

// ---------------------------------------------------------------------------
// qkv GEMM — 1-TERM hi-only, K=1024 (UNCHANGED):
//   C[4096][5120] = Xhi[4096][1024] . Whi[5120][1024]^T
// Tile 256x320, K-tile 64, 8 waves 2M x 4N, counted vmcnt(8), 16 K-tiles.
// ---------------------------------------------------------------------------
#define VMW(N) asm volatile("s_waitcnt vmcnt(" #N ")" ::: "memory")
#define LGKM0  asm volatile("s_waitcnt lgkmcnt(0)" ::: "memory")

__global__ __launch_bounds__(512, 2)
void gemm_qkv(const unsigned short* __restrict__ Ap,
              const unsigned short* __restrict__ Bp,
              unsigned short* __restrict__ Ch, unsigned short* __restrict__ Vt)
{
    __shared__ __align__(16) unsigned short A0s[2][8192];    // [256][32] each
    __shared__ __align__(16) unsigned short A1s[2][8192];
    __shared__ __align__(16) unsigned short B0s[2][10240];   // [320][32] each
    __shared__ __align__(16) unsigned short B1s[2][10240];

    const int t    = threadIdx.x;
    const int lane = t & 63;
    const int w    = t >> 6;
    const int wm   = w >> 2;          // M-half (0..1): 128 rows
    const int wn   = w & 3;           // N-quarter (0..3): 80 cols
    const int s    = lane & 15;
    const int g    = (lane >> 4) & 3;
    const int row0 = blockIdx.x * 256;
    const int col0 = blockIdx.y * 320;

    // read-side swizzled offsets (element units, 32-wide rows)
    const int cofs  = ((g ^ ((lane >> 1) & 3)) << 3);
    const int addrA = (wm * 128 + s) * 32 + cofs;   // + ii*512
    const int addrB = (wn * 80 + s) * 32 + cofs;    // + nf*512

    // stage-side pre-swizzled global source base (logical chunk per thread)
    const int alc = (t & 3) ^ ((t >> 3) & 3);
    const unsigned short* Ag = Ap + (size_t)(row0 + (t >> 2)) * 2048 + alc * 8;
    const unsigned short* Bg = Bp + (size_t)(col0 + (t >> 2)) * 2048 + alc * 8;

#define STAGE_A(dst, kofs) {                                                                              \
    __builtin_amdgcn_global_load_lds((gvoid*)(Ag + (kofs)),              (lvoid*)((dst) + t * 8),        16, 0, 0); \
    __builtin_amdgcn_global_load_lds((gvoid*)(Ag + (kofs) + 128 * 2048), (lvoid*)((dst) + 4096 + t * 8), 16, 0, 0); }

#define STAGE_B(dst, kofs) {                                                                              \
    __builtin_amdgcn_global_load_lds((gvoid*)(Bg + (kofs)),              (lvoid*)((dst) + t * 8),        16, 0, 0); \
    __builtin_amdgcn_global_load_lds((gvoid*)(Bg + (kofs) + 128 * 2048), (lvoid*)((dst) + 4096 + t * 8), 16, 0, 0); \
    if (t < 256)                                                                                          \
    __builtin_amdgcn_global_load_lds((gvoid*)(Bg + (kofs) + 256 * 2048), (lvoid*)((dst) + 8192 + t * 8), 16, 0, 0); }

    floatx4 acc[8][5];
    #pragma unroll
    for (int ii = 0; ii < 8; ++ii)
        #pragma unroll
        for (int nf = 0; nf < 5; ++nf)
            acc[ii][nf] = (floatx4)(0.0f);

    // ---- prologue: tile0 (kh0,kh1) and tile1 (kh0) ----
    STAGE_A(A0s[0], 0);
    STAGE_B(B0s[0], 0);
    STAGE_A(A1s[0], 32);
    STAGE_B(B1s[0], 32);
    STAGE_A(A0s[1], 64);
    STAGE_B(B0s[1], 64);
    VMW(4);                       // tile0 fully landed (newest 4-5 = tile1 kh0)
    __builtin_amdgcn_s_barrier();
    __builtin_amdgcn_sched_barrier(0);

#define MFMA_CLUSTER(IOFS)                                                                      \
    __builtin_amdgcn_s_setprio(1);                                                              \
    _Pragma("unroll")                                                                           \
    for (int ii = 0; ii < 4; ++ii)                                                              \
        _Pragma("unroll")                                                                       \
        for (int nf = 0; nf < 5; ++nf)                                                          \
            acc[(IOFS) + ii][nf] = __builtin_amdgcn_mfma_f32_16x16x32_bf16(af[ii], bf[nf], acc[(IOFS) + ii][nf], 0, 0, 0); \
    __builtin_amdgcn_s_setprio(0);

#define TILE_BODY(TAU, DO12, DO34, W2, W4)                                                      \
{                                                                                               \
    const int cur_ = (TAU) & 1;                                                                 \
    const unsigned short* a0k = A0s[cur_];                                                      \
    const unsigned short* a1k = A1s[cur_];                                                      \
    const unsigned short* b0k = B0s[cur_];                                                      \
    const unsigned short* b1k = B1s[cur_];                                                      \
    short8 af[4], bf[5];                                                                        \
    /* ---- p1: kh0, M-half0 + B-kh0 read ; stage (TAU+1) A-kh1 ---- */                         \
    _Pragma("unroll")                                                                           \
    for (int ii = 0; ii < 4; ++ii) af[ii] = *(const short8*)&a0k[addrA + ii * 512];             \
    _Pragma("unroll")                                                                           \
    for (int nf = 0; nf < 5; ++nf) bf[nf] = *(const short8*)&b0k[addrB + nf * 512];             \
    if (DO12) STAGE_A(A1s[cur_ ^ 1], ((TAU) + 1) * 64 + 32);                                    \
    LGKM0;                                                                                      \
    __builtin_amdgcn_s_barrier();                                                               \
    __builtin_amdgcn_sched_barrier(0);                                                          \
    MFMA_CLUSTER(0)                                                                             \
    /* ---- p2: kh0, M-half1 ; stage (TAU+1) B-kh1 ; vmcnt ---- */                              \
    _Pragma("unroll")                                                                           \
    for (int ii = 0; ii < 4; ++ii) af[ii] = *(const short8*)&a0k[addrA + (ii + 4) * 512];       \
    if (DO12) STAGE_B(B1s[cur_ ^ 1], ((TAU) + 1) * 64 + 32);                                    \
    LGKM0;                                                                                      \
    W2;                                                                                         \
    __builtin_amdgcn_s_barrier();                                                               \
    __builtin_amdgcn_sched_barrier(0);                                                          \
    MFMA_CLUSTER(4)                                                                             \
    /* ---- p3: kh1, M-half0 + B-kh1 read ; stage (TAU+2) A-kh0 ---- */                         \
    _Pragma("unroll")                                                                           \
    for (int ii = 0; ii < 4; ++ii) af[ii] = *(const short8*)&a1k[addrA + ii * 512];             \
    _Pragma("unroll")                                                                           \
    for (int nf = 0; nf < 5; ++nf) bf[nf] = *(const short8*)&b1k[addrB + nf * 512];             \
    if (DO34) STAGE_A(A0s[cur_], ((TAU) + 2) * 64);                                             \
    LGKM0;                                                                                      \
    __builtin_amdgcn_s_barrier();                                                               \
    __builtin_amdgcn_sched_barrier(0);                                                          \
    MFMA_CLUSTER(0)                                                                             \
    /* ---- p4: kh1, M-half1 ; stage (TAU+2) B-kh0 ; vmcnt ---- */                              \
    _Pragma("unroll")                                                                           \
    for (int ii = 0; ii < 4; ++ii) af[ii] = *(const short8*)&a1k[addrA + (ii + 4) * 512];       \
    if (DO34) STAGE_B(B0s[cur_], ((TAU) + 2) * 64);                                             \
    LGKM0;                                                                                      \
    W4;                                                                                        \
    __builtin_amdgcn_s_barrier();                                                               \
    __builtin_amdgcn_sched_barrier(0);                                                          \
    MFMA_CLUSTER(4)                                                                             \
}

    #pragma unroll 2
    for (int tau = 0; tau < 14; ++tau)
        TILE_BODY(tau, 1, 1, VMW(8), VMW(8));
    TILE_BODY(14, 1, 0, VMW(8), VMW(4));
    TILE_BODY(15, 0, 0, VMW(0), ((void)0));

#undef TILE_BODY
#undef MFMA_CLUSTER
#undef STAGE_A
#undef STAGE_B

    // ---- epilogue: lane-local RoPE (+1/64 q-scale); V transposed ----
    const int cr = (lane >> 4) * 4;
    const int cc = lane & 15;
    const int rwbase = row0 + wm * 128;
    const float L2C = -0.41524101186092029f;  // -log2(10000)/32

    #pragma unroll
    for (int nf = 0; nf < 5; ++nf) {
        const int cg = col0 + wn * 80 + nf * 16;  // global col of this frag
        const int p  = cg >> 10;                  // 0=q 1=k 2=q2 3=k2 4=v
        const int h  = (cg >> 6) & 15;
        const int f  = (cg >> 4) & 3;
        if (p < 4) {
            const float sc  = (p == 0 || p == 2) ? 0.015625f : 1.0f;
            const float inv = exp2f((float)(f * 8 + (cc & 7)) * L2C);
            unsigned short* hp = Ch + (size_t)p * 4194304;
            #pragma unroll
            for (int ii = 0; ii < 8; ++ii) {
                int r0  = rwbase + ii * 16 + cr;
                int bhi = ((r0 >> 11) << 4) + h;
                size_t base = ((size_t)bhi * 2048 + (r0 & 2047)) * 64;
                #pragma unroll
                for (int rr = 0; rr < 4; ++rr) {
                    float tt = (float)((r0 + rr) & 2047);
                    float s0, c0;
                    __sincosf(tt * inv, &s0, &c0);
                    float x  = acc[ii][nf][rr];
                    float xp = __shfl_xor(x, 8, 64);
                    float y  = (cc < 8) ? (x * c0 + xp * s0) : (x * c0 - xp * s0);
                    hp[base + (size_t)rr * 64 + (f * 16 + cc)] = f2bf(y * sc);
                }
            }
        } else {
            #pragma unroll
            for (int ii = 0; ii < 8; ++ii) {
                int r0  = rwbase + ii * 16 + cr;
                int bhi = ((r0 >> 11) << 4) + h;
                int d   = f * 16 + cc;
                ushort4 o;
                o.x = f2bf(acc[ii][nf][0]); o.y = f2bf(acc[ii][nf][1]);
                o.z = f2bf(acc[ii][nf][2]); o.w = f2bf(acc[ii][nf][3]);
                *(ushort4*)(Vt + ((size_t)bhi * 64 + d) * 2048 + (r0 & 2047)) = o;
            }
        }
    }
}

// ---------------------------------------------------------------------------
// Output projection — 1-TERM bf16: C = Ah . Bh^T, fp32 out (z and Wproj both
// single-bf16 now; dropped Al.Bh and Ah.Bl terms — each contributes ~1.1e-3
// relative error, same class as the bf16 storage rounding already present).
// 128x128 tile, grid (32,8) = 256 blocks = 1/CU, 4 waves (wave-tile 64x64),
// 16 MFMA : 8 ds_reads per K-step, 16 KB LDS, chunk-XOR swizzle, 2 barriers.
// ---------------------------------------------------------------------------
__global__ __launch_bounds__(256)
void gemm_proj(const unsigned short* __restrict__ Ap,
               const unsigned short* __restrict__ Bp,
               float* __restrict__ Cf)
{
    __shared__ __align__(16) unsigned short Ah[128 * 32];
    __shared__ __align__(16) unsigned short Bh[128 * 32];

    const int t    = threadIdx.x;
    const int lane = t & 63;
    const int s    = lane & 15;
    const int row0 = blockIdx.x * 128;
    const int col0 = blockIdx.y * 128;
    const int m0   = ((t >> 6) >> 1) * 64;
    const int n0   = ((t >> 6) & 1) * 64;

    floatx4 acc[4][4];
    #pragma unroll
    for (int i = 0; i < 4; ++i)
        #pragma unroll
        for (int j = 0; j < 4; ++j)
            acc[i][j] = (floatx4)(0.0f);

    const int sr  = t >> 2;
    const int skx = ((t & 3) ^ ((t >> 3) & 3)) * 8;
    char* dA  = (char*)Ah + (size_t)t * 16;
    char* dB  = (char*)Bh + (size_t)t * 16;
    const size_t arow = (size_t)(row0 + sr) * 2048 + skx;
    const size_t brow = (size_t)(col0 + sr) * 2048 + skx;

    #define ISSUE(k0)                                                                         \
    {                                                                                         \
        const unsigned short* ga = Ap + arow + (k0);                                          \
        const unsigned short* gb = Bp + brow + (k0);                                          \
        __builtin_amdgcn_global_load_lds((gvoid*)ga,                 (lvoid*)dA,          16, 0, 0); \
        __builtin_amdgcn_global_load_lds((gvoid*)(ga + 64*2048),     (lvoid*)(dA + 4096), 16, 0, 0); \
        __builtin_amdgcn_global_load_lds((gvoid*)gb,                 (lvoid*)dB,          16, 0, 0); \
        __builtin_amdgcn_global_load_lds((gvoid*)(gb + 64*2048),     (lvoid*)(dB + 4096), 16, 0, 0); \
    }

    const int cofs = (((lane >> 4) ^ ((lane >> 1) & 3)) << 3);

    ISSUE(0);
    for (int ks = 0; ks < 32; ++ks) {
        __syncthreads();
        short8 ahf[4], bhf[4];
        #pragma unroll
        for (int i = 0; i < 4; ++i)
            ahf[i] = *(const short8*)&Ah[(m0 + i * 16 + s) * 32 + cofs];
        #pragma unroll
        for (int j = 0; j < 4; ++j)
            bhf[j] = *(const short8*)&Bh[(n0 + j * 16 + s) * 32 + cofs];
        #pragma unroll
        for (int i = 0; i < 4; ++i)
            #pragma unroll
            for (int j = 0; j < 4; ++j)
                acc[i][j] = __builtin_amdgcn_mfma_f32_16x16x32_bf16(ahf[i], bhf[j], acc[i][j], 0, 0, 0);
        __syncthreads();
        if (ks + 1 < 32) ISSUE((ks + 1) * 32);
    }
    #undef ISSUE

    const int cr = (lane >> 4) * 4;
    const int cc = lane & 15;
    #pragma unroll
    for (int i = 0; i < 4; ++i)
        #pragma unroll
        for (int j = 0; j < 4; ++j) {
            int r = row0 + m0 + i * 16 + cr;
            int c = col0 + n0 + j * 16 + cc;
            #pragma unroll
            for (int rr = 0; rr < 4; ++rr)
                Cf[(size_t)(r + rr) * 1024 + c] = acc[i][j][rr];
        }
}

// ---------------------------------------------------------------------------
// MFMA bilinear causal attention — 8-wave, balanced 2-pass, XCD-aware,
// T14 prefetch + double-buffered K/V (UNCHANGED structure from round 11);
// epilogue now writes z as SINGLE bf16 (hi only — proj is 1-term), halving
// the z store traffic.
// Grid 256 = 1 block/CU, every block exactly 17 tile-iters. LDS 128 KB.
// ---------------------------------------------------------------------------
__global__ __launch_bounds__(512, 2)
void attn_mfma(const unsigned short* __restrict__ qh, const unsigned short* __restrict__ q2h,
               const unsigned short* __restrict__ kh, const unsigned short* __restrict__ k2h,
               const unsigned short* __restrict__ vt, unsigned short* __restrict__ zout)
{
    __shared__ __align__(16) unsigned short smem[65536];   // 128 KB
    unsigned short* qs  = smem;              // [128][64] rot8 (init only)
    unsigned short* q2s = smem + 8192;
    unsigned short* psq = smem;              // [128][128] rot16, overlays qs/q2s
    unsigned short* kvb = smem + 16384;      // 2 x {ks 8192, k2s 8192, vts 8192}

    const int bid  = blockIdx.x;
    const int xcd  = bid & 7;
    const int slot = bid >> 3;          // 0..31
    const int hh   = slot >> 3;         // 0..3
    const int pr   = slot & 7;          // 0..7 (pair index)
    const int bh   = xcd * 4 + hh;
    const int t  = threadIdx.x;
    const int lane = t & 63;
    const int w    = t >> 6;          // 0..7
    const int s    = lane & 15;
    const int g    = lane >> 4;
    const int mk   = (w >> 1) * 32;   // 4-way k-split: 32 rows/wave
    const int nq   = (w & 1) * 64;    // 2-way q-split

    const int b = bh >> 4, h = bh & 15;

    short8 kf[2], k2f[2], vf[2];

#define LOADKV(TK) {                                                                \
    const unsigned short* kb  = kh  + ((size_t)bh * 2048 + (TK) * 128) * 64;        \
    const unsigned short* k2b = k2h + ((size_t)bh * 2048 + (TK) * 128) * 64;        \
    const unsigned short* vb  = vt  + (size_t)bh * 131072 + (TK) * 128;             \
    const int krow_ = t >> 2;                                                       \
    const int vd_   = t >> 3;                                                       \
    _Pragma("unroll")                                                               \
    for (int c = 0; c < 2; ++c) {                                                   \
        int cg_ = (t & 3) * 2 + c;                                                  \
        kf[c]  = *(const short8*)(kb  + (size_t)krow_ * 64 + cg_ * 8);              \
        k2f[c] = *(const short8*)(k2b + (size_t)krow_ * 64 + cg_ * 8);              \
        int cg16_ = (t & 7) * 2 + c;                                                \
        vf[c]  = *(const short8*)(vb + (size_t)vd_ * 2048 + cg16_ * 8);             \
    } }

#define WRITEKV(DST) {                                                              \
    unsigned short* ksd_  = (DST);                                                  \
    unsigned short* k2sd_ = (DST) + 8192;                                           \
    unsigned short* vtsd_ = (DST) + 16384;                                          \
    const int krow_ = t >> 2;                                                       \
    const int vd_   = t >> 3;                                                       \
    _Pragma("unroll")                                                               \
    for (int c = 0; c < 2; ++c) {                                                   \
        int cg_  = (t & 3) * 2 + c;                                                 \
        int cgm_ = (cg_ + krow_) & 7;                                               \
        *(short8*)&ksd_ [krow_ * 64 + cgm_ * 8] = kf[c];                            \
        *(short8*)&k2sd_[krow_ * 64 + cgm_ * 8] = k2f[c];                           \
        int cg16_  = (t & 7) * 2 + c;                                               \
        int cgm16_ = (cg16_ + vd_) & 15;                                            \
        *(short8*)&vtsd_[vd_ * 128 + cgm16_ * 8] = vf[c];                           \
    } }

    #pragma unroll
    for (int pass = 0; pass < 2; ++pass) {
        const int qt = pass ? pr : (15 - pr);

        __syncthreads();   // pass boundary: prev pass's psq/KV reads all done

        // issue K/V tile-0 loads early: latency overlaps q staging + hoist
        LOADKV(0);

        // ---- stage q, q2 for this q-tile ----
        {
            const unsigned short* qb  = qh  + ((size_t)bh * 2048 + qt * 128) * 64;
            const unsigned short* q2b = q2h + ((size_t)bh * 2048 + qt * 128) * 64;
            const int row = t >> 2;                    // 0..127
            #pragma unroll
            for (int c = 0; c < 2; ++c) {
                int cg  = (t & 3) * 2 + c;             // 0..7
                short8 a  = *(const short8*)(qb  + (size_t)row * 64 + cg * 8);
                short8 a2 = *(const short8*)(q2b + (size_t)row * 64 + cg * 8);
                int cgm = (cg + row) & 7;
                *(short8*)&qs [row * 64 + cgm * 8] = a;
                *(short8*)&q2s[row * 64 + cgm * 8] = a2;
            }
        }
        __syncthreads();   // qs visible
        short8 bq[2][4], bq2[2][4];
        #pragma unroll
        for (int kstep = 0; kstep < 2; ++kstep) {
            const int gl = kstep * 4 + g;
            #pragma unroll
            for (int j = 0; j < 4; ++j) {
                int row = nq + j * 16 + s;
                int a = row * 64 + ((gl + row) & 7) * 8;
                bq[kstep][j]  = *(const short8*)&qs [a];
                bq2[kstep][j] = *(const short8*)&q2s[a];
            }
        }

        // write KV[0] (compiler drains vmcnt for kf here), prefetch tile 1
        WRITEKV(kvb);
        if (qt > 0) LOADKV(1);
        __syncthreads();   // b_init: KV[0] visible; all waves' q-hoist done
                           // (guards psq overlay of qs)

        floatx4 zac[4];
        #pragma unroll
        for (int j = 0; j < 4; ++j)
            zac[j] = (floatx4)(0.0f);

        for (int tk = 0; tk <= qt; ++tk) {
            const int cur = tk & 1;
            unsigned short* kvc = kvb + cur * 24576;        // read buffer
            unsigned short* kvn = kvb + (cur ^ 1) * 24576;  // write buffer

            // ---- phase A: ds_write next K/V (overlaps S+P MFMA) ----
            if (tk < qt) WRITEKV(kvn);

            // ---- S + P, i-outer (2 frags of 16 k-rows per wave) ----
            #pragma unroll
            for (int i = 0; i < 2; ++i) {
                floatx4 a1[4], a2[4];
                #pragma unroll
                for (int j = 0; j < 4; ++j) { a1[j] = (floatx4)(0.0f); a2[j] = (floatx4)(0.0f); }
                #pragma unroll
                for (int kstep = 0; kstep < 2; ++kstep) {
                    const int gl = kstep * 4 + g;
                    int row = mk + i * 16 + s;
                    int a = row * 64 + ((gl + row) & 7) * 8;
                    short8 ak  = *(const short8*)&kvc[a];
                    short8 ak2 = *(const short8*)&kvc[8192 + a];
                    #pragma unroll
                    for (int j = 0; j < 4; ++j) {
                        a1[j] = __builtin_amdgcn_mfma_f32_16x16x32_bf16(ak,  bq[kstep][j],  a1[j], 0, 0, 0);
                        a2[j] = __builtin_amdgcn_mfma_f32_16x16x32_bf16(ak2, bq2[kstep][j], a2[j], 0, 0, 0);
                    }
                }
                // P-write for this i: psq region unread by anyone during the loop
                const int kl0   = mk + i * 16 + g * 4;
                const int chunk = kl0 >> 3;
                const int sub   = kl0 & 7;
                if (tk < qt) {
                    #pragma unroll
                    for (int j = 0; j < 4; ++j) {
                        const int ql = nq + j * 16 + s;
                        ushort4 pw;
                        pw.x = f2bf(a1[j][0] * a2[j][0]);
                        pw.y = f2bf(a1[j][1] * a2[j][1]);
                        pw.z = f2bf(a1[j][2] * a2[j][2]);
                        pw.w = f2bf(a1[j][3] * a2[j][3]);
                        *(ushort4*)&psq[ql * 128 + ((chunk + ql) & 15) * 8 + sub] = pw;
                    }
                } else {
                    #pragma unroll
                    for (int j = 0; j < 4; ++j) {
                        const int ql = nq + j * 16 + s;
                        ushort4 pw;
                        pw.x = (kl0 + 0 <= ql) ? f2bf(a1[j][0] * a2[j][0]) : (unsigned short)0;
                        pw.y = (kl0 + 1 <= ql) ? f2bf(a1[j][1] * a2[j][1]) : (unsigned short)0;
                        pw.z = (kl0 + 2 <= ql) ? f2bf(a1[j][2] * a2[j][2]) : (unsigned short)0;
                        pw.w = (kl0 + 3 <= ql) ? f2bf(a1[j][3] * a2[j][3]) : (unsigned short)0;
                        *(ushort4*)&psq[ql * 128 + ((chunk + ql) & 15) * 8 + sub] = pw;
                    }
                }
            }

            __syncthreads();   // b2: psq (and KV writes) visible

            // ---- phase B: prefetch K/V(tk+2) regs; latency hides under PV ----
            if (tk + 2 <= qt) LOADKV(tk + 2);
            __builtin_amdgcn_sched_barrier(0);

            // ---- PV: z[q][d] += P[q][k] * vT[d][k] ; wave owns 16 q-rows ----
            const int wm0 = w * 16;
            #pragma unroll
            for (int kstep = 0; kstep < 4; ++kstep) {
                const int cbase = kstep * 4 + g;
                short8 ap, bv[4];
                {
                    int q = wm0 + s;
                    ap = *(const short8*)&psq[q * 128 + ((cbase + q) & 15) * 8];
                }
                #pragma unroll
                for (int jd = 0; jd < 4; ++jd) {
                    int d = jd * 16 + s;
                    bv[jd] = *(const short8*)&kvc[16384 + d * 128 + ((cbase + d) & 15) * 8];
                }
                #pragma unroll
                for (int jd = 0; jd < 4; ++jd)
                    zac[jd] = __builtin_amdgcn_mfma_f32_16x16x32_bf16(ap, bv[jd], zac[jd], 0, 0, 0);
            }

            __syncthreads();   // bA: PV reads done; next iter may overwrite
                               // KV[cur] and psq
        }

        // ---- epilogue: z -> single bf16 into zout[4096][2048] (hi cols) ----
        const size_t zrow0 = (size_t)(b * TSEQ + qt * 128);
        #pragma unroll
        for (int j = 0; j < 4; ++j)
            #pragma unroll
            for (int r = 0; r < 4; ++r) {
                size_t row = zrow0 + w * 16 + g * 4 + r;
                int col = h * 64 + j * 16 + s;
                zout[row * 2048 + col] = f2bf(zac[j][r]);
            }
    }
#undef LOADKV
#undef WRITEKV
}

// ---------------------------------------------------------------------------
extern "C" void kernel_launch(void* const* d_in, const int* in_sizes, int n_in,
                              void* d_out, int out_size, void* d_ws, size_t ws_size,
                              hipStream_t stream)
{
    const float* x     = (const float*)d_in[0];
    const float* Wq    = (const float*)d_in[1];
    const float* Wk    = (const float*)d_in[2];
    const float* Wq2   = (const float*)d_in[3];
    const float* Wk2   = (const float*)d_in[4];
    const float* Wv    = (const float*)d_in[5];
    const float* Wproj = (const float*)d_in[6];

    // workspace (bytes):
    //   Xp    bf16 [4096][2048] (x-hi, later z single-bf16) @ 0       (16,777,216)
    //   Wp    bf16 [6144][2048]                          @ 16,777,216 (25,165,824)
    //         rows [0,1024)    = Wproj [hi|dead]
    //         rows [1024,6144) = Wq,Wk,Wq2,Wk2 (head-interleaved), Wv [hi|dead]
    //   heads bf16 4x[32][2048][64] (q,k,q2,k2)          @ 41,943,040 (33,554,432)
    //   vt    bf16 [32][64][2048]                        @ 75,497,472 ( 8,388,608)
    unsigned short* Xp    = (unsigned short*)d_ws;
    unsigned short* Wp    = (unsigned short*)((char*)d_ws + 16777216);
    unsigned short* heads = (unsigned short*)((char*)d_ws + 41943040);
    unsigned short* vt    = (unsigned short*)((char*)d_ws + 75497472);

    const size_t HS = (size_t)32 * 2048 * 64;
    unsigned short* qh  = heads;
    unsigned short* kh  = heads + 1 * HS;
    unsigned short* q2h = heads + 2 * HS;
    unsigned short* k2h = heads + 3 * HS;

    pack_all_kernel<<<10240, 256, 0, stream>>>(x, Wproj, Wq, Wk, Wq2, Wk2, Wv, Xp, Wp);
    gemm_qkv<<<dim3(16, 16), 512, 0, stream>>>(Xp, Wp + (size_t)1024 * 2048, heads, vt);
    attn_mfma<<<256, 512, 0, stream>>>(qh, q2h, kh, k2h, vt, Xp);
    gemm_proj<<<dim3(32, 8), 256, 0, stream>>>(Xp, Wp, (float*)d_out);
}